// Round 5
// baseline (1567.045 us; speedup 1.0000x reference)
//
#include <hip/hip_runtime.h>

#define N_NODES 100000
#define N_EDGES 1600000
#define IN_F 64
#define HID 128
#define N_CLS 64

#define NPB 128                               // nodes per dst-bucket (32 KB LDS acc)
#define NBUK ((N_NODES + NPB - 1) / NPB)      // 782
#define PAD 16                                // ints per padded counter (64 B line)

// ================= generic helpers =================
__global__ void k_zero_f4(float4* __restrict__ p, int n4) {
    int i = blockIdx.x * blockDim.x + threadIdx.x;
    if (i < n4) p[i] = make_float4(0.f, 0.f, 0.f, 0.f);
}
__global__ void k_init_bias(float* __restrict__ out, const float* __restrict__ b2, int n) {
    int i = blockIdx.x * blockDim.x + threadIdx.x;
    if (i < n) out[i] = b2[i & 63];
}

// ================= bucket build =================
// LDS-staged histogram of dst buckets -> padded global counters
__global__ __launch_bounds__(256) void k_bhist(const int* __restrict__ dst,
                                               int* __restrict__ bcnt) {
    __shared__ int h[NBUK];
    for (int i = threadIdx.x; i < NBUK; i += 256) h[i] = 0;
    __syncthreads();
    int stride = gridDim.x * blockDim.x;
    for (int e = blockIdx.x * blockDim.x + threadIdx.x; e < N_EDGES; e += stride)
        atomicAdd(&h[dst[e] >> 7], 1);
    __syncthreads();
    for (int i = threadIdx.x; i < NBUK; i += 256) {
        int v = h[i];
        if (v) atomicAdd(&bcnt[i * PAD], v);
    }
}

// scan 782 bucket counts -> boff[NBUK+1], init padded cursors
__global__ __launch_bounds__(1024) void k_bscan(const int* __restrict__ bcnt,
                                                int* __restrict__ boff,
                                                int* __restrict__ cursor) {
    __shared__ int buf[2][1024];
    const int t = threadIdx.x;
    int v = (t < NBUK) ? bcnt[t * PAD] : 0;
    buf[0][t] = v;
    __syncthreads();
    int cur = 0;
    for (int d = 1; d < 1024; d <<= 1) {
        int x = buf[cur][t];
        if (t >= d) x += buf[cur][t - d];
        buf[cur ^ 1][t] = x;
        __syncthreads();
        cur ^= 1;
    }
    if (t < NBUK) {
        int ex = buf[cur][t] - v;
        boff[t] = ex;
        cursor[t * PAD] = ex;
    }
    if (t == 0) boff[NBUK] = N_EDGES;
}

// scatter packed (dstLow<<17 | src) into bucket-ordered eb
__global__ void k_bscatter(const int* __restrict__ src, const int* __restrict__ dst,
                           int* __restrict__ cursor, int* __restrict__ eb) {
    int e = blockIdx.x * blockDim.x + threadIdx.x;
    if (e >= N_EDGES) return;
    int d = dst[e];
    int b = d >> 7;
    int pos = atomicAdd(&cursor[b * PAD], 1);
    eb[pos] = ((d & 127) << 17) | src[e];
}

// ================= fused bucket gather: LDS accumulate =================
// out[n][lane] = (bias?bias[lane]:0) + sum_{edges with dst==n} feat[src][lane]
__global__ __launch_bounds__(256) void k_bgather(const float* __restrict__ feat,
                                                 const int* __restrict__ eb,
                                                 const int* __restrict__ boff,
                                                 const float* __restrict__ bias,
                                                 float* __restrict__ out) {
    __shared__ float acc[NPB * 64];           // 32 KB
    const int t = threadIdx.x;
    const int lane = t & 63;
    const int wv = t >> 6;
    for (int i = t; i < NPB * 64; i += 256) acc[i] = 0.f;
    __syncthreads();

    const int beg = boff[blockIdx.x], end = boff[blockIdx.x + 1];
    for (int base = beg + wv * 64; base < end; base += 256) {
        int m = end - base; if (m > 64) m = 64;
        int id = (lane < m) ? eb[base + lane] : 0;
        int k = 0;
        for (; k + 4 <= m; k += 4) {
            int p0 = __shfl(id, k),     p1 = __shfl(id, k + 1);
            int p2 = __shfl(id, k + 2), p3 = __shfl(id, k + 3);
            float v0 = feat[(size_t)(p0 & 0x1FFFF) * 64 + lane];
            float v1 = feat[(size_t)(p1 & 0x1FFFF) * 64 + lane];
            float v2 = feat[(size_t)(p2 & 0x1FFFF) * 64 + lane];
            float v3 = feat[(size_t)(p3 & 0x1FFFF) * 64 + lane];
            atomicAdd(&acc[((p0 >> 17) << 6) + lane], v0);
            atomicAdd(&acc[((p1 >> 17) << 6) + lane], v1);
            atomicAdd(&acc[((p2 >> 17) << 6) + lane], v2);
            atomicAdd(&acc[((p3 >> 17) << 6) + lane], v3);
        }
        for (; k < m; ++k) {
            int p = __shfl(id, k);
            atomicAdd(&acc[((p >> 17) << 6) + lane],
                      feat[(size_t)(p & 0x1FFFF) * 64 + lane]);
        }
    }
    __syncthreads();

    const int n0 = blockIdx.x * NPB;
    const float bv = bias ? bias[lane] : 0.f;
    for (int i = t; i < NPB * 64; i += 256) {
        int n = n0 + (i >> 6);
        if (n < N_NODES) out[(size_t)n * 64 + (i & 63)] = acc[i] + bv;
    }
}

// ================= fallback atomic scatter (if ws too small) =================
__global__ void k_scatter64(const float* __restrict__ feat,
                            const int* __restrict__ src,
                            const int* __restrict__ dst,
                            float* __restrict__ out) {
    int i = blockIdx.x * blockDim.x + threadIdx.x;
    int e = i >> 4;
    if (e >= N_EDGES) return;
    int j = (i & 15) << 2;
    int s = src[e];
    int d = dst[e];
    float4 v = *reinterpret_cast<const float4*>(feat + (size_t)s * 64 + j);
    float* o = out + (size_t)d * 64 + j;
    atomicAdd(o + 0, v.x);
    atomicAdd(o + 1, v.y);
    atomicAdd(o + 2, v.z);
    atomicAdd(o + 3, v.w);
}

// ================= fused MLP: Z = relu(A*W1 + b1) * W2, in-place, register-tiled =================
#define MROWS 32
__global__ __launch_bounds__(256, 2) void k_mlp(float* __restrict__ A,
                                                const float* __restrict__ W1,
                                                const float* __restrict__ b1,
                                                const float* __restrict__ W2) {
    __shared__ float Ws[64 * 128];      // 32 KB: holds W1, then reused for W2
    __shared__ float xs[64 * 36];       // x transposed [k][row], padded stride 36
    __shared__ float hs[32 * 132];      // h row-major, padded stride 132
    __shared__ float b1s[128];
    const int t = threadIdx.x;
    const int row0 = blockIdx.x * MROWS;

    {
        const float4* w4 = (const float4*)W1;
        float4* s4 = (float4*)Ws;
        for (int i = t; i < 2048; i += 256) s4[i] = w4[i];
    }
    if (t < 128) b1s[t] = b1[t];
#pragma unroll
    for (int c = 0; c < 2; ++c) {
        int lin = t + c * 256;
        int r = lin >> 4;
        int k4 = lin & 15;
        float4 v = *(const float4*)(A + (size_t)(row0 + r) * 64 + k4 * 4);
        xs[(k4 * 4 + 0) * 36 + r] = v.x;
        xs[(k4 * 4 + 1) * 36 + r] = v.y;
        xs[(k4 * 4 + 2) * 36 + r] = v.z;
        xs[(k4 * 4 + 3) * 36 + r] = v.w;
    }
    __syncthreads();

    {
        const int rg = t >> 5, cg = t & 31;
        const int r0 = rg * 4, c0 = cg * 4;
        float4 bv = *(const float4*)&b1s[c0];
        float4 acc0 = bv, acc1 = bv, acc2 = bv, acc3 = bv;
#pragma unroll 8
        for (int k = 0; k < 64; ++k) {
            float4 w = *(const float4*)&Ws[k * 128 + c0];
            float4 a = *(const float4*)&xs[k * 36 + r0];
            acc0.x = fmaf(a.x, w.x, acc0.x); acc0.y = fmaf(a.x, w.y, acc0.y);
            acc0.z = fmaf(a.x, w.z, acc0.z); acc0.w = fmaf(a.x, w.w, acc0.w);
            acc1.x = fmaf(a.y, w.x, acc1.x); acc1.y = fmaf(a.y, w.y, acc1.y);
            acc1.z = fmaf(a.y, w.z, acc1.z); acc1.w = fmaf(a.y, w.w, acc1.w);
            acc2.x = fmaf(a.z, w.x, acc2.x); acc2.y = fmaf(a.z, w.y, acc2.y);
            acc2.z = fmaf(a.z, w.z, acc2.z); acc2.w = fmaf(a.z, w.w, acc2.w);
            acc3.x = fmaf(a.w, w.x, acc3.x); acc3.y = fmaf(a.w, w.y, acc3.y);
            acc3.z = fmaf(a.w, w.z, acc3.z); acc3.w = fmaf(a.w, w.w, acc3.w);
        }
        float4 h;
        h.x = fmaxf(acc0.x, 0.f); h.y = fmaxf(acc0.y, 0.f); h.z = fmaxf(acc0.z, 0.f); h.w = fmaxf(acc0.w, 0.f);
        *(float4*)&hs[(r0 + 0) * 132 + c0] = h;
        h.x = fmaxf(acc1.x, 0.f); h.y = fmaxf(acc1.y, 0.f); h.z = fmaxf(acc1.z, 0.f); h.w = fmaxf(acc1.w, 0.f);
        *(float4*)&hs[(r0 + 1) * 132 + c0] = h;
        h.x = fmaxf(acc2.x, 0.f); h.y = fmaxf(acc2.y, 0.f); h.z = fmaxf(acc2.z, 0.f); h.w = fmaxf(acc2.w, 0.f);
        *(float4*)&hs[(r0 + 2) * 132 + c0] = h;
        h.x = fmaxf(acc3.x, 0.f); h.y = fmaxf(acc3.y, 0.f); h.z = fmaxf(acc3.z, 0.f); h.w = fmaxf(acc3.w, 0.f);
        *(float4*)&hs[(r0 + 3) * 132 + c0] = h;
    }
    __syncthreads();

    {
        const float4* w4 = (const float4*)W2;
        float4* s4 = (float4*)Ws;
        for (int i = t; i < 2048; i += 256) s4[i] = w4[i];
    }
    __syncthreads();

    {
        const int rg = t >> 4, cg = t & 15;
        const int r0 = rg * 2, c0 = cg * 4;
        float4 acc0 = make_float4(0.f, 0.f, 0.f, 0.f);
        float4 acc1 = make_float4(0.f, 0.f, 0.f, 0.f);
#pragma unroll 8
        for (int k = 0; k < 128; ++k) {
            float4 w = *(const float4*)&Ws[k * 64 + c0];
            float h0 = hs[(r0 + 0) * 132 + k];
            float h1 = hs[(r0 + 1) * 132 + k];
            acc0.x = fmaf(h0, w.x, acc0.x); acc0.y = fmaf(h0, w.y, acc0.y);
            acc0.z = fmaf(h0, w.z, acc0.z); acc0.w = fmaf(h0, w.w, acc0.w);
            acc1.x = fmaf(h1, w.x, acc1.x); acc1.y = fmaf(h1, w.y, acc1.y);
            acc1.z = fmaf(h1, w.z, acc1.z); acc1.w = fmaf(h1, w.w, acc1.w);
        }
        *(float4*)(A + (size_t)(row0 + r0 + 0) * 64 + c0) = acc0;
        *(float4*)(A + (size_t)(row0 + r0 + 1) * 64 + c0) = acc1;
    }
}

extern "C" void kernel_launch(void* const* d_in, const int* in_sizes, int n_in,
                              void* d_out, int out_size, void* d_ws, size_t ws_size,
                              hipStream_t stream) {
    const float* x  = (const float*)d_in[0];
    const float* W1 = (const float*)d_in[1];
    const float* b1 = (const float*)d_in[2];
    const float* W2 = (const float*)d_in[3];
    const float* b2 = (const float*)d_in[4];
    const int* src  = (const int*)d_in[5];
    const int* dst  = (const int*)d_in[6];
    float* out = (float*)d_out;

    const int nfeat = N_NODES * 64;
    const int nfeat4 = nfeat / 4;

    // workspace layout
    char* ws = (char*)d_ws;
    float* A    = (float*)ws;   ws += (size_t)nfeat * 4;            // 25.6 MB
    int* eb     = (int*)ws;     ws += (size_t)N_EDGES * 4;          // 6.4 MB
    int* bcnt   = (int*)ws;     ws += (size_t)NBUK * PAD * 4;       // 50 KB (padded)
    int* cursor = (int*)ws;     ws += (size_t)NBUK * PAD * 4;       // 50 KB (padded)
    int* boff   = (int*)ws;     ws += (size_t)(NBUK + 1) * 4;
    size_t need = (size_t)(ws - (char*)d_ws);

    if (ws_size >= need) {
        // ---- bucket build ----
        hipMemsetAsync(bcnt, 0, (size_t)NBUK * PAD * 4, stream);
        k_bhist<<<256, 256, 0, stream>>>(dst, bcnt);
        k_bscan<<<1, 1024, 0, stream>>>(bcnt, boff, cursor);
        k_bscatter<<<(N_EDGES + 255) / 256, 256, 0, stream>>>(src, dst, cursor, eb);

        // ---- layer 1 aggregate: A = segsum(x) ----
        k_bgather<<<NBUK, 256, 0, stream>>>(x, eb, boff, nullptr, A);
        // ---- MLP in place: A = relu(A*W1+b1)*W2 ----
        k_mlp<<<N_NODES / MROWS, 256, 0, stream>>>(A, W1, b1, W2);
        // ---- layer 2 aggregate + bias: out = b2 + segsum(A) ----
        k_bgather<<<NBUK, 256, 0, stream>>>(A, eb, boff, b2, out);
    } else {
        // fallback: atomic scatter path
        k_zero_f4<<<(nfeat4 + 255) / 256, 256, 0, stream>>>((float4*)A, nfeat4);
        int threads = N_EDGES * 16;
        k_scatter64<<<(threads + 255) / 256, 256, 0, stream>>>(x, src, dst, A);
        k_mlp<<<N_NODES / MROWS, 256, 0, stream>>>(A, W1, b1, W2);
        k_init_bias<<<(nfeat + 255) / 256, 256, 0, stream>>>(out, b2, nfeat);
        k_scatter64<<<(threads + 255) / 256, 256, 0, stream>>>(A, src, dst, out);
    }
}

// Round 6
// 355.606 us; speedup vs baseline: 4.4067x; 4.4067x over previous
//
#include <hip/hip_runtime.h>

#define N_NODES 100000
#define N_EDGES 1600000
#define IN_F 64
#define HID 128
#define N_CLS 64

#define SCAN_B 1024
#define NB ((N_NODES + SCAN_B - 1) / SCAN_B)   // 98

#define NPB 128                                // nodes per dst-bucket
#define NBUK ((N_NODES + NPB - 1) / NPB)       // 782
#define PAD 16                                 // ints per padded bucket cursor (64 B)

// ================= generic helpers =================
__global__ void k_zero_f4(float4* __restrict__ p, int n4) {
    int i = blockIdx.x * blockDim.x + threadIdx.x;
    if (i < n4) p[i] = make_float4(0.f, 0.f, 0.f, 0.f);
}
__global__ void k_zero_i(int* __restrict__ p, int n) {
    int i = blockIdx.x * blockDim.x + threadIdx.x;
    if (i < n) p[i] = 0;
}
__global__ void k_init_bias(float* __restrict__ out, const float* __restrict__ b2, int n) {
    int i = blockIdx.x * blockDim.x + threadIdx.x;
    if (i < n) out[i] = b2[i & 63];
}

// ================= node-degree histogram =================
__global__ void k_hist(const int* __restrict__ dst, int* __restrict__ deg) {
    int e = blockIdx.x * blockDim.x + threadIdx.x;
    if (e < N_EDGES) atomicAdd(&deg[dst[e]], 1);
}

// ================= two-level scan: deg -> off =================
__global__ __launch_bounds__(SCAN_B) void k_scan1(const int* __restrict__ deg,
                                                  int* __restrict__ off,
                                                  int* __restrict__ blockTot) {
    __shared__ int buf[2][SCAN_B];
    const int t = threadIdx.x;
    const int gid = blockIdx.x * SCAN_B + t;
    int v = (gid < N_NODES) ? deg[gid] : 0;
    buf[0][t] = v;
    __syncthreads();
    int cur = 0;
    for (int d = 1; d < SCAN_B; d <<= 1) {
        int x = buf[cur][t];
        if (t >= d) x += buf[cur][t - d];
        buf[cur ^ 1][t] = x;
        __syncthreads();
        cur ^= 1;
    }
    if (gid < N_NODES) off[gid] = buf[cur][t] - v;
    if (t == SCAN_B - 1) blockTot[blockIdx.x] = buf[cur][t];
}

__global__ __launch_bounds__(128) void k_scan2(const int* __restrict__ blockTot,
                                               int* __restrict__ blockOff) {
    __shared__ int buf[2][128];
    const int t = threadIdx.x;
    int v = (t < NB) ? blockTot[t] : 0;
    buf[0][t] = v;
    __syncthreads();
    int cur = 0;
    for (int d = 1; d < 128; d <<= 1) {
        int x = buf[cur][t];
        if (t >= d) x += buf[cur][t - d];
        buf[cur ^ 1][t] = x;
        __syncthreads();
        cur ^= 1;
    }
    if (t < NB) blockOff[t] = buf[cur][t] - v;
}

__global__ void k_scan3(int* __restrict__ off, const int* __restrict__ blockOff) {
    int i = blockIdx.x * blockDim.x + threadIdx.x;
    if (i < N_NODES) off[i] += blockOff[i >> 10];
    else if (i == N_NODES) off[N_NODES] = N_EDGES;
}

// ================= bucket cursors from off =================
__global__ void k_bcur(const int* __restrict__ off, int* __restrict__ cursor) {
    int b = blockIdx.x * blockDim.x + threadIdx.x;
    if (b < NBUK) {
        int n = b * NPB;
        cursor[b * PAD] = off[n];
    }
}

// scatter packed (dstLow<<17 | src) into bucket-ordered eb (782 dense streams)
__global__ void k_bscatter(const int* __restrict__ src, const int* __restrict__ dst,
                           int* __restrict__ cursor, int* __restrict__ eb) {
    int e = blockIdx.x * blockDim.x + threadIdx.x;
    if (e >= N_EDGES) return;
    int d = dst[e];
    int b = d >> 7;
    int pos = atomicAdd(&cursor[b * PAD], 1);
    eb[pos] = ((d & 127) << 17) | src[e];
}

// per-bucket: eb (bucket-ordered) -> es (node-sorted) via LDS cursors.
// All writes land in this bucket's contiguous window of es -> line-dense.
__global__ __launch_bounds__(256) void k_fill2(const int* __restrict__ eb,
                                               const int* __restrict__ off,
                                               int* __restrict__ es) {
    __shared__ int lcur[NPB];
    const int t = threadIdx.x;
    const int n0 = blockIdx.x * NPB;
    if (t < NPB) {
        int n = n0 + t;
        lcur[t] = (n < N_NODES) ? off[n] : 0;
    }
    __syncthreads();
    int hi = n0 + NPB; if (hi > N_NODES) hi = N_NODES;
    const int beg = off[n0], end = off[hi];
    for (int i = beg + t; i < end; i += 256) {
        int p = eb[i];
        int pos = atomicAdd(&lcur[p >> 17], 1);
        es[pos] = p & 0x1FFFF;
    }
}

// node-level fill (tier-2 fallback): random 4B writes
__global__ void k_fill(const int* __restrict__ src, const int* __restrict__ dst,
                       const int* __restrict__ off, int* __restrict__ cursor,
                       int* __restrict__ es) {
    int e = blockIdx.x * blockDim.x + threadIdx.x;
    if (e >= N_EDGES) return;
    int d = dst[e];
    int pos = atomicAdd(&cursor[d], 1);
    es[off[d] + pos] = src[e];
}

// ================= gather aggregation: one wave per node =================
__global__ __launch_bounds__(256) void k_gather(const float* __restrict__ feat,
                                                const int* __restrict__ es,
                                                const int* __restrict__ off,
                                                const float* __restrict__ bias,
                                                float* __restrict__ out) {
    const int wave = threadIdx.x >> 6;
    const int lane = threadIdx.x & 63;
    const int n = blockIdx.x * 4 + wave;
    if (n >= N_NODES) return;
    const int beg = off[n], end = off[n + 1];
    float acc = bias ? bias[lane] : 0.f;
    for (int base = beg; base < end; base += 64) {
        int m = end - base; if (m > 64) m = 64;
        int id = (lane < m) ? es[base + lane] : 0;
        int k = 0;
        for (; k + 4 <= m; k += 4) {
            int s0 = __shfl(id, k), s1 = __shfl(id, k + 1);
            int s2 = __shfl(id, k + 2), s3 = __shfl(id, k + 3);
            float v0 = feat[(size_t)s0 * 64 + lane];
            float v1 = feat[(size_t)s1 * 64 + lane];
            float v2 = feat[(size_t)s2 * 64 + lane];
            float v3 = feat[(size_t)s3 * 64 + lane];
            acc += (v0 + v1) + (v2 + v3);
        }
        for (; k < m; ++k) {
            int s = __shfl(id, k);
            acc += feat[(size_t)s * 64 + lane];
        }
    }
    out[(size_t)n * 64 + lane] = acc;
}

// ================= fallback atomic scatter (tier-3) =================
__global__ void k_scatter64(const float* __restrict__ feat,
                            const int* __restrict__ src,
                            const int* __restrict__ dst,
                            float* __restrict__ out) {
    int i = blockIdx.x * blockDim.x + threadIdx.x;
    int e = i >> 4;
    if (e >= N_EDGES) return;
    int j = (i & 15) << 2;
    int s = src[e];
    int d = dst[e];
    float4 v = *reinterpret_cast<const float4*>(feat + (size_t)s * 64 + j);
    float* o = out + (size_t)d * 64 + j;
    atomicAdd(o + 0, v.x);
    atomicAdd(o + 1, v.y);
    atomicAdd(o + 2, v.z);
    atomicAdd(o + 3, v.w);
}

// ================= fused MLP: Z = relu(A*W1 + b1) * W2, in-place, register-tiled =================
#define MROWS 32
__global__ __launch_bounds__(256, 2) void k_mlp(float* __restrict__ A,
                                                const float* __restrict__ W1,
                                                const float* __restrict__ b1,
                                                const float* __restrict__ W2) {
    __shared__ float Ws[64 * 128];
    __shared__ float xs[64 * 36];
    __shared__ float hs[32 * 132];
    __shared__ float b1s[128];
    const int t = threadIdx.x;
    const int row0 = blockIdx.x * MROWS;

    {
        const float4* w4 = (const float4*)W1;
        float4* s4 = (float4*)Ws;
        for (int i = t; i < 2048; i += 256) s4[i] = w4[i];
    }
    if (t < 128) b1s[t] = b1[t];
#pragma unroll
    for (int c = 0; c < 2; ++c) {
        int lin = t + c * 256;
        int r = lin >> 4;
        int k4 = lin & 15;
        float4 v = *(const float4*)(A + (size_t)(row0 + r) * 64 + k4 * 4);
        xs[(k4 * 4 + 0) * 36 + r] = v.x;
        xs[(k4 * 4 + 1) * 36 + r] = v.y;
        xs[(k4 * 4 + 2) * 36 + r] = v.z;
        xs[(k4 * 4 + 3) * 36 + r] = v.w;
    }
    __syncthreads();

    {
        const int rg = t >> 5, cg = t & 31;
        const int r0 = rg * 4, c0 = cg * 4;
        float4 bv = *(const float4*)&b1s[c0];
        float4 acc0 = bv, acc1 = bv, acc2 = bv, acc3 = bv;
#pragma unroll 8
        for (int k = 0; k < 64; ++k) {
            float4 w = *(const float4*)&Ws[k * 128 + c0];
            float4 a = *(const float4*)&xs[k * 36 + r0];
            acc0.x = fmaf(a.x, w.x, acc0.x); acc0.y = fmaf(a.x, w.y, acc0.y);
            acc0.z = fmaf(a.x, w.z, acc0.z); acc0.w = fmaf(a.x, w.w, acc0.w);
            acc1.x = fmaf(a.y, w.x, acc1.x); acc1.y = fmaf(a.y, w.y, acc1.y);
            acc1.z = fmaf(a.y, w.z, acc1.z); acc1.w = fmaf(a.y, w.w, acc1.w);
            acc2.x = fmaf(a.z, w.x, acc2.x); acc2.y = fmaf(a.z, w.y, acc2.y);
            acc2.z = fmaf(a.z, w.z, acc2.z); acc2.w = fmaf(a.z, w.w, acc2.w);
            acc3.x = fmaf(a.w, w.x, acc3.x); acc3.y = fmaf(a.w, w.y, acc3.y);
            acc3.z = fmaf(a.w, w.z, acc3.z); acc3.w = fmaf(a.w, w.w, acc3.w);
        }
        float4 h;
        h.x = fmaxf(acc0.x, 0.f); h.y = fmaxf(acc0.y, 0.f); h.z = fmaxf(acc0.z, 0.f); h.w = fmaxf(acc0.w, 0.f);
        *(float4*)&hs[(r0 + 0) * 132 + c0] = h;
        h.x = fmaxf(acc1.x, 0.f); h.y = fmaxf(acc1.y, 0.f); h.z = fmaxf(acc1.z, 0.f); h.w = fmaxf(acc1.w, 0.f);
        *(float4*)&hs[(r0 + 1) * 132 + c0] = h;
        h.x = fmaxf(acc2.x, 0.f); h.y = fmaxf(acc2.y, 0.f); h.z = fmaxf(acc2.z, 0.f); h.w = fmaxf(acc2.w, 0.f);
        *(float4*)&hs[(r0 + 2) * 132 + c0] = h;
        h.x = fmaxf(acc3.x, 0.f); h.y = fmaxf(acc3.y, 0.f); h.z = fmaxf(acc3.z, 0.f); h.w = fmaxf(acc3.w, 0.f);
        *(float4*)&hs[(r0 + 3) * 132 + c0] = h;
    }
    __syncthreads();

    {
        const float4* w4 = (const float4*)W2;
        float4* s4 = (float4*)Ws;
        for (int i = t; i < 2048; i += 256) s4[i] = w4[i];
    }
    __syncthreads();

    {
        const int rg = t >> 4, cg = t & 15;
        const int r0 = rg * 2, c0 = cg * 4;
        float4 acc0 = make_float4(0.f, 0.f, 0.f, 0.f);
        float4 acc1 = make_float4(0.f, 0.f, 0.f, 0.f);
#pragma unroll 8
        for (int k = 0; k < 128; ++k) {
            float4 w = *(const float4*)&Ws[k * 64 + c0];
            float h0 = hs[(r0 + 0) * 132 + k];
            float h1 = hs[(r0 + 1) * 132 + k];
            acc0.x = fmaf(h0, w.x, acc0.x); acc0.y = fmaf(h0, w.y, acc0.y);
            acc0.z = fmaf(h0, w.z, acc0.z); acc0.w = fmaf(h0, w.w, acc0.w);
            acc1.x = fmaf(h1, w.x, acc1.x); acc1.y = fmaf(h1, w.y, acc1.y);
            acc1.z = fmaf(h1, w.z, acc1.z); acc1.w = fmaf(h1, w.w, acc1.w);
        }
        *(float4*)(A + (size_t)(row0 + r0 + 0) * 64 + c0) = acc0;
        *(float4*)(A + (size_t)(row0 + r0 + 1) * 64 + c0) = acc1;
    }
}

extern "C" void kernel_launch(void* const* d_in, const int* in_sizes, int n_in,
                              void* d_out, int out_size, void* d_ws, size_t ws_size,
                              hipStream_t stream) {
    const float* x  = (const float*)d_in[0];
    const float* W1 = (const float*)d_in[1];
    const float* b1 = (const float*)d_in[2];
    const float* W2 = (const float*)d_in[3];
    const float* b2 = (const float*)d_in[4];
    const int* src  = (const int*)d_in[5];
    const int* dst  = (const int*)d_in[6];
    float* out = (float*)d_out;

    const int nfeat = N_NODES * 64;
    const int nfeat4 = nfeat / 4;

    // ---- tier-1 layout: two-stage fill (eb + es). deg aliases eb (dead after scan). ----
    char* ws = (char*)d_ws;
    float* A      = (float*)ws;  ws += (size_t)nfeat * 4;           // 25.6 MB
    int* eb       = (int*)ws;    ws += (size_t)N_EDGES * 4;         // 6.4 MB (deg aliases front)
    int* es       = (int*)ws;    ws += (size_t)N_EDGES * 4;         // 6.4 MB
    int* off      = (int*)ws;    ws += (size_t)(N_NODES + 1) * 4;
    int* cursor   = (int*)ws;    ws += (size_t)NBUK * PAD * 4;      // 50 KB
    int* blockTot = (int*)ws;    ws += (size_t)NB * 4;
    int* blockOff = (int*)ws;    ws += (size_t)NB * 4;
    size_t need1 = (size_t)(ws - (char*)d_ws);
    int* deg = eb;  // alias: deg used only before eb is written

    // ---- tier-2 layout: round-4 style single-stage fill ----
    char* w2p = (char*)d_ws;
    float* A2      = (float*)w2p;  w2p += (size_t)nfeat * 4;
    int* deg2      = (int*)w2p;    w2p += (size_t)N_NODES * 4;
    int* cursor2   = (int*)w2p;    w2p += (size_t)N_NODES * 4;
    int* off2      = (int*)w2p;    w2p += (size_t)(N_NODES + 1) * 4;
    int* es2       = (int*)w2p;    w2p += (size_t)N_EDGES * 4;
    int* blockTot2 = (int*)w2p;    w2p += (size_t)NB * 4;
    int* blockOff2 = (int*)w2p;    w2p += (size_t)NB * 4;
    size_t need2 = (size_t)(w2p - (char*)d_ws);

    if (ws_size >= need1) {
        // ---- CSR build, write-local ----
        k_zero_i<<<(N_NODES + 255) / 256, 256, 0, stream>>>(deg, N_NODES);
        k_hist<<<(N_EDGES + 255) / 256, 256, 0, stream>>>(dst, deg);
        k_scan1<<<NB, SCAN_B, 0, stream>>>(deg, off, blockTot);
        k_scan2<<<1, 128, 0, stream>>>(blockTot, blockOff);
        k_scan3<<<(N_NODES + 1 + 1023) / 1024, 1024, 0, stream>>>(off, blockOff);
        k_bcur<<<(NBUK + 255) / 256, 256, 0, stream>>>(off, cursor);
        k_bscatter<<<(N_EDGES + 255) / 256, 256, 0, stream>>>(src, dst, cursor, eb);
        k_fill2<<<NBUK, 256, 0, stream>>>(eb, off, es);

        // ---- layer 1 aggregate: A = segsum(x) ----
        k_gather<<<(N_NODES + 3) / 4, 256, 0, stream>>>(x, es, off, nullptr, A);
        // ---- MLP in place ----
        k_mlp<<<N_NODES / MROWS, 256, 0, stream>>>(A, W1, b1, W2);
        // ---- layer 2 aggregate + bias ----
        k_gather<<<(N_NODES + 3) / 4, 256, 0, stream>>>(A, es, off, b2, out);
    } else if (ws_size >= need2) {
        // ---- round-4 proven path ----
        k_zero_i<<<(2 * N_NODES + 255) / 256, 256, 0, stream>>>(deg2, 2 * N_NODES);
        k_hist<<<(N_EDGES + 255) / 256, 256, 0, stream>>>(dst, deg2);
        k_scan1<<<NB, SCAN_B, 0, stream>>>(deg2, off2, blockTot2);
        k_scan2<<<1, 128, 0, stream>>>(blockTot2, blockOff2);
        k_scan3<<<(N_NODES + 1 + 1023) / 1024, 1024, 0, stream>>>(off2, blockOff2);
        k_fill<<<(N_EDGES + 255) / 256, 256, 0, stream>>>(src, dst, off2, cursor2, es2);

        k_gather<<<(N_NODES + 3) / 4, 256, 0, stream>>>(x, es2, off2, nullptr, A2);
        k_mlp<<<N_NODES / MROWS, 256, 0, stream>>>(A2, W1, b1, W2);
        k_gather<<<(N_NODES + 3) / 4, 256, 0, stream>>>(A2, es2, off2, b2, out);
    } else {
        // ---- tier-3: atomic scatter ----
        k_zero_f4<<<(nfeat4 + 255) / 256, 256, 0, stream>>>((float4*)A, nfeat4);
        int threads = N_EDGES * 16;
        k_scatter64<<<(threads + 255) / 256, 256, 0, stream>>>(x, src, dst, A);
        k_mlp<<<N_NODES / MROWS, 256, 0, stream>>>(A, W1, b1, W2);
        k_init_bias<<<(nfeat + 255) / 256, 256, 0, stream>>>(out, b2, nfeat);
        k_scatter64<<<(threads + 255) / 256, 256, 0, stream>>>(A, src, dst, out);
    }
}

// Round 7
// 267.947 us; speedup vs baseline: 5.8483x; 1.3271x over previous
//
#include <hip/hip_runtime.h>

#define N_NODES 100000
#define N_EDGES 1600000
#define IN_F 64
#define HID 128
#define N_CLS 64

#define NPB2 2048                               // nodes per coarse bucket (d >> 11)
#define NBK2 ((N_NODES + NPB2 - 1) / NPB2)      // 49
#define PAD 16                                  // ints per padded global counter (64 B)
#define PCHUNK 8192                             // edges per k_part block
#define NPBLK ((N_EDGES + PCHUNK - 1) / PCHUNK) // 196

// ================= generic helpers =================
__global__ void k_zero_f4(float4* __restrict__ p, int n4) {
    int i = blockIdx.x * blockDim.x + threadIdx.x;
    if (i < n4) p[i] = make_float4(0.f, 0.f, 0.f, 0.f);
}
__global__ void k_init_bias(float* __restrict__ out, const float* __restrict__ b2, int n) {
    int i = blockIdx.x * blockDim.x + threadIdx.x;
    if (i < n) out[i] = b2[i & 63];
}

// ================= coarse bucket histogram (LDS-staged) =================
__global__ __launch_bounds__(256) void k_bhist(const int* __restrict__ dst,
                                               int* __restrict__ bcnt) {
    __shared__ int h[NBK2];
    for (int i = threadIdx.x; i < NBK2; i += 256) h[i] = 0;
    __syncthreads();
    int stride = gridDim.x * blockDim.x;
    for (int e = blockIdx.x * blockDim.x + threadIdx.x; e < N_EDGES; e += stride)
        atomicAdd(&h[dst[e] >> 11], 1);
    __syncthreads();
    for (int i = threadIdx.x; i < NBK2; i += 256) {
        int v = h[i];
        if (v) atomicAdd(&bcnt[i * PAD], v);
    }
}

// scan 49 bucket counts -> boff[NBK2+1]; seed padded global cursors
__global__ __launch_bounds__(64) void k_bscan(const int* __restrict__ bcnt,
                                              int* __restrict__ boff,
                                              int* __restrict__ gcur) {
    __shared__ int s[NBK2];
    const int t = threadIdx.x;
    if (t < NBK2) s[t] = bcnt[t * PAD];
    __syncthreads();
    if (t == 0) {
        int run = 0;
        for (int i = 0; i < NBK2; ++i) { int v = s[i]; s[i] = run; run += v; }
    }
    __syncthreads();
    if (t < NBK2) { boff[t] = s[t]; gcur[t * PAD] = s[t]; }
    if (t == 0) boff[NBK2] = N_EDGES;
}

// ================= block-aggregated partition into coarse buckets =================
// Each block owns its output runs exclusively -> line-dense writes, no XCD bouncing.
__global__ __launch_bounds__(256) void k_part(const int* __restrict__ src,
                                              const int* __restrict__ dst,
                                              int* __restrict__ gcur,
                                              int* __restrict__ eb) {
    __shared__ int hist[NBK2];
    __shared__ int gbase[NBK2];
    __shared__ int lcur[NBK2];
    const int t = threadIdx.x;
    const int e0 = blockIdx.x * PCHUNK;
    int e1 = e0 + PCHUNK; if (e1 > N_EDGES) e1 = N_EDGES;
    for (int i = t; i < NBK2; i += 256) hist[i] = 0;
    __syncthreads();
    for (int e = e0 + t; e < e1; e += 256) atomicAdd(&hist[dst[e] >> 11], 1);
    __syncthreads();
    if (t < NBK2) {
        int c = hist[t];
        gbase[t] = c ? atomicAdd(&gcur[t * PAD], c) : 0;
        lcur[t] = 0;
    }
    __syncthreads();
    for (int e = e0 + t; e < e1; e += 256) {
        int d = dst[e];
        int b = d >> 11;
        int r = atomicAdd(&lcur[b], 1);
        eb[gbase[b] + r] = ((d & 2047) << 17) | src[e];   // dstLow(11b) | src(17b)
    }
}

// ================= per-bucket: node-degree hist + scan -> off; sort -> es =================
__global__ __launch_bounds__(1024) void k_fill3(const int* __restrict__ eb,
                                                const int* __restrict__ boff,
                                                int* __restrict__ off,
                                                int* __restrict__ es) {
    __shared__ int ldeg[NPB2];
    __shared__ int lofs[NPB2];
    __shared__ int sc[2][1024];
    const int t = threadIdx.x;
    const int b = blockIdx.x;
    const int bbase = boff[b], bend = boff[b + 1];

    ldeg[t] = 0; ldeg[t + 1024] = 0;
    __syncthreads();
    for (int i = bbase + t; i < bend; i += 1024) atomicAdd(&ldeg[eb[i] >> 17], 1);
    __syncthreads();

    // exclusive scan of 2048 degrees (pairs per thread)
    int a0 = ldeg[2 * t], a1 = ldeg[2 * t + 1];
    int s = a0 + a1;
    sc[0][t] = s;
    __syncthreads();
    int cur = 0;
    for (int d = 1; d < 1024; d <<= 1) {
        int v = sc[cur][t];
        if (t >= d) v += sc[cur][t - d];
        sc[cur ^ 1][t] = v;
        __syncthreads();
        cur ^= 1;
    }
    int ex = sc[cur][t] - s;
    lofs[2 * t] = ex;
    lofs[2 * t + 1] = ex + a0;
    __syncthreads();

    // emit node-level CSR offsets for this bucket
    const int n0 = b * NPB2;
    int cnt = N_NODES - n0; if (cnt > NPB2) cnt = NPB2;
    if (t < cnt) off[n0 + t] = bbase + lofs[t];
    if (t + 1024 < cnt) off[n0 + t + 1024] = bbase + lofs[t + 1024];
    if (b == NBK2 - 1 && t == 0) off[N_NODES] = N_EDGES;
    __syncthreads();

    // scatter into node-sorted es within this bucket's private window
    for (int i = bbase + t; i < bend; i += 1024) {
        int p = eb[i];
        int r = atomicAdd(&lofs[p >> 17], 1);
        es[bbase + r] = p & 0x1FFFF;
    }
}

// ================= gather aggregation: one wave per node =================
__global__ __launch_bounds__(256) void k_gather(const float* __restrict__ feat,
                                                const int* __restrict__ es,
                                                const int* __restrict__ off,
                                                const float* __restrict__ bias,
                                                float* __restrict__ out) {
    const int wave = threadIdx.x >> 6;
    const int lane = threadIdx.x & 63;
    const int n = blockIdx.x * 4 + wave;
    if (n >= N_NODES) return;
    const int beg = off[n], end = off[n + 1];
    float acc = bias ? bias[lane] : 0.f;
    for (int base = beg; base < end; base += 64) {
        int m = end - base; if (m > 64) m = 64;
        int id = (lane < m) ? es[base + lane] : 0;
        int k = 0;
        for (; k + 4 <= m; k += 4) {
            int s0 = __shfl(id, k), s1 = __shfl(id, k + 1);
            int s2 = __shfl(id, k + 2), s3 = __shfl(id, k + 3);
            float v0 = feat[(size_t)s0 * 64 + lane];
            float v1 = feat[(size_t)s1 * 64 + lane];
            float v2 = feat[(size_t)s2 * 64 + lane];
            float v3 = feat[(size_t)s3 * 64 + lane];
            acc += (v0 + v1) + (v2 + v3);
        }
        for (; k < m; ++k) {
            int s = __shfl(id, k);
            acc += feat[(size_t)s * 64 + lane];
        }
    }
    out[(size_t)n * 64 + lane] = acc;
}

// ================= fallback atomic scatter =================
__global__ void k_scatter64(const float* __restrict__ feat,
                            const int* __restrict__ src,
                            const int* __restrict__ dst,
                            float* __restrict__ out) {
    int i = blockIdx.x * blockDim.x + threadIdx.x;
    int e = i >> 4;
    if (e >= N_EDGES) return;
    int j = (i & 15) << 2;
    int s = src[e];
    int d = dst[e];
    float4 v = *reinterpret_cast<const float4*>(feat + (size_t)s * 64 + j);
    float* o = out + (size_t)d * 64 + j;
    atomicAdd(o + 0, v.x);
    atomicAdd(o + 1, v.y);
    atomicAdd(o + 2, v.z);
    atomicAdd(o + 3, v.w);
}

// ================= fused MLP: Z = relu(A*W1 + b1) * W2, in-place, register-tiled =================
#define MROWS 32
__global__ __launch_bounds__(256, 2) void k_mlp(float* __restrict__ A,
                                                const float* __restrict__ W1,
                                                const float* __restrict__ b1,
                                                const float* __restrict__ W2) {
    __shared__ float Ws[64 * 128];
    __shared__ float xs[64 * 36];
    __shared__ float hs[32 * 132];
    __shared__ float b1s[128];
    const int t = threadIdx.x;
    const int row0 = blockIdx.x * MROWS;

    {
        const float4* w4 = (const float4*)W1;
        float4* s4 = (float4*)Ws;
        for (int i = t; i < 2048; i += 256) s4[i] = w4[i];
    }
    if (t < 128) b1s[t] = b1[t];
#pragma unroll
    for (int c = 0; c < 2; ++c) {
        int lin = t + c * 256;
        int r = lin >> 4;
        int k4 = lin & 15;
        float4 v = *(const float4*)(A + (size_t)(row0 + r) * 64 + k4 * 4);
        xs[(k4 * 4 + 0) * 36 + r] = v.x;
        xs[(k4 * 4 + 1) * 36 + r] = v.y;
        xs[(k4 * 4 + 2) * 36 + r] = v.z;
        xs[(k4 * 4 + 3) * 36 + r] = v.w;
    }
    __syncthreads();

    {
        const int rg = t >> 5, cg = t & 31;
        const int r0 = rg * 4, c0 = cg * 4;
        float4 bv = *(const float4*)&b1s[c0];
        float4 acc0 = bv, acc1 = bv, acc2 = bv, acc3 = bv;
#pragma unroll 8
        for (int k = 0; k < 64; ++k) {
            float4 w = *(const float4*)&Ws[k * 128 + c0];
            float4 a = *(const float4*)&xs[k * 36 + r0];
            acc0.x = fmaf(a.x, w.x, acc0.x); acc0.y = fmaf(a.x, w.y, acc0.y);
            acc0.z = fmaf(a.x, w.z, acc0.z); acc0.w = fmaf(a.x, w.w, acc0.w);
            acc1.x = fmaf(a.y, w.x, acc1.x); acc1.y = fmaf(a.y, w.y, acc1.y);
            acc1.z = fmaf(a.y, w.z, acc1.z); acc1.w = fmaf(a.y, w.w, acc1.w);
            acc2.x = fmaf(a.z, w.x, acc2.x); acc2.y = fmaf(a.z, w.y, acc2.y);
            acc2.z = fmaf(a.z, w.z, acc2.z); acc2.w = fmaf(a.z, w.w, acc2.w);
            acc3.x = fmaf(a.w, w.x, acc3.x); acc3.y = fmaf(a.w, w.y, acc3.y);
            acc3.z = fmaf(a.w, w.z, acc3.z); acc3.w = fmaf(a.w, w.w, acc3.w);
        }
        float4 h;
        h.x = fmaxf(acc0.x, 0.f); h.y = fmaxf(acc0.y, 0.f); h.z = fmaxf(acc0.z, 0.f); h.w = fmaxf(acc0.w, 0.f);
        *(float4*)&hs[(r0 + 0) * 132 + c0] = h;
        h.x = fmaxf(acc1.x, 0.f); h.y = fmaxf(acc1.y, 0.f); h.z = fmaxf(acc1.z, 0.f); h.w = fmaxf(acc1.w, 0.f);
        *(float4*)&hs[(r0 + 1) * 132 + c0] = h;
        h.x = fmaxf(acc2.x, 0.f); h.y = fmaxf(acc2.y, 0.f); h.z = fmaxf(acc2.z, 0.f); h.w = fmaxf(acc2.w, 0.f);
        *(float4*)&hs[(r0 + 2) * 132 + c0] = h;
        h.x = fmaxf(acc3.x, 0.f); h.y = fmaxf(acc3.y, 0.f); h.z = fmaxf(acc3.z, 0.f); h.w = fmaxf(acc3.w, 0.f);
        *(float4*)&hs[(r0 + 3) * 132 + c0] = h;
    }
    __syncthreads();

    {
        const float4* w4 = (const float4*)W2;
        float4* s4 = (float4*)Ws;
        for (int i = t; i < 2048; i += 256) s4[i] = w4[i];
    }
    __syncthreads();

    {
        const int rg = t >> 4, cg = t & 15;
        const int r0 = rg * 2, c0 = cg * 4;
        float4 acc0 = make_float4(0.f, 0.f, 0.f, 0.f);
        float4 acc1 = make_float4(0.f, 0.f, 0.f, 0.f);
#pragma unroll 8
        for (int k = 0; k < 128; ++k) {
            float4 w = *(const float4*)&Ws[k * 64 + c0];
            float h0 = hs[(r0 + 0) * 132 + k];
            float h1 = hs[(r0 + 1) * 132 + k];
            acc0.x = fmaf(h0, w.x, acc0.x); acc0.y = fmaf(h0, w.y, acc0.y);
            acc0.z = fmaf(h0, w.z, acc0.z); acc0.w = fmaf(h0, w.w, acc0.w);
            acc1.x = fmaf(h1, w.x, acc1.x); acc1.y = fmaf(h1, w.y, acc1.y);
            acc1.z = fmaf(h1, w.z, acc1.z); acc1.w = fmaf(h1, w.w, acc1.w);
        }
        *(float4*)(A + (size_t)(row0 + r0 + 0) * 64 + c0) = acc0;
        *(float4*)(A + (size_t)(row0 + r0 + 1) * 64 + c0) = acc1;
    }
}

extern "C" void kernel_launch(void* const* d_in, const int* in_sizes, int n_in,
                              void* d_out, int out_size, void* d_ws, size_t ws_size,
                              hipStream_t stream) {
    const float* x  = (const float*)d_in[0];
    const float* W1 = (const float*)d_in[1];
    const float* b1 = (const float*)d_in[2];
    const float* W2 = (const float*)d_in[3];
    const float* b2 = (const float*)d_in[4];
    const int* src  = (const int*)d_in[5];
    const int* dst  = (const int*)d_in[6];
    float* out = (float*)d_out;

    const int nfeat = N_NODES * 64;
    const int nfeat4 = nfeat / 4;

    // workspace layout
    char* ws = (char*)d_ws;
    float* A    = (float*)ws;  ws += (size_t)nfeat * 4;            // 25.6 MB
    int* eb     = (int*)ws;    ws += (size_t)N_EDGES * 4;          // 6.4 MB
    int* es     = (int*)ws;    ws += (size_t)N_EDGES * 4;          // 6.4 MB
    int* off    = (int*)ws;    ws += (size_t)(N_NODES + 1) * 4;    // 400 KB
    int* bcnt   = (int*)ws;    ws += (size_t)NBK2 * PAD * 4;       // ~3 KB
    int* gcur   = (int*)ws;    ws += (size_t)NBK2 * PAD * 4;       // ~3 KB
    int* boff   = (int*)ws;    ws += (size_t)(NBK2 + 1) * 4;
    size_t need = (size_t)(ws - (char*)d_ws);

    if (ws_size >= need) {
        // ---- CSR build (block-aggregated two-stage partition) ----
        hipMemsetAsync(bcnt, 0, (size_t)NBK2 * PAD * 4, stream);
        k_bhist<<<512, 256, 0, stream>>>(dst, bcnt);
        k_bscan<<<1, 64, 0, stream>>>(bcnt, boff, gcur);
        k_part<<<NPBLK, 256, 0, stream>>>(src, dst, gcur, eb);
        k_fill3<<<NBK2, 1024, 0, stream>>>(eb, boff, off, es);

        // ---- layer 1 aggregate: A = segsum(x) ----
        k_gather<<<(N_NODES + 3) / 4, 256, 0, stream>>>(x, es, off, nullptr, A);
        // ---- MLP in place: A = relu(A*W1+b1)*W2 ----
        k_mlp<<<N_NODES / MROWS, 256, 0, stream>>>(A, W1, b1, W2);
        // ---- layer 2 aggregate + bias: out = b2 + segsum(A) ----
        k_gather<<<(N_NODES + 3) / 4, 256, 0, stream>>>(A, es, off, b2, out);
    } else {
        // ---- fallback: atomic scatter ----
        k_zero_f4<<<(nfeat4 + 255) / 256, 256, 0, stream>>>((float4*)A, nfeat4);
        int threads = N_EDGES * 16;
        k_scatter64<<<(threads + 255) / 256, 256, 0, stream>>>(x, src, dst, A);
        k_mlp<<<N_NODES / MROWS, 256, 0, stream>>>(A, W1, b1, W2);
        k_init_bias<<<(nfeat + 255) / 256, 256, 0, stream>>>(out, b2, nfeat);
        k_scatter64<<<(threads + 255) / 256, 256, 0, stream>>>(A, src, dst, out);
    }
}

// Round 9
// 252.183 us; speedup vs baseline: 6.2139x; 1.0625x over previous
//
#include <hip/hip_runtime.h>

#define N_NODES 100000
#define N_EDGES 1600000
#define IN_F 64
#define HID 128
#define N_CLS 64

#define NPB2 512                                // nodes per coarse bucket (d >> 9)
#define NBK2 ((N_NODES + NPB2 - 1) / NPB2)      // 196
#define PAD 16                                  // ints per padded global counter (64 B)
#define PCHUNK 8192                             // edges per k_part block
#define NPBLK ((N_EDGES + PCHUNK - 1) / PCHUNK) // 196

// ================= generic helpers =================
__global__ void k_zero_f4(float4* __restrict__ p, int n4) {
    int i = blockIdx.x * blockDim.x + threadIdx.x;
    if (i < n4) p[i] = make_float4(0.f, 0.f, 0.f, 0.f);
}
__global__ void k_init_bias(float* __restrict__ out, const float* __restrict__ b2, int n) {
    int i = blockIdx.x * blockDim.x + threadIdx.x;
    if (i < n) out[i] = b2[i & 63];
}

// ================= coarse bucket histogram (LDS-staged) =================
__global__ __launch_bounds__(256) void k_bhist(const int* __restrict__ dst,
                                               int* __restrict__ bcnt) {
    __shared__ int h[NBK2];
    for (int i = threadIdx.x; i < NBK2; i += 256) h[i] = 0;
    __syncthreads();
    int stride = gridDim.x * blockDim.x;
    for (int e = blockIdx.x * blockDim.x + threadIdx.x; e < N_EDGES; e += stride)
        atomicAdd(&h[dst[e] >> 9], 1);
    __syncthreads();
    for (int i = threadIdx.x; i < NBK2; i += 256) {
        int v = h[i];
        if (v) atomicAdd(&bcnt[i * PAD], v);
    }
}

// scan NBK2 bucket counts -> boff[NBK2+1]; seed padded global cursors
__global__ __launch_bounds__(256) void k_bscan(const int* __restrict__ bcnt,
                                               int* __restrict__ boff,
                                               int* __restrict__ gcur) {
    __shared__ int s[NBK2];
    const int t = threadIdx.x;
    if (t < NBK2) s[t] = bcnt[t * PAD];
    __syncthreads();
    if (t == 0) {
        int run = 0;
        for (int i = 0; i < NBK2; ++i) { int v = s[i]; s[i] = run; run += v; }
    }
    __syncthreads();
    if (t < NBK2) { boff[t] = s[t]; gcur[t * PAD] = s[t]; }
    if (t == 0) boff[NBK2] = N_EDGES;
}

// ================= block-aggregated partition into coarse buckets =================
__global__ __launch_bounds__(256) void k_part(const int* __restrict__ src,
                                              const int* __restrict__ dst,
                                              int* __restrict__ gcur,
                                              int* __restrict__ eb) {
    __shared__ int hist[NBK2];
    __shared__ int gbase[NBK2];
    __shared__ int lcur[NBK2];
    const int t = threadIdx.x;
    const int e0 = blockIdx.x * PCHUNK;
    int e1 = e0 + PCHUNK; if (e1 > N_EDGES) e1 = N_EDGES;
    for (int i = t; i < NBK2; i += 256) hist[i] = 0;
    __syncthreads();
    for (int e = e0 + t; e < e1; e += 256) atomicAdd(&hist[dst[e] >> 9], 1);
    __syncthreads();
    if (t < NBK2) {
        int c = hist[t];
        gbase[t] = c ? atomicAdd(&gcur[t * PAD], c) : 0;
        lcur[t] = 0;
    }
    __syncthreads();
    for (int e = e0 + t; e < e1; e += 256) {
        int d = dst[e];
        int b = d >> 9;
        int r = atomicAdd(&lcur[b], 1);
        eb[gbase[b] + r] = ((d & 511) << 17) | src[e];   // dstLow(9b) | src(17b)
    }
}

// ================= per-bucket: node-degree hist + scan -> off; sort -> es =================
__global__ __launch_bounds__(512) void k_fill3(const int* __restrict__ eb,
                                               const int* __restrict__ boff,
                                               int* __restrict__ off,
                                               int* __restrict__ es) {
    __shared__ int ldeg[NPB2];
    __shared__ int sc[2][NPB2];
    const int t = threadIdx.x;
    const int b = blockIdx.x;
    const int bbase = boff[b], bend = boff[b + 1];

    ldeg[t] = 0;
    __syncthreads();
    for (int i = bbase + t; i < bend; i += 512) atomicAdd(&ldeg[eb[i] >> 17], 1);
    __syncthreads();

    int v = ldeg[t];
    sc[0][t] = v;
    __syncthreads();
    int cur = 0;
    for (int d = 1; d < NPB2; d <<= 1) {
        int x = sc[cur][t];
        if (t >= d) x += sc[cur][t - d];
        sc[cur ^ 1][t] = x;
        __syncthreads();
        cur ^= 1;
    }
    int ex = sc[cur][t] - v;                 // exclusive prefix within bucket

    const int n0 = b * NPB2;
    if (n0 + t < N_NODES) off[n0 + t] = bbase + ex;
    if (b == NBK2 - 1 && t == 0) off[N_NODES] = N_EDGES;

    ldeg[t] = ex;                            // reuse as cursor
    __syncthreads();

    for (int i = bbase + t; i < bend; i += 512) {
        int p = eb[i];
        int r = atomicAdd(&ldeg[p >> 17], 1);
        es[bbase + r] = p & 0x1FFFF;
    }
}

// ================= gather aggregation: one wave per node =================
__global__ __launch_bounds__(256) void k_gather(const float* __restrict__ feat,
                                                const int* __restrict__ es,
                                                const int* __restrict__ off,
                                                const float* __restrict__ bias,
                                                float* __restrict__ out) {
    const int wave = threadIdx.x >> 6;
    const int lane = threadIdx.x & 63;
    const int n = blockIdx.x * 4 + wave;
    if (n >= N_NODES) return;
    const int beg = off[n], end = off[n + 1];
    float acc = bias ? bias[lane] : 0.f;
    for (int base = beg; base < end; base += 64) {
        int m = end - base; if (m > 64) m = 64;
        int id = (lane < m) ? es[base + lane] : 0;
        int k = 0;
        for (; k + 4 <= m; k += 4) {
            int s0 = __shfl(id, k), s1 = __shfl(id, k + 1);
            int s2 = __shfl(id, k + 2), s3 = __shfl(id, k + 3);
            float v0 = feat[(size_t)s0 * 64 + lane];
            float v1 = feat[(size_t)s1 * 64 + lane];
            float v2 = feat[(size_t)s2 * 64 + lane];
            float v3 = feat[(size_t)s3 * 64 + lane];
            acc += (v0 + v1) + (v2 + v3);
        }
        for (; k < m; ++k) {
            int s = __shfl(id, k);
            acc += feat[(size_t)s * 64 + lane];
        }
    }
    out[(size_t)n * 64 + lane] = acc;
}

// ================= fallback atomic scatter =================
__global__ void k_scatter64(const float* __restrict__ feat,
                            const int* __restrict__ src,
                            const int* __restrict__ dst,
                            float* __restrict__ out) {
    int i = blockIdx.x * blockDim.x + threadIdx.x;
    int e = i >> 4;
    if (e >= N_EDGES) return;
    int j = (i & 15) << 2;
    int s = src[e];
    int d = dst[e];
    float4 v = *reinterpret_cast<const float4*>(feat + (size_t)s * 64 + j);
    float* o = out + (size_t)d * 64 + j;
    atomicAdd(o + 0, v.x);
    atomicAdd(o + 1, v.y);
    atomicAdd(o + 2, v.z);
    atomicAdd(o + 3, v.w);
}

// ================= fused MLP: Z = relu(A*W1 + b1) * W2, in-place =================
// Conflict-free: x staged row-major [32][68]; a-reads are wave-broadcast float4s.
#define MROWS 32
#define XS_S 68
#define HS_S 132

__device__ __forceinline__ void fma4(float4& a, float s, const float4& wv) {
    a.x = fmaf(s, wv.x, a.x);
    a.y = fmaf(s, wv.y, a.y);
    a.z = fmaf(s, wv.z, a.z);
    a.w = fmaf(s, wv.w, a.w);
}

__global__ __launch_bounds__(256, 2) void k_mlp(float* __restrict__ A,
                                                const float* __restrict__ W1,
                                                const float* __restrict__ b1,
                                                const float* __restrict__ W2) {
    __shared__ float Ws[64 * 128];          // 32 KB: W1 then W2
    __shared__ float xs[MROWS * XS_S];      // 8.7 KB row-major, stride 68 (16B aligned rows)
    __shared__ float hs[MROWS * HS_S];      // 16.9 KB row-major, stride 132
    __shared__ float b1s[128];
    const int t = threadIdx.x;
    const int row0 = blockIdx.x * MROWS;

    // stage W1 (2048 float4)
    {
        const float4* w4 = (const float4*)W1;
        float4* s4 = (float4*)Ws;
        for (int i = t; i < 2048; i += 256) s4[i] = w4[i];
    }
    if (t < 128) b1s[t] = b1[t];
    // stage x row-major: 512 float4s
#pragma unroll
    for (int c = 0; c < 2; ++c) {
        int lin = t + c * 256;               // 0..511
        int r = lin >> 4;                    // 0..31
        int k4 = lin & 15;                   // 0..15
        float4 v = *(const float4*)(A + (size_t)(row0 + r) * 64 + k4 * 4);
        *(float4*)&xs[r * XS_S + k4 * 4] = v;
    }
    __syncthreads();

    // ---- phase 1: h = relu(x*W1 + b1), 4 rows x 4 cols per thread ----
    {
        const int rg = t >> 5, cg = t & 31;
        const int r0 = rg * 4, c0 = cg * 4;
        float4 bv = *(const float4*)&b1s[c0];
        float4 acc0 = bv, acc1 = bv, acc2 = bv, acc3 = bv;
#pragma unroll 4
        for (int k4 = 0; k4 < 16; ++k4) {
            float4 a0 = *(const float4*)&xs[(r0 + 0) * XS_S + k4 * 4];
            float4 a1 = *(const float4*)&xs[(r0 + 1) * XS_S + k4 * 4];
            float4 a2 = *(const float4*)&xs[(r0 + 2) * XS_S + k4 * 4];
            float4 a3 = *(const float4*)&xs[(r0 + 3) * XS_S + k4 * 4];
            float4 w0 = *(const float4*)&Ws[(k4 * 4 + 0) * 128 + c0];
            float4 w1 = *(const float4*)&Ws[(k4 * 4 + 1) * 128 + c0];
            float4 w2 = *(const float4*)&Ws[(k4 * 4 + 2) * 128 + c0];
            float4 w3 = *(const float4*)&Ws[(k4 * 4 + 3) * 128 + c0];
            fma4(acc0, a0.x, w0); fma4(acc0, a0.y, w1); fma4(acc0, a0.z, w2); fma4(acc0, a0.w, w3);
            fma4(acc1, a1.x, w0); fma4(acc1, a1.y, w1); fma4(acc1, a1.z, w2); fma4(acc1, a1.w, w3);
            fma4(acc2, a2.x, w0); fma4(acc2, a2.y, w1); fma4(acc2, a2.z, w2); fma4(acc2, a2.w, w3);
            fma4(acc3, a3.x, w0); fma4(acc3, a3.y, w1); fma4(acc3, a3.z, w2); fma4(acc3, a3.w, w3);
        }
        float4 h;
        h.x = fmaxf(acc0.x, 0.f); h.y = fmaxf(acc0.y, 0.f); h.z = fmaxf(acc0.z, 0.f); h.w = fmaxf(acc0.w, 0.f);
        *(float4*)&hs[(r0 + 0) * HS_S + c0] = h;
        h.x = fmaxf(acc1.x, 0.f); h.y = fmaxf(acc1.y, 0.f); h.z = fmaxf(acc1.z, 0.f); h.w = fmaxf(acc1.w, 0.f);
        *(float4*)&hs[(r0 + 1) * HS_S + c0] = h;
        h.x = fmaxf(acc2.x, 0.f); h.y = fmaxf(acc2.y, 0.f); h.z = fmaxf(acc2.z, 0.f); h.w = fmaxf(acc2.w, 0.f);
        *(float4*)&hs[(r0 + 2) * HS_S + c0] = h;
        h.x = fmaxf(acc3.x, 0.f); h.y = fmaxf(acc3.y, 0.f); h.z = fmaxf(acc3.z, 0.f); h.w = fmaxf(acc3.w, 0.f);
        *(float4*)&hs[(r0 + 3) * HS_S + c0] = h;
    }
    __syncthreads();

    // stage W2 into the same LDS buffer
    {
        const float4* w4 = (const float4*)W2;
        float4* s4 = (float4*)Ws;
        for (int i = t; i < 2048; i += 256) s4[i] = w4[i];
    }
    __syncthreads();

    // ---- phase 2: z = h*W2, 2 rows x 4 cols per thread ----
    {
        const int rg = t >> 4, cg = t & 15;
        const int r0 = rg * 2, c0 = cg * 4;
        float4 acc0 = make_float4(0.f, 0.f, 0.f, 0.f);
        float4 acc1 = make_float4(0.f, 0.f, 0.f, 0.f);
#pragma unroll 4
        for (int k4 = 0; k4 < 32; ++k4) {
            float4 h0 = *(const float4*)&hs[(r0 + 0) * HS_S + k4 * 4];
            float4 h1 = *(const float4*)&hs[(r0 + 1) * HS_S + k4 * 4];
            float4 w0 = *(const float4*)&Ws[(k4 * 4 + 0) * 64 + c0];
            float4 w1 = *(const float4*)&Ws[(k4 * 4 + 1) * 64 + c0];
            float4 w2 = *(const float4*)&Ws[(k4 * 4 + 2) * 64 + c0];
            float4 w3 = *(const float4*)&Ws[(k4 * 4 + 3) * 64 + c0];
            fma4(acc0, h0.x, w0); fma4(acc0, h0.y, w1); fma4(acc0, h0.z, w2); fma4(acc0, h0.w, w3);
            fma4(acc1, h1.x, w0); fma4(acc1, h1.y, w1); fma4(acc1, h1.z, w2); fma4(acc1, h1.w, w3);
        }
        *(float4*)(A + (size_t)(row0 + r0 + 0) * 64 + c0) = acc0;
        *(float4*)(A + (size_t)(row0 + r0 + 1) * 64 + c0) = acc1;
    }
}

extern "C" void kernel_launch(void* const* d_in, const int* in_sizes, int n_in,
                              void* d_out, int out_size, void* d_ws, size_t ws_size,
                              hipStream_t stream) {
    const float* x  = (const float*)d_in[0];
    const float* W1 = (const float*)d_in[1];
    const float* b1 = (const float*)d_in[2];
    const float* W2 = (const float*)d_in[3];
    const float* b2 = (const float*)d_in[4];
    const int* src  = (const int*)d_in[5];
    const int* dst  = (const int*)d_in[6];
    float* out = (float*)d_out;

    const int nfeat = N_NODES * 64;
    const int nfeat4 = nfeat / 4;

    // workspace layout
    char* ws = (char*)d_ws;
    float* A    = (float*)ws;  ws += (size_t)nfeat * 4;            // 25.6 MB
    int* eb     = (int*)ws;    ws += (size_t)N_EDGES * 4;          // 6.4 MB
    int* es     = (int*)ws;    ws += (size_t)N_EDGES * 4;          // 6.4 MB
    int* off    = (int*)ws;    ws += (size_t)(N_NODES + 1) * 4;    // 400 KB
    int* bcnt   = (int*)ws;    ws += (size_t)NBK2 * PAD * 4;       // 12.5 KB
    int* gcur   = (int*)ws;    ws += (size_t)NBK2 * PAD * 4;       // 12.5 KB
    int* boff   = (int*)ws;    ws += (size_t)(NBK2 + 1) * 4;
    size_t need = (size_t)(ws - (char*)d_ws);

    if (ws_size >= need) {
        // ---- CSR build (block-aggregated two-stage partition) ----
        hipMemsetAsync(bcnt, 0, (size_t)NBK2 * PAD * 4, stream);
        k_bhist<<<512, 256, 0, stream>>>(dst, bcnt);
        k_bscan<<<1, 256, 0, stream>>>(bcnt, boff, gcur);
        k_part<<<NPBLK, 256, 0, stream>>>(src, dst, gcur, eb);
        k_fill3<<<NBK2, 512, 0, stream>>>(eb, boff, off, es);

        // ---- layer 1 aggregate: A = segsum(x) ----
        k_gather<<<(N_NODES + 3) / 4, 256, 0, stream>>>(x, es, off, nullptr, A);
        // ---- MLP in place: A = relu(A*W1+b1)*W2 ----
        k_mlp<<<N_NODES / MROWS, 256, 0, stream>>>(A, W1, b1, W2);
        // ---- layer 2 aggregate + bias: out = b2 + segsum(A) ----
        k_gather<<<(N_NODES + 3) / 4, 256, 0, stream>>>(A, es, off, b2, out);
    } else {
        // ---- fallback: atomic scatter ----
        k_zero_f4<<<(nfeat4 + 255) / 256, 256, 0, stream>>>((float4*)A, nfeat4);
        int threads = N_EDGES * 16;
        k_scatter64<<<(threads + 255) / 256, 256, 0, stream>>>(x, src, dst, A);
        k_mlp<<<N_NODES / MROWS, 256, 0, stream>>>(A, W1, b1, W2);
        k_init_bias<<<(nfeat + 255) / 256, 256, 0, stream>>>(out, b2, nfeat);
        k_scatter64<<<(threads + 255) / 256, 256, 0, stream>>>(A, src, dst, out);
    }
}

// Round 10
// 246.395 us; speedup vs baseline: 6.3599x; 1.0235x over previous
//
#include <hip/hip_runtime.h>

#define N_NODES 100000
#define N_EDGES 1600000
#define IN_F 64
#define HID 128
#define N_CLS 64

#define NPB2 512                                // nodes per coarse bucket (d >> 9)
#define NBK2 ((N_NODES + NPB2 - 1) / NPB2)      // 196
#define PAD 16                                  // ints per padded global counter (64 B)
#define PCHUNK 8192                             // edges per k_part block
#define NPBLK ((N_EDGES + PCHUNK - 1) / PCHUNK) // 196

// ================= bf16 helpers =================
__device__ __forceinline__ unsigned short f2bf(float f) {
    unsigned int u = __float_as_uint(f);
    u = (u + 0x7FFFu + ((u >> 16) & 1u)) >> 16;   // RNE
    return (unsigned short)u;
}
__device__ __forceinline__ float bf2f(unsigned short h) {
    return __uint_as_float(((unsigned int)h) << 16);
}

// ================= generic helpers =================
__global__ void k_zero_f4(float4* __restrict__ p, int n4) {
    int i = blockIdx.x * blockDim.x + threadIdx.x;
    if (i < n4) p[i] = make_float4(0.f, 0.f, 0.f, 0.f);
}
__global__ void k_init_bias(float* __restrict__ out, const float* __restrict__ b2, int n) {
    int i = blockIdx.x * blockDim.x + threadIdx.x;
    if (i < n) out[i] = b2[i & 63];
}

// convert fp32 -> bf16, 8 elems/thread
__global__ void k_cvt(const float4* __restrict__ x4, uint4* __restrict__ xh, int n8) {
    int i = blockIdx.x * blockDim.x + threadIdx.x;
    if (i >= n8) return;
    float4 a = x4[2 * i], b = x4[2 * i + 1];
    uint4 o;
    o.x = (unsigned)f2bf(a.x) | ((unsigned)f2bf(a.y) << 16);
    o.y = (unsigned)f2bf(a.z) | ((unsigned)f2bf(a.w) << 16);
    o.z = (unsigned)f2bf(b.x) | ((unsigned)f2bf(b.y) << 16);
    o.w = (unsigned)f2bf(b.z) | ((unsigned)f2bf(b.w) << 16);
    xh[i] = o;
}

// ================= coarse bucket histogram (LDS-staged) =================
__global__ __launch_bounds__(256) void k_bhist(const int* __restrict__ dst,
                                               int* __restrict__ bcnt) {
    __shared__ int h[NBK2];
    for (int i = threadIdx.x; i < NBK2; i += 256) h[i] = 0;
    __syncthreads();
    int stride = gridDim.x * blockDim.x;
    for (int e = blockIdx.x * blockDim.x + threadIdx.x; e < N_EDGES; e += stride)
        atomicAdd(&h[dst[e] >> 9], 1);
    __syncthreads();
    for (int i = threadIdx.x; i < NBK2; i += 256) {
        int v = h[i];
        if (v) atomicAdd(&bcnt[i * PAD], v);
    }
}

__global__ __launch_bounds__(256) void k_bscan(const int* __restrict__ bcnt,
                                               int* __restrict__ boff,
                                               int* __restrict__ gcur) {
    __shared__ int s[NBK2];
    const int t = threadIdx.x;
    if (t < NBK2) s[t] = bcnt[t * PAD];
    __syncthreads();
    if (t == 0) {
        int run = 0;
        for (int i = 0; i < NBK2; ++i) { int v = s[i]; s[i] = run; run += v; }
    }
    __syncthreads();
    if (t < NBK2) { boff[t] = s[t]; gcur[t * PAD] = s[t]; }
    if (t == 0) boff[NBK2] = N_EDGES;
}

// ================= block-aggregated partition into coarse buckets =================
__global__ __launch_bounds__(256) void k_part(const int* __restrict__ src,
                                              const int* __restrict__ dst,
                                              int* __restrict__ gcur,
                                              int* __restrict__ eb) {
    __shared__ int hist[NBK2];
    __shared__ int gbase[NBK2];
    __shared__ int lcur[NBK2];
    const int t = threadIdx.x;
    const int e0 = blockIdx.x * PCHUNK;
    int e1 = e0 + PCHUNK; if (e1 > N_EDGES) e1 = N_EDGES;
    for (int i = t; i < NBK2; i += 256) hist[i] = 0;
    __syncthreads();
    for (int e = e0 + t; e < e1; e += 256) atomicAdd(&hist[dst[e] >> 9], 1);
    __syncthreads();
    if (t < NBK2) {
        int c = hist[t];
        gbase[t] = c ? atomicAdd(&gcur[t * PAD], c) : 0;
        lcur[t] = 0;
    }
    __syncthreads();
    for (int e = e0 + t; e < e1; e += 256) {
        int d = dst[e];
        int b = d >> 9;
        int r = atomicAdd(&lcur[b], 1);
        eb[gbase[b] + r] = ((d & 511) << 17) | src[e];   // dstLow(9b) | src(17b)
    }
}

// ================= per-bucket: node-degree hist + scan -> off; sort -> es =================
__global__ __launch_bounds__(512) void k_fill3(const int* __restrict__ eb,
                                               const int* __restrict__ boff,
                                               int* __restrict__ off,
                                               int* __restrict__ es) {
    __shared__ int ldeg[NPB2];
    __shared__ int sc[2][NPB2];
    const int t = threadIdx.x;
    const int b = blockIdx.x;
    const int bbase = boff[b], bend = boff[b + 1];

    ldeg[t] = 0;
    __syncthreads();
    for (int i = bbase + t; i < bend; i += 512) atomicAdd(&ldeg[eb[i] >> 17], 1);
    __syncthreads();

    int v = ldeg[t];
    sc[0][t] = v;
    __syncthreads();
    int cur = 0;
    for (int d = 1; d < NPB2; d <<= 1) {
        int x = sc[cur][t];
        if (t >= d) x += sc[cur][t - d];
        sc[cur ^ 1][t] = x;
        __syncthreads();
        cur ^= 1;
    }
    int ex = sc[cur][t] - v;

    const int n0 = b * NPB2;
    if (n0 + t < N_NODES) off[n0 + t] = bbase + ex;
    if (b == NBK2 - 1 && t == 0) off[N_NODES] = N_EDGES;

    ldeg[t] = ex;
    __syncthreads();

    for (int i = bbase + t; i < bend; i += 512) {
        int p = eb[i];
        int r = atomicAdd(&ldeg[p >> 17], 1);
        es[bbase + r] = p & 0x1FFFF;
    }
}

// ================= gather (bf16 feat): one wave per node =================
__global__ __launch_bounds__(256) void k_gather(const unsigned short* __restrict__ feat,
                                                const int* __restrict__ es,
                                                const int* __restrict__ off,
                                                const float* __restrict__ bias,
                                                float* __restrict__ out) {
    const int wave = threadIdx.x >> 6;
    const int lane = threadIdx.x & 63;
    const int n = blockIdx.x * 4 + wave;
    if (n >= N_NODES) return;
    const int beg = off[n], end = off[n + 1];
    float acc = bias ? bias[lane] : 0.f;
    for (int base = beg; base < end; base += 64) {
        int m = end - base; if (m > 64) m = 64;
        int id = (lane < m) ? es[base + lane] : 0;
        int k = 0;
        for (; k + 4 <= m; k += 4) {
            int s0 = __shfl(id, k), s1 = __shfl(id, k + 1);
            int s2 = __shfl(id, k + 2), s3 = __shfl(id, k + 3);
            float v0 = bf2f(feat[(size_t)s0 * 64 + lane]);
            float v1 = bf2f(feat[(size_t)s1 * 64 + lane]);
            float v2 = bf2f(feat[(size_t)s2 * 64 + lane]);
            float v3 = bf2f(feat[(size_t)s3 * 64 + lane]);
            acc += (v0 + v1) + (v2 + v3);
        }
        for (; k < m; ++k) {
            int s = __shfl(id, k);
            acc += bf2f(feat[(size_t)s * 64 + lane]);
        }
    }
    out[(size_t)n * 64 + lane] = acc;
}

// ================= gather (fp32 feat): tier-2 =================
__global__ __launch_bounds__(256) void k_gatherF(const float* __restrict__ feat,
                                                 const int* __restrict__ es,
                                                 const int* __restrict__ off,
                                                 const float* __restrict__ bias,
                                                 float* __restrict__ out) {
    const int wave = threadIdx.x >> 6;
    const int lane = threadIdx.x & 63;
    const int n = blockIdx.x * 4 + wave;
    if (n >= N_NODES) return;
    const int beg = off[n], end = off[n + 1];
    float acc = bias ? bias[lane] : 0.f;
    for (int base = beg; base < end; base += 64) {
        int m = end - base; if (m > 64) m = 64;
        int id = (lane < m) ? es[base + lane] : 0;
        int k = 0;
        for (; k + 4 <= m; k += 4) {
            int s0 = __shfl(id, k), s1 = __shfl(id, k + 1);
            int s2 = __shfl(id, k + 2), s3 = __shfl(id, k + 3);
            float v0 = feat[(size_t)s0 * 64 + lane];
            float v1 = feat[(size_t)s1 * 64 + lane];
            float v2 = feat[(size_t)s2 * 64 + lane];
            float v3 = feat[(size_t)s3 * 64 + lane];
            acc += (v0 + v1) + (v2 + v3);
        }
        for (; k < m; ++k) {
            int s = __shfl(id, k);
            acc += feat[(size_t)s * 64 + lane];
        }
    }
    out[(size_t)n * 64 + lane] = acc;
}

// ================= fallback atomic scatter =================
__global__ void k_scatter64(const float* __restrict__ feat,
                            const int* __restrict__ src,
                            const int* __restrict__ dst,
                            float* __restrict__ out) {
    int i = blockIdx.x * blockDim.x + threadIdx.x;
    int e = i >> 4;
    if (e >= N_EDGES) return;
    int j = (i & 15) << 2;
    int s = src[e];
    int d = dst[e];
    float4 v = *reinterpret_cast<const float4*>(feat + (size_t)s * 64 + j);
    float* o = out + (size_t)d * 64 + j;
    atomicAdd(o + 0, v.x);
    atomicAdd(o + 1, v.y);
    atomicAdd(o + 2, v.z);
    atomicAdd(o + 3, v.w);
}

// ================= fused MLP: Z = relu(A*W1 + b1) * W2 =================
// OUTBF=1: write z as bf16 to zh. OUTBF=0: write fp32 in-place to A.
#define MROWS 32
#define XS_S 68
#define HS_S 132

__device__ __forceinline__ void fma4(float4& a, float s, const float4& wv) {
    a.x = fmaf(s, wv.x, a.x);
    a.y = fmaf(s, wv.y, a.y);
    a.z = fmaf(s, wv.z, a.z);
    a.w = fmaf(s, wv.w, a.w);
}

template <int OUTBF>
__global__ __launch_bounds__(256, 2) void k_mlp(float* __restrict__ A,
                                                unsigned short* __restrict__ zh,
                                                const float* __restrict__ W1,
                                                const float* __restrict__ b1,
                                                const float* __restrict__ W2) {
    __shared__ float Ws[64 * 128];          // 32 KB: W1 then W2
    __shared__ float xs[MROWS * XS_S];
    __shared__ float hs[MROWS * HS_S];
    __shared__ float b1s[128];
    const int t = threadIdx.x;
    const int row0 = blockIdx.x * MROWS;

    // stage W1 (2048 float4)
    {
        const float4* w4 = (const float4*)W1;
        float4* s4 = (float4*)Ws;
        for (int i = t; i < 2048; i += 256) s4[i] = w4[i];
    }
    // early-issue W2 into registers (latency hides under phase 1)
    float4 w2r[8];
    {
        const float4* w4 = (const float4*)W2;
#pragma unroll
        for (int i = 0; i < 8; ++i) w2r[i] = w4[t + i * 256];
    }
    if (t < 128) b1s[t] = b1[t];
    // stage x row-major
#pragma unroll
    for (int c = 0; c < 2; ++c) {
        int lin = t + c * 256;
        int r = lin >> 4;
        int k4 = lin & 15;
        float4 v = *(const float4*)(A + (size_t)(row0 + r) * 64 + k4 * 4);
        *(float4*)&xs[r * XS_S + k4 * 4] = v;
    }
    __syncthreads();

    // ---- phase 1: h = relu(x*W1 + b1), 4 rows x 4 cols per thread ----
    {
        const int rg = t >> 5, cg = t & 31;
        const int r0 = rg * 4, c0 = cg * 4;
        float4 bv = *(const float4*)&b1s[c0];
        float4 acc0 = bv, acc1 = bv, acc2 = bv, acc3 = bv;
#pragma unroll 4
        for (int k4 = 0; k4 < 16; ++k4) {
            float4 a0 = *(const float4*)&xs[(r0 + 0) * XS_S + k4 * 4];
            float4 a1 = *(const float4*)&xs[(r0 + 1) * XS_S + k4 * 4];
            float4 a2 = *(const float4*)&xs[(r0 + 2) * XS_S + k4 * 4];
            float4 a3 = *(const float4*)&xs[(r0 + 3) * XS_S + k4 * 4];
            float4 w0 = *(const float4*)&Ws[(k4 * 4 + 0) * 128 + c0];
            float4 w1 = *(const float4*)&Ws[(k4 * 4 + 1) * 128 + c0];
            float4 w2 = *(const float4*)&Ws[(k4 * 4 + 2) * 128 + c0];
            float4 w3 = *(const float4*)&Ws[(k4 * 4 + 3) * 128 + c0];
            fma4(acc0, a0.x, w0); fma4(acc0, a0.y, w1); fma4(acc0, a0.z, w2); fma4(acc0, a0.w, w3);
            fma4(acc1, a1.x, w0); fma4(acc1, a1.y, w1); fma4(acc1, a1.z, w2); fma4(acc1, a1.w, w3);
            fma4(acc2, a2.x, w0); fma4(acc2, a2.y, w1); fma4(acc2, a2.z, w2); fma4(acc2, a2.w, w3);
            fma4(acc3, a3.x, w0); fma4(acc3, a3.y, w1); fma4(acc3, a3.z, w2); fma4(acc3, a3.w, w3);
        }
        float4 h;
        h.x = fmaxf(acc0.x, 0.f); h.y = fmaxf(acc0.y, 0.f); h.z = fmaxf(acc0.z, 0.f); h.w = fmaxf(acc0.w, 0.f);
        *(float4*)&hs[(r0 + 0) * HS_S + c0] = h;
        h.x = fmaxf(acc1.x, 0.f); h.y = fmaxf(acc1.y, 0.f); h.z = fmaxf(acc1.z, 0.f); h.w = fmaxf(acc1.w, 0.f);
        *(float4*)&hs[(r0 + 1) * HS_S + c0] = h;
        h.x = fmaxf(acc2.x, 0.f); h.y = fmaxf(acc2.y, 0.f); h.z = fmaxf(acc2.z, 0.f); h.w = fmaxf(acc2.w, 0.f);
        *(float4*)&hs[(r0 + 2) * HS_S + c0] = h;
        h.x = fmaxf(acc3.x, 0.f); h.y = fmaxf(acc3.y, 0.f); h.z = fmaxf(acc3.z, 0.f); h.w = fmaxf(acc3.w, 0.f);
        *(float4*)&hs[(r0 + 3) * HS_S + c0] = h;
    }
    __syncthreads();

    // write W2 registers into Ws (no memory wait here)
    {
        float4* s4 = (float4*)Ws;
#pragma unroll
        for (int i = 0; i < 8; ++i) s4[t + i * 256] = w2r[i];
    }
    __syncthreads();

    // ---- phase 2: z = h*W2, 2 rows x 4 cols per thread ----
    {
        const int rg = t >> 4, cg = t & 15;
        const int r0 = rg * 2, c0 = cg * 4;
        float4 acc0 = make_float4(0.f, 0.f, 0.f, 0.f);
        float4 acc1 = make_float4(0.f, 0.f, 0.f, 0.f);
#pragma unroll 4
        for (int k4 = 0; k4 < 32; ++k4) {
            float4 h0 = *(const float4*)&hs[(r0 + 0) * HS_S + k4 * 4];
            float4 h1 = *(const float4*)&hs[(r0 + 1) * HS_S + k4 * 4];
            float4 w0 = *(const float4*)&Ws[(k4 * 4 + 0) * 64 + c0];
            float4 w1 = *(const float4*)&Ws[(k4 * 4 + 1) * 64 + c0];
            float4 w2 = *(const float4*)&Ws[(k4 * 4 + 2) * 64 + c0];
            float4 w3 = *(const float4*)&Ws[(k4 * 4 + 3) * 64 + c0];
            fma4(acc0, h0.x, w0); fma4(acc0, h0.y, w1); fma4(acc0, h0.z, w2); fma4(acc0, h0.w, w3);
            fma4(acc1, h1.x, w0); fma4(acc1, h1.y, w1); fma4(acc1, h1.z, w2); fma4(acc1, h1.w, w3);
        }
        if (OUTBF) {
            ushort4 o0, o1;
            o0.x = f2bf(acc0.x); o0.y = f2bf(acc0.y); o0.z = f2bf(acc0.z); o0.w = f2bf(acc0.w);
            o1.x = f2bf(acc1.x); o1.y = f2bf(acc1.y); o1.z = f2bf(acc1.z); o1.w = f2bf(acc1.w);
            *(ushort4*)&zh[(size_t)(row0 + r0 + 0) * 64 + c0] = o0;
            *(ushort4*)&zh[(size_t)(row0 + r0 + 1) * 64 + c0] = o1;
        } else {
            *(float4*)(A + (size_t)(row0 + r0 + 0) * 64 + c0) = acc0;
            *(float4*)(A + (size_t)(row0 + r0 + 1) * 64 + c0) = acc1;
        }
    }
}

extern "C" void kernel_launch(void* const* d_in, const int* in_sizes, int n_in,
                              void* d_out, int out_size, void* d_ws, size_t ws_size,
                              hipStream_t stream) {
    const float* x  = (const float*)d_in[0];
    const float* W1 = (const float*)d_in[1];
    const float* b1 = (const float*)d_in[2];
    const float* W2 = (const float*)d_in[3];
    const float* b2 = (const float*)d_in[4];
    const int* src  = (const int*)d_in[5];
    const int* dst  = (const int*)d_in[6];
    float* out = (float*)d_out;

    const int nfeat = N_NODES * 64;
    const int nfeat4 = nfeat / 4;

    // ---- tier-1 layout: bf16 gather payloads. A aliases (overlays) eb. ----
    char* ws = (char*)d_ws;
    unsigned short* xh = (unsigned short*)ws;  ws += (size_t)nfeat * 2;         // 12.8 MB (zh aliases)
    int* es     = (int*)ws;    ws += (size_t)N_EDGES * 4;                       // 6.4 MB
    int* off    = (int*)ws;    ws += (size_t)(N_NODES + 1) * 4;                 // 400 KB
    int* bcnt   = (int*)ws;    ws += (size_t)NBK2 * PAD * 4;
    int* gcur   = (int*)ws;    ws += (size_t)NBK2 * PAD * 4;
    int* boff   = (int*)ws;    ws += (size_t)(NBK2 + 1) * 4;
    char* shrd  = ws;          // shared region: eb (6.4 MB) then A (25.6 MB) overlays it
    int* eb     = (int*)shrd;
    float* A    = (float*)shrd;
    ws += (size_t)nfeat * 4;   // A size dominates
    size_t need1 = (size_t)(ws - (char*)d_ws);
    unsigned short* zh = xh;   // alias: xh dead after gather1, zh written by k_mlp

    // ---- tier-2 layout: round-9 fp32 path ----
    char* w2p = (char*)d_ws;
    float* A2   = (float*)w2p; w2p += (size_t)nfeat * 4;
    int* eb2    = (int*)w2p;   w2p += (size_t)N_EDGES * 4;
    int* es2    = (int*)w2p;   w2p += (size_t)N_EDGES * 4;
    int* off2   = (int*)w2p;   w2p += (size_t)(N_NODES + 1) * 4;
    int* bcnt2  = (int*)w2p;   w2p += (size_t)NBK2 * PAD * 4;
    int* gcur2  = (int*)w2p;   w2p += (size_t)NBK2 * PAD * 4;
    int* boff2  = (int*)w2p;   w2p += (size_t)(NBK2 + 1) * 4;
    size_t need2 = (size_t)(w2p - (char*)d_ws);

    if (ws_size >= need1) {
        // ---- x -> bf16 ----
        k_cvt<<<(nfeat / 8 + 255) / 256, 256, 0, stream>>>((const float4*)x, (uint4*)xh, nfeat / 8);
        // ---- CSR build ----
        hipMemsetAsync(bcnt, 0, (size_t)NBK2 * PAD * 4, stream);
        k_bhist<<<512, 256, 0, stream>>>(dst, bcnt);
        k_bscan<<<1, 256, 0, stream>>>(bcnt, boff, gcur);
        k_part<<<NPBLK, 256, 0, stream>>>(src, dst, gcur, eb);
        k_fill3<<<NBK2, 512, 0, stream>>>(eb, boff, off, es);

        // ---- layer 1 aggregate: A = segsum(xh)  (A overlays dead eb) ----
        k_gather<<<(N_NODES + 3) / 4, 256, 0, stream>>>(xh, es, off, nullptr, A);
        // ---- MLP: zh = bf16(relu(A*W1+b1)*W2)  (zh overlays dead xh) ----
        k_mlp<1><<<N_NODES / MROWS, 256, 0, stream>>>(A, zh, W1, b1, W2);
        // ---- layer 2 aggregate + bias: out = b2 + segsum(zh) ----
        k_gather<<<(N_NODES + 3) / 4, 256, 0, stream>>>(zh, es, off, b2, out);
    } else if (ws_size >= need2) {
        // ---- round-9 proven fp32 path ----
        hipMemsetAsync(bcnt2, 0, (size_t)NBK2 * PAD * 4, stream);
        k_bhist<<<512, 256, 0, stream>>>(dst, bcnt2);
        k_bscan<<<1, 256, 0, stream>>>(bcnt2, boff2, gcur2);
        k_part<<<NPBLK, 256, 0, stream>>>(src, dst, gcur2, eb2);
        k_fill3<<<NBK2, 512, 0, stream>>>(eb2, boff2, off2, es2);

        k_gatherF<<<(N_NODES + 3) / 4, 256, 0, stream>>>(x, es2, off2, nullptr, A2);
        k_mlp<0><<<N_NODES / MROWS, 256, 0, stream>>>(A2, nullptr, W1, b1, W2);
        k_gatherF<<<(N_NODES + 3) / 4, 256, 0, stream>>>(A2, es2, off2, b2, out);
    } else {
        // ---- tier-3: atomic scatter ----
        float* A3 = (float*)d_ws;
        k_zero_f4<<<(nfeat4 + 255) / 256, 256, 0, stream>>>((float4*)A3, nfeat4);
        int threads = N_EDGES * 16;
        k_scatter64<<<(threads + 255) / 256, 256, 0, stream>>>(x, src, dst, A3);
        k_mlp<0><<<N_NODES / MROWS, 256, 0, stream>>>(A3, nullptr, W1, b1, W2);
        k_init_bias<<<(nfeat + 255) / 256, 256, 0, stream>>>(out, b2, nfeat);
        k_scatter64<<<(threads + 255) / 256, 256, 0, stream>>>(A3, src, dst, out);
    }
}

// Round 11
// 229.939 us; speedup vs baseline: 6.8150x; 1.0716x over previous
//
#include <hip/hip_runtime.h>

#define N_NODES 100000
#define N_EDGES 1600000
#define IN_F 64
#define HID 128
#define N_CLS 64

#define NPB2 512                                // nodes per coarse bucket (d >> 9)
#define NBK2 ((N_NODES + NPB2 - 1) / NPB2)      // 196
#define PAD 16                                  // ints per padded global counter (64 B)
#define PCHUNK 8192                             // edges per k_part block
#define NPBLK ((N_EDGES + PCHUNK - 1) / PCHUNK) // 196

// ================= bf16 helpers =================
__device__ __forceinline__ unsigned short f2bf(float f) {
    unsigned int u = __float_as_uint(f);
    u = (u + 0x7FFFu + ((u >> 16) & 1u)) >> 16;   // RNE
    return (unsigned short)u;
}
__device__ __forceinline__ float bf2f(unsigned short h) {
    return __uint_as_float(((unsigned int)h) << 16);
}

// ================= generic helpers =================
__global__ void k_zero_f4(float4* __restrict__ p, int n4) {
    int i = blockIdx.x * blockDim.x + threadIdx.x;
    if (i < n4) p[i] = make_float4(0.f, 0.f, 0.f, 0.f);
}
__global__ void k_init_bias(float* __restrict__ out, const float* __restrict__ b2, int n) {
    int i = blockIdx.x * blockDim.x + threadIdx.x;
    if (i < n) out[i] = b2[i & 63];
}

// convert fp32 -> bf16, 8 elems/thread
__global__ void k_cvt(const float4* __restrict__ x4, uint4* __restrict__ xh, int n8) {
    int i = blockIdx.x * blockDim.x + threadIdx.x;
    if (i >= n8) return;
    float4 a = x4[2 * i], b = x4[2 * i + 1];
    uint4 o;
    o.x = (unsigned)f2bf(a.x) | ((unsigned)f2bf(a.y) << 16);
    o.y = (unsigned)f2bf(a.z) | ((unsigned)f2bf(a.w) << 16);
    o.z = (unsigned)f2bf(b.x) | ((unsigned)f2bf(b.y) << 16);
    o.w = (unsigned)f2bf(b.z) | ((unsigned)f2bf(b.w) << 16);
    xh[i] = o;
}

// ================= coarse bucket histogram (LDS-staged) =================
__global__ __launch_bounds__(256) void k_bhist(const int* __restrict__ dst,
                                               int* __restrict__ bcnt) {
    __shared__ int h[NBK2];
    for (int i = threadIdx.x; i < NBK2; i += 256) h[i] = 0;
    __syncthreads();
    int stride = gridDim.x * blockDim.x;
    for (int e = blockIdx.x * blockDim.x + threadIdx.x; e < N_EDGES; e += stride)
        atomicAdd(&h[dst[e] >> 9], 1);
    __syncthreads();
    for (int i = threadIdx.x; i < NBK2; i += 256) {
        int v = h[i];
        if (v) atomicAdd(&bcnt[i * PAD], v);
    }
}

__global__ __launch_bounds__(256) void k_bscan(const int* __restrict__ bcnt,
                                               int* __restrict__ boff,
                                               int* __restrict__ gcur) {
    __shared__ int s[NBK2];
    const int t = threadIdx.x;
    if (t < NBK2) s[t] = bcnt[t * PAD];
    __syncthreads();
    if (t == 0) {
        int run = 0;
        for (int i = 0; i < NBK2; ++i) { int v = s[i]; s[i] = run; run += v; }
    }
    __syncthreads();
    if (t < NBK2) { boff[t] = s[t]; gcur[t * PAD] = s[t]; }
    if (t == 0) boff[NBK2] = N_EDGES;
}

// ================= block-aggregated partition into coarse buckets =================
__global__ __launch_bounds__(256) void k_part(const int* __restrict__ src,
                                              const int* __restrict__ dst,
                                              int* __restrict__ gcur,
                                              int* __restrict__ eb) {
    __shared__ int hist[NBK2];
    __shared__ int gbase[NBK2];
    __shared__ int lcur[NBK2];
    const int t = threadIdx.x;
    const int e0 = blockIdx.x * PCHUNK;
    int e1 = e0 + PCHUNK; if (e1 > N_EDGES) e1 = N_EDGES;
    for (int i = t; i < NBK2; i += 256) hist[i] = 0;
    __syncthreads();
    for (int e = e0 + t; e < e1; e += 256) atomicAdd(&hist[dst[e] >> 9], 1);
    __syncthreads();
    if (t < NBK2) {
        int c = hist[t];
        gbase[t] = c ? atomicAdd(&gcur[t * PAD], c) : 0;
        lcur[t] = 0;
    }
    __syncthreads();
    for (int e = e0 + t; e < e1; e += 256) {
        int d = dst[e];
        int b = d >> 9;
        int r = atomicAdd(&lcur[b], 1);
        eb[gbase[b] + r] = ((d & 511) << 17) | src[e];   // dstLow(9b) | src(17b)
    }
}

// ================= per-bucket: node-degree hist + scan -> off; sort -> es =================
__global__ __launch_bounds__(512) void k_fill3(const int* __restrict__ eb,
                                               const int* __restrict__ boff,
                                               int* __restrict__ off,
                                               int* __restrict__ es) {
    __shared__ int ldeg[NPB2];
    __shared__ int sc[2][NPB2];
    const int t = threadIdx.x;
    const int b = blockIdx.x;
    const int bbase = boff[b], bend = boff[b + 1];

    ldeg[t] = 0;
    __syncthreads();
    for (int i = bbase + t; i < bend; i += 512) atomicAdd(&ldeg[eb[i] >> 17], 1);
    __syncthreads();

    int v = ldeg[t];
    sc[0][t] = v;
    __syncthreads();
    int cur = 0;
    for (int d = 1; d < NPB2; d <<= 1) {
        int x = sc[cur][t];
        if (t >= d) x += sc[cur][t - d];
        sc[cur ^ 1][t] = x;
        __syncthreads();
        cur ^= 1;
    }
    int ex = sc[cur][t] - v;

    const int n0 = b * NPB2;
    if (n0 + t < N_NODES) off[n0 + t] = bbase + ex;
    if (b == NBK2 - 1 && t == 0) off[N_NODES] = N_EDGES;

    ldeg[t] = ex;
    __syncthreads();

    for (int i = bbase + t; i < bend; i += 512) {
        int p = eb[i];
        int r = atomicAdd(&ldeg[p >> 17], 1);
        es[bbase + r] = p & 0x1FFFF;
    }
}

// ================= gather (bf16 feat): one wave per node =================
__global__ __launch_bounds__(256) void k_gather(const unsigned short* __restrict__ feat,
                                                const int* __restrict__ es,
                                                const int* __restrict__ off,
                                                const float* __restrict__ bias,
                                                float* __restrict__ out) {
    const int wave = threadIdx.x >> 6;
    const int lane = threadIdx.x & 63;
    const int n = blockIdx.x * 4 + wave;
    if (n >= N_NODES) return;
    const int beg = off[n], end = off[n + 1];
    float acc = bias ? bias[lane] : 0.f;
    for (int base = beg; base < end; base += 64) {
        int m = end - base; if (m > 64) m = 64;
        int id = (lane < m) ? es[base + lane] : 0;
        int k = 0;
        for (; k + 4 <= m; k += 4) {
            int s0 = __shfl(id, k), s1 = __shfl(id, k + 1);
            int s2 = __shfl(id, k + 2), s3 = __shfl(id, k + 3);
            float v0 = bf2f(feat[(size_t)s0 * 64 + lane]);
            float v1 = bf2f(feat[(size_t)s1 * 64 + lane]);
            float v2 = bf2f(feat[(size_t)s2 * 64 + lane]);
            float v3 = bf2f(feat[(size_t)s3 * 64 + lane]);
            acc += (v0 + v1) + (v2 + v3);
        }
        for (; k < m; ++k) {
            int s = __shfl(id, k);
            acc += bf2f(feat[(size_t)s * 64 + lane]);
        }
    }
    out[(size_t)n * 64 + lane] = acc;
}

// ================= gather (fp32 feat): tier-2 =================
__global__ __launch_bounds__(256) void k_gatherF(const float* __restrict__ feat,
                                                 const int* __restrict__ es,
                                                 const int* __restrict__ off,
                                                 const float* __restrict__ bias,
                                                 float* __restrict__ out) {
    const int wave = threadIdx.x >> 6;
    const int lane = threadIdx.x & 63;
    const int n = blockIdx.x * 4 + wave;
    if (n >= N_NODES) return;
    const int beg = off[n], end = off[n + 1];
    float acc = bias ? bias[lane] : 0.f;
    for (int base = beg; base < end; base += 64) {
        int m = end - base; if (m > 64) m = 64;
        int id = (lane < m) ? es[base + lane] : 0;
        int k = 0;
        for (; k + 4 <= m; k += 4) {
            int s0 = __shfl(id, k), s1 = __shfl(id, k + 1);
            int s2 = __shfl(id, k + 2), s3 = __shfl(id, k + 3);
            float v0 = feat[(size_t)s0 * 64 + lane];
            float v1 = feat[(size_t)s1 * 64 + lane];
            float v2 = feat[(size_t)s2 * 64 + lane];
            float v3 = feat[(size_t)s3 * 64 + lane];
            acc += (v0 + v1) + (v2 + v3);
        }
        for (; k < m; ++k) {
            int s = __shfl(id, k);
            acc += feat[(size_t)s * 64 + lane];
        }
    }
    out[(size_t)n * 64 + lane] = acc;
}

// ================= fallback atomic scatter =================
__global__ void k_scatter64(const float* __restrict__ feat,
                            const int* __restrict__ src,
                            const int* __restrict__ dst,
                            float* __restrict__ out) {
    int i = blockIdx.x * blockDim.x + threadIdx.x;
    int e = i >> 4;
    if (e >= N_EDGES) return;
    int j = (i & 15) << 2;
    int s = src[e];
    int d = dst[e];
    float4 v = *reinterpret_cast<const float4*>(feat + (size_t)s * 64 + j);
    float* o = out + (size_t)d * 64 + j;
    atomicAdd(o + 0, v.x);
    atomicAdd(o + 1, v.y);
    atomicAdd(o + 2, v.z);
    atomicAdd(o + 3, v.w);
}

// ================= split GEMMs =================
#define MROWS 32
#define XS_S 68      // float stride for x rows
#define HS2_S 152    // ushort stride for h rows (304 B, 16B-aligned)

__device__ __forceinline__ void fma4(float4& a, float s, const float4& wv) {
    a.x = fmaf(s, wv.x, a.x);
    a.y = fmaf(s, wv.y, a.y);
    a.z = fmaf(s, wv.z, a.z);
    a.w = fmaf(s, wv.w, a.w);
}

// GEMM1: H(bf16, stride 128, overlays A) = relu(A*W1 + b1)
__global__ __launch_bounds__(256, 3) void k_gemm1(const float* __restrict__ A,
                                                  unsigned short* __restrict__ H,
                                                  const float* __restrict__ W1,
                                                  const float* __restrict__ b1) {
    __shared__ float Ws[64 * 128];          // 32 KB
    __shared__ float xs[MROWS * XS_S];      // 8.7 KB
    __shared__ float b1s[128];
    const int t = threadIdx.x;
    const int row0 = blockIdx.x * MROWS;

    {
        const float4* w4 = (const float4*)W1;
        float4* s4 = (float4*)Ws;
        for (int i = t; i < 2048; i += 256) s4[i] = w4[i];
    }
    if (t < 128) b1s[t] = b1[t];
#pragma unroll
    for (int c = 0; c < 2; ++c) {
        int lin = t + c * 256;
        int r = lin >> 4, k4 = lin & 15;
        float4 v = *(const float4*)(A + (size_t)(row0 + r) * 64 + k4 * 4);
        *(float4*)&xs[r * XS_S + k4 * 4] = v;
    }
    __syncthreads();   // all A-reads done before in-place H writes

    const int rg = t >> 5, cg = t & 31;
    const int r0 = rg * 4, c0 = cg * 4;
    float4 bv = *(const float4*)&b1s[c0];
    float4 acc0 = bv, acc1 = bv, acc2 = bv, acc3 = bv;
#pragma unroll 4
    for (int k4 = 0; k4 < 16; ++k4) {
        float4 a0 = *(const float4*)&xs[(r0 + 0) * XS_S + k4 * 4];
        float4 a1 = *(const float4*)&xs[(r0 + 1) * XS_S + k4 * 4];
        float4 a2 = *(const float4*)&xs[(r0 + 2) * XS_S + k4 * 4];
        float4 a3 = *(const float4*)&xs[(r0 + 3) * XS_S + k4 * 4];
        float4 w0 = *(const float4*)&Ws[(k4 * 4 + 0) * 128 + c0];
        float4 w1 = *(const float4*)&Ws[(k4 * 4 + 1) * 128 + c0];
        float4 w2 = *(const float4*)&Ws[(k4 * 4 + 2) * 128 + c0];
        float4 w3 = *(const float4*)&Ws[(k4 * 4 + 3) * 128 + c0];
        fma4(acc0, a0.x, w0); fma4(acc0, a0.y, w1); fma4(acc0, a0.z, w2); fma4(acc0, a0.w, w3);
        fma4(acc1, a1.x, w0); fma4(acc1, a1.y, w1); fma4(acc1, a1.z, w2); fma4(acc1, a1.w, w3);
        fma4(acc2, a2.x, w0); fma4(acc2, a2.y, w1); fma4(acc2, a2.z, w2); fma4(acc2, a2.w, w3);
        fma4(acc3, a3.x, w0); fma4(acc3, a3.y, w1); fma4(acc3, a3.z, w2); fma4(acc3, a3.w, w3);
    }
    ushort4 o;
    o.x = f2bf(fmaxf(acc0.x, 0.f)); o.y = f2bf(fmaxf(acc0.y, 0.f));
    o.z = f2bf(fmaxf(acc0.z, 0.f)); o.w = f2bf(fmaxf(acc0.w, 0.f));
    *(ushort4*)&H[(size_t)(row0 + r0 + 0) * 128 + c0] = o;
    o.x = f2bf(fmaxf(acc1.x, 0.f)); o.y = f2bf(fmaxf(acc1.y, 0.f));
    o.z = f2bf(fmaxf(acc1.z, 0.f)); o.w = f2bf(fmaxf(acc1.w, 0.f));
    *(ushort4*)&H[(size_t)(row0 + r0 + 1) * 128 + c0] = o;
    o.x = f2bf(fmaxf(acc2.x, 0.f)); o.y = f2bf(fmaxf(acc2.y, 0.f));
    o.z = f2bf(fmaxf(acc2.z, 0.f)); o.w = f2bf(fmaxf(acc2.w, 0.f));
    *(ushort4*)&H[(size_t)(row0 + r0 + 2) * 128 + c0] = o;
    o.x = f2bf(fmaxf(acc3.x, 0.f)); o.y = f2bf(fmaxf(acc3.y, 0.f));
    o.z = f2bf(fmaxf(acc3.z, 0.f)); o.w = f2bf(fmaxf(acc3.w, 0.f));
    *(ushort4*)&H[(size_t)(row0 + r0 + 3) * 128 + c0] = o;
}

// GEMM2: zh(bf16) = H(bf16) * W2
__global__ __launch_bounds__(256, 3) void k_gemm2(const unsigned short* __restrict__ H,
                                                  unsigned short* __restrict__ zh,
                                                  const float* __restrict__ W2) {
    __shared__ float Ws[128 * 64];                 // 32 KB
    __shared__ unsigned short hsb[MROWS * HS2_S];  // 9.5 KB
    const int t = threadIdx.x;
    const int row0 = blockIdx.x * MROWS;

    {
        const float4* w4 = (const float4*)W2;
        float4* s4 = (float4*)Ws;
        for (int i = t; i < 2048; i += 256) s4[i] = w4[i];
    }
    // stage h rows: 32 rows x 128 bf16 = 512 uint4
#pragma unroll
    for (int c = 0; c < 2; ++c) {
        int lin = t + c * 256;
        int r = lin >> 4, k8 = lin & 15;
        uint4 v = *(const uint4*)(H + (size_t)(row0 + r) * 128 + k8 * 8);
        *(uint4*)&hsb[r * HS2_S + k8 * 8] = v;
    }
    __syncthreads();

    const int rg = t >> 4, cg = t & 15;
    const int r0 = rg * 2, c0 = cg * 4;
    float4 acc0 = make_float4(0.f, 0.f, 0.f, 0.f);
    float4 acc1 = make_float4(0.f, 0.f, 0.f, 0.f);
#pragma unroll 4
    for (int k4 = 0; k4 < 32; ++k4) {
        ushort4 u0 = *(const ushort4*)&hsb[(r0 + 0) * HS2_S + k4 * 4];
        ushort4 u1 = *(const ushort4*)&hsb[(r0 + 1) * HS2_S + k4 * 4];
        float4 w0 = *(const float4*)&Ws[(k4 * 4 + 0) * 64 + c0];
        float4 w1 = *(const float4*)&Ws[(k4 * 4 + 1) * 64 + c0];
        float4 w2 = *(const float4*)&Ws[(k4 * 4 + 2) * 64 + c0];
        float4 w3 = *(const float4*)&Ws[(k4 * 4 + 3) * 64 + c0];
        fma4(acc0, bf2f(u0.x), w0); fma4(acc0, bf2f(u0.y), w1);
        fma4(acc0, bf2f(u0.z), w2); fma4(acc0, bf2f(u0.w), w3);
        fma4(acc1, bf2f(u1.x), w0); fma4(acc1, bf2f(u1.y), w1);
        fma4(acc1, bf2f(u1.z), w2); fma4(acc1, bf2f(u1.w), w3);
    }
    ushort4 o0, o1;
    o0.x = f2bf(acc0.x); o0.y = f2bf(acc0.y); o0.z = f2bf(acc0.z); o0.w = f2bf(acc0.w);
    o1.x = f2bf(acc1.x); o1.y = f2bf(acc1.y); o1.z = f2bf(acc1.z); o1.w = f2bf(acc1.w);
    *(ushort4*)&zh[(size_t)(row0 + r0 + 0) * 64 + c0] = o0;
    *(ushort4*)&zh[(size_t)(row0 + r0 + 1) * 64 + c0] = o1;
}

// fp32 in-place MLP (tier-2/3 fallback, round-9 proven structure)
__global__ __launch_bounds__(256, 2) void k_mlpF(float* __restrict__ A,
                                                 const float* __restrict__ W1,
                                                 const float* __restrict__ b1,
                                                 const float* __restrict__ W2) {
    __shared__ float Ws[64 * 128];
    __shared__ float xs[MROWS * XS_S];
    __shared__ float hs[MROWS * 132];
    __shared__ float b1s[128];
    const int t = threadIdx.x;
    const int row0 = blockIdx.x * MROWS;

    {
        const float4* w4 = (const float4*)W1;
        float4* s4 = (float4*)Ws;
        for (int i = t; i < 2048; i += 256) s4[i] = w4[i];
    }
    if (t < 128) b1s[t] = b1[t];
#pragma unroll
    for (int c = 0; c < 2; ++c) {
        int lin = t + c * 256;
        int r = lin >> 4, k4 = lin & 15;
        float4 v = *(const float4*)(A + (size_t)(row0 + r) * 64 + k4 * 4);
        *(float4*)&xs[r * XS_S + k4 * 4] = v;
    }
    __syncthreads();
    {
        const int rg = t >> 5, cg = t & 31;
        const int r0 = rg * 4, c0 = cg * 4;
        float4 bv = *(const float4*)&b1s[c0];
        float4 acc0 = bv, acc1 = bv, acc2 = bv, acc3 = bv;
#pragma unroll 4
        for (int k4 = 0; k4 < 16; ++k4) {
            float4 a0 = *(const float4*)&xs[(r0 + 0) * XS_S + k4 * 4];
            float4 a1 = *(const float4*)&xs[(r0 + 1) * XS_S + k4 * 4];
            float4 a2 = *(const float4*)&xs[(r0 + 2) * XS_S + k4 * 4];
            float4 a3 = *(const float4*)&xs[(r0 + 3) * XS_S + k4 * 4];
            float4 w0 = *(const float4*)&Ws[(k4 * 4 + 0) * 128 + c0];
            float4 w1 = *(const float4*)&Ws[(k4 * 4 + 1) * 128 + c0];
            float4 w2 = *(const float4*)&Ws[(k4 * 4 + 2) * 128 + c0];
            float4 w3 = *(const float4*)&Ws[(k4 * 4 + 3) * 128 + c0];
            fma4(acc0, a0.x, w0); fma4(acc0, a0.y, w1); fma4(acc0, a0.z, w2); fma4(acc0, a0.w, w3);
            fma4(acc1, a1.x, w0); fma4(acc1, a1.y, w1); fma4(acc1, a1.z, w2); fma4(acc1, a1.w, w3);
            fma4(acc2, a2.x, w0); fma4(acc2, a2.y, w1); fma4(acc2, a2.z, w2); fma4(acc2, a2.w, w3);
            fma4(acc3, a3.x, w0); fma4(acc3, a3.y, w1); fma4(acc3, a3.z, w2); fma4(acc3, a3.w, w3);
        }
        float4 h;
        h.x = fmaxf(acc0.x, 0.f); h.y = fmaxf(acc0.y, 0.f); h.z = fmaxf(acc0.z, 0.f); h.w = fmaxf(acc0.w, 0.f);
        *(float4*)&hs[(r0 + 0) * 132 + c0] = h;
        h.x = fmaxf(acc1.x, 0.f); h.y = fmaxf(acc1.y, 0.f); h.z = fmaxf(acc1.z, 0.f); h.w = fmaxf(acc1.w, 0.f);
        *(float4*)&hs[(r0 + 1) * 132 + c0] = h;
        h.x = fmaxf(acc2.x, 0.f); h.y = fmaxf(acc2.y, 0.f); h.z = fmaxf(acc2.z, 0.f); h.w = fmaxf(acc2.w, 0.f);
        *(float4*)&hs[(r0 + 2) * 132 + c0] = h;
        h.x = fmaxf(acc3.x, 0.f); h.y = fmaxf(acc3.y, 0.f); h.z = fmaxf(acc3.z, 0.f); h.w = fmaxf(acc3.w, 0.f);
        *(float4*)&hs[(r0 + 3) * 132 + c0] = h;
    }
    __syncthreads();
    {
        const float4* w4 = (const float4*)W2;
        float4* s4 = (float4*)Ws;
        for (int i = t; i < 2048; i += 256) s4[i] = w4[i];
    }
    __syncthreads();
    {
        const int rg = t >> 4, cg = t & 15;
        const int r0 = rg * 2, c0 = cg * 4;
        float4 acc0 = make_float4(0.f, 0.f, 0.f, 0.f);
        float4 acc1 = make_float4(0.f, 0.f, 0.f, 0.f);
#pragma unroll 4
        for (int k4 = 0; k4 < 32; ++k4) {
            float4 h0 = *(const float4*)&hs[(r0 + 0) * 132 + k4 * 4];
            float4 h1 = *(const float4*)&hs[(r0 + 1) * 132 + k4 * 4];
            float4 w0 = *(const float4*)&Ws[(k4 * 4 + 0) * 64 + c0];
            float4 w1 = *(const float4*)&Ws[(k4 * 4 + 1) * 64 + c0];
            float4 w2 = *(const float4*)&Ws[(k4 * 4 + 2) * 64 + c0];
            float4 w3 = *(const float4*)&Ws[(k4 * 4 + 3) * 64 + c0];
            fma4(acc0, h0.x, w0); fma4(acc0, h0.y, w1); fma4(acc0, h0.z, w2); fma4(acc0, h0.w, w3);
            fma4(acc1, h1.x, w0); fma4(acc1, h1.y, w1); fma4(acc1, h1.z, w2); fma4(acc1, h1.w, w3);
        }
        *(float4*)(A + (size_t)(row0 + r0 + 0) * 64 + c0) = acc0;
        *(float4*)(A + (size_t)(row0 + r0 + 1) * 64 + c0) = acc1;
    }
}

static inline size_t alignup(size_t v, size_t a) { return (v + a - 1) & ~(a - 1); }

extern "C" void kernel_launch(void* const* d_in, const int* in_sizes, int n_in,
                              void* d_out, int out_size, void* d_ws, size_t ws_size,
                              hipStream_t stream) {
    const float* x  = (const float*)d_in[0];
    const float* W1 = (const float*)d_in[1];
    const float* b1 = (const float*)d_in[2];
    const float* W2 = (const float*)d_in[3];
    const float* b2 = (const float*)d_in[4];
    const int* src  = (const int*)d_in[5];
    const int* dst  = (const int*)d_in[6];
    float* out = (float*)d_out;

    const int nfeat = N_NODES * 64;
    const int nfeat4 = nfeat / 4;

    // ---- tier-1 layout (64B-aligned fields) ----
    char* base = (char*)d_ws;
    size_t o = 0;
    size_t o_xh   = o;                  o = alignup(o + (size_t)nfeat * 2, 64);          // 12.8 MB
    size_t o_es   = o;                  o = alignup(o + (size_t)N_EDGES * 4, 64);        // 6.4 MB
    size_t o_off  = o;                  o = alignup(o + (size_t)(N_NODES + 1) * 4, 64);
    size_t o_bcnt = o;                  o = alignup(o + (size_t)NBK2 * PAD * 4, 64);
    size_t o_gcur = o;                  o = alignup(o + (size_t)NBK2 * PAD * 4, 64);
    size_t o_boff = o;                  o = alignup(o + (size_t)(NBK2 + 1) * 4, 64);
    size_t o_shrd = o;                  o = alignup(o + (size_t)nfeat * 4, 64);          // eb / A / H share
    size_t need1 = o;

    unsigned short* xh = (unsigned short*)(base + o_xh);
    int* es    = (int*)(base + o_es);
    int* off   = (int*)(base + o_off);
    int* bcnt  = (int*)(base + o_bcnt);
    int* gcur  = (int*)(base + o_gcur);
    int* boff  = (int*)(base + o_boff);
    int* eb    = (int*)(base + o_shrd);
    float* A   = (float*)(base + o_shrd);
    unsigned short* H = (unsigned short*)(base + o_shrd);   // bf16 h overlays A in place
    unsigned short* zh = xh;                                 // z overlays dead xh

    // ---- tier-2 layout: fp32 path ----
    size_t p = 0;
    size_t p_A    = p;   p = alignup(p + (size_t)nfeat * 4, 64);
    size_t p_eb   = p;   p = alignup(p + (size_t)N_EDGES * 4, 64);
    size_t p_es   = p;   p = alignup(p + (size_t)N_EDGES * 4, 64);
    size_t p_off  = p;   p = alignup(p + (size_t)(N_NODES + 1) * 4, 64);
    size_t p_bcnt = p;   p = alignup(p + (size_t)NBK2 * PAD * 4, 64);
    size_t p_gcur = p;   p = alignup(p + (size_t)NBK2 * PAD * 4, 64);
    size_t p_boff = p;   p = alignup(p + (size_t)(NBK2 + 1) * 4, 64);
    size_t need2 = p;

    if (ws_size >= need1) {
        // ---- x -> bf16 ----
        k_cvt<<<(nfeat / 8 + 255) / 256, 256, 0, stream>>>((const float4*)x, (uint4*)xh, nfeat / 8);
        // ---- CSR build ----
        hipMemsetAsync(bcnt, 0, (size_t)NBK2 * PAD * 4, stream);
        k_bhist<<<512, 256, 0, stream>>>(dst, bcnt);
        k_bscan<<<1, 256, 0, stream>>>(bcnt, boff, gcur);
        k_part<<<NPBLK, 256, 0, stream>>>(src, dst, gcur, eb);
        k_fill3<<<NBK2, 512, 0, stream>>>(eb, boff, off, es);

        // ---- layer 1 aggregate: A = segsum(xh)  (A overlays dead eb) ----
        k_gather<<<(N_NODES + 3) / 4, 256, 0, stream>>>(xh, es, off, nullptr, A);
        // ---- GEMM1: H = bf16(relu(A*W1+b1)), in place over A ----
        k_gemm1<<<N_NODES / MROWS, 256, 0, stream>>>(A, H, W1, b1);
        // ---- GEMM2: zh = bf16(H*W2) ----
        k_gemm2<<<N_NODES / MROWS, 256, 0, stream>>>(H, zh, W2);
        // ---- layer 2 aggregate + bias: out = b2 + segsum(zh) ----
        k_gather<<<(N_NODES + 3) / 4, 256, 0, stream>>>(zh, es, off, b2, out);
    } else if (ws_size >= need2) {
        float* A2  = (float*)(base + p_A);
        int* eb2   = (int*)(base + p_eb);
        int* es2   = (int*)(base + p_es);
        int* off2  = (int*)(base + p_off);
        int* bcnt2 = (int*)(base + p_bcnt);
        int* gcur2 = (int*)(base + p_gcur);
        int* boff2 = (int*)(base + p_boff);

        hipMemsetAsync(bcnt2, 0, (size_t)NBK2 * PAD * 4, stream);
        k_bhist<<<512, 256, 0, stream>>>(dst, bcnt2);
        k_bscan<<<1, 256, 0, stream>>>(bcnt2, boff2, gcur2);
        k_part<<<NPBLK, 256, 0, stream>>>(src, dst, gcur2, eb2);
        k_fill3<<<NBK2, 512, 0, stream>>>(eb2, boff2, off2, es2);

        k_gatherF<<<(N_NODES + 3) / 4, 256, 0, stream>>>(x, es2, off2, nullptr, A2);
        k_mlpF<<<N_NODES / MROWS, 256, 0, stream>>>(A2, W1, b1, W2);
        k_gatherF<<<(N_NODES + 3) / 4, 256, 0, stream>>>(A2, es2, off2, b2, out);
    } else {
        float* A3 = (float*)d_ws;
        k_zero_f4<<<(nfeat4 + 255) / 256, 256, 0, stream>>>((float4*)A3, nfeat4);
        int threads = N_EDGES * 16;
        k_scatter64<<<(threads + 255) / 256, 256, 0, stream>>>(x, src, dst, A3);
        k_mlpF<<<N_NODES / MROWS, 256, 0, stream>>>(A3, W1, b1, W2);
        k_init_bias<<<(nfeat + 255) / 256, 256, 0, stream>>>(out, b2, nfeat);
        k_scatter64<<<(threads + 255) / 256, 256, 0, stream>>>(A3, src, dst, out);
    }
}

// Round 12
// 205.582 us; speedup vs baseline: 7.6225x; 1.1185x over previous
//
#include <hip/hip_runtime.h>

#define N_NODES 100000
#define N_EDGES 1600000
#define IN_F 64
#define HID 128
#define N_CLS 64

#define NPB2 512                                // nodes per coarse bucket (d >> 9)
#define NBK2 ((N_NODES + NPB2 - 1) / NPB2)      // 196
#define PAD 16                                  // ints per padded global counter (64 B)
#define PCHUNK 8192                             // edges per k_part block
#define NPBLK ((N_EDGES + PCHUNK - 1) / PCHUNK) // 196

// ================= bf16 helpers =================
__device__ __forceinline__ unsigned short f2bf(float f) {
    unsigned int u = __float_as_uint(f);
    u = (u + 0x7FFFu + ((u >> 16) & 1u)) >> 16;   // RNE
    return (unsigned short)u;
}
__device__ __forceinline__ float bf2f(unsigned short h) {
    return __uint_as_float(((unsigned int)h) << 16);
}

// ================= generic helpers =================
__global__ void k_zero_f4(float4* __restrict__ p, int n4) {
    int i = blockIdx.x * blockDim.x + threadIdx.x;
    if (i < n4) p[i] = make_float4(0.f, 0.f, 0.f, 0.f);
}
__global__ void k_init_bias(float* __restrict__ out, const float* __restrict__ b2, int n) {
    int i = blockIdx.x * blockDim.x + threadIdx.x;
    if (i < n) out[i] = b2[i & 63];
}

// convert fp32 -> bf16, 8 elems/thread
__global__ void k_cvt(const float4* __restrict__ x4, uint4* __restrict__ xh, int n8) {
    int i = blockIdx.x * blockDim.x + threadIdx.x;
    if (i >= n8) return;
    float4 a = x4[2 * i], b = x4[2 * i + 1];
    uint4 o;
    o.x = (unsigned)f2bf(a.x) | ((unsigned)f2bf(a.y) << 16);
    o.y = (unsigned)f2bf(a.z) | ((unsigned)f2bf(a.w) << 16);
    o.z = (unsigned)f2bf(b.x) | ((unsigned)f2bf(b.y) << 16);
    o.w = (unsigned)f2bf(b.z) | ((unsigned)f2bf(b.w) << 16);
    xh[i] = o;
}

// ================= coarse bucket histogram (LDS-staged) =================
__global__ __launch_bounds__(256) void k_bhist(const int* __restrict__ dst,
                                               int* __restrict__ bcnt) {
    __shared__ int h[NBK2];
    for (int i = threadIdx.x; i < NBK2; i += 256) h[i] = 0;
    __syncthreads();
    int stride = gridDim.x * blockDim.x;
    for (int e = blockIdx.x * blockDim.x + threadIdx.x; e < N_EDGES; e += stride)
        atomicAdd(&h[dst[e] >> 9], 1);
    __syncthreads();
    for (int i = threadIdx.x; i < NBK2; i += 256) {
        int v = h[i];
        if (v) atomicAdd(&bcnt[i * PAD], v);
    }
}

__global__ __launch_bounds__(256) void k_bscan(const int* __restrict__ bcnt,
                                               int* __restrict__ boff,
                                               int* __restrict__ gcur) {
    __shared__ int s[NBK2];
    const int t = threadIdx.x;
    if (t < NBK2) s[t] = bcnt[t * PAD];
    __syncthreads();
    if (t == 0) {
        int run = 0;
        for (int i = 0; i < NBK2; ++i) { int v = s[i]; s[i] = run; run += v; }
    }
    __syncthreads();
    if (t < NBK2) { boff[t] = s[t]; gcur[t * PAD] = s[t]; }
    if (t == 0) boff[NBK2] = N_EDGES;
}

// ================= block-aggregated partition into coarse buckets =================
__global__ __launch_bounds__(256) void k_part(const int* __restrict__ src,
                                              const int* __restrict__ dst,
                                              int* __restrict__ gcur,
                                              int* __restrict__ eb) {
    __shared__ int hist[NBK2];
    __shared__ int gbase[NBK2];
    __shared__ int lcur[NBK2];
    const int t = threadIdx.x;
    const int e0 = blockIdx.x * PCHUNK;
    int e1 = e0 + PCHUNK; if (e1 > N_EDGES) e1 = N_EDGES;
    for (int i = t; i < NBK2; i += 256) hist[i] = 0;
    __syncthreads();
    for (int e = e0 + t; e < e1; e += 256) atomicAdd(&hist[dst[e] >> 9], 1);
    __syncthreads();
    if (t < NBK2) {
        int c = hist[t];
        gbase[t] = c ? atomicAdd(&gcur[t * PAD], c) : 0;
        lcur[t] = 0;
    }
    __syncthreads();
    for (int e = e0 + t; e < e1; e += 256) {
        int d = dst[e];
        int b = d >> 9;
        int r = atomicAdd(&lcur[b], 1);
        eb[gbase[b] + r] = ((d & 511) << 17) | src[e];   // dstLow(9b) | src(17b)
    }
}

// ================= per-bucket: node-degree hist + scan -> off; sort -> es =================
__global__ __launch_bounds__(512) void k_fill3(const int* __restrict__ eb,
                                               const int* __restrict__ boff,
                                               int* __restrict__ off,
                                               int* __restrict__ es) {
    __shared__ int ldeg[NPB2];
    __shared__ int sc[2][NPB2];
    const int t = threadIdx.x;
    const int b = blockIdx.x;
    const int bbase = boff[b], bend = boff[b + 1];

    ldeg[t] = 0;
    __syncthreads();
    for (int i = bbase + t; i < bend; i += 512) atomicAdd(&ldeg[eb[i] >> 17], 1);
    __syncthreads();

    int v = ldeg[t];
    sc[0][t] = v;
    __syncthreads();
    int cur = 0;
    for (int d = 1; d < NPB2; d <<= 1) {
        int x = sc[cur][t];
        if (t >= d) x += sc[cur][t - d];
        sc[cur ^ 1][t] = x;
        __syncthreads();
        cur ^= 1;
    }
    int ex = sc[cur][t] - v;

    const int n0 = b * NPB2;
    if (n0 + t < N_NODES) off[n0 + t] = bbase + ex;
    if (b == NBK2 - 1 && t == 0) off[N_NODES] = N_EDGES;

    ldeg[t] = ex;
    __syncthreads();

    for (int i = bbase + t; i < bend; i += 512) {
        int p = eb[i];
        int r = atomicAdd(&ldeg[p >> 17], 1);
        es[bbase + r] = p & 0x1FFFF;
    }
}

// ================= gather (bf16 feat, 2 nodes/wave): lanes 0-31 node A, 32-63 node B =================
// feat viewed as uint rows of 32 (2 bf16 per uint). Per edge: 1 shfl + 1 dword load per 32 lanes.
__global__ __launch_bounds__(256) void k_gather2(const unsigned* __restrict__ feat,
                                                 const int* __restrict__ es,
                                                 const int* __restrict__ off,
                                                 const float* __restrict__ bias,
                                                 float* __restrict__ out) {
    const int wave = threadIdx.x >> 6;
    const int lane = threadIdx.x & 63;
    const int half = lane >> 5;
    const int l32 = lane & 31;
    const int n = blockIdx.x * 8 + wave * 2 + half;    // 12500*8 == N_NODES exactly
    const int beg = off[n], end = off[n + 1];
    const int hb = half << 5;
    float acc0 = 0.f, acc1 = 0.f;
    for (int base = beg; base < end; base += 32) {
        int m = end - base; if (m > 32) m = 32;
        int id = (l32 < m) ? es[base + l32] : 0;
        int k = 0;
        for (; k + 4 <= m; k += 4) {
            int s0 = __shfl(id, hb | (k + 0));
            int s1 = __shfl(id, hb | (k + 1));
            int s2 = __shfl(id, hb | (k + 2));
            int s3 = __shfl(id, hb | (k + 3));
            unsigned u0 = feat[(unsigned)s0 * 32u + l32];
            unsigned u1 = feat[(unsigned)s1 * 32u + l32];
            unsigned u2 = feat[(unsigned)s2 * 32u + l32];
            unsigned u3 = feat[(unsigned)s3 * 32u + l32];
            acc0 += (__uint_as_float(u0 << 16) + __uint_as_float(u1 << 16))
                  + (__uint_as_float(u2 << 16) + __uint_as_float(u3 << 16));
            acc1 += (__uint_as_float(u0 & 0xFFFF0000u) + __uint_as_float(u1 & 0xFFFF0000u))
                  + (__uint_as_float(u2 & 0xFFFF0000u) + __uint_as_float(u3 & 0xFFFF0000u));
        }
        for (; k < m; ++k) {
            int s = __shfl(id, hb | k);
            unsigned u = feat[(unsigned)s * 32u + l32];
            acc0 += __uint_as_float(u << 16);
            acc1 += __uint_as_float(u & 0xFFFF0000u);
        }
    }
    if (bias) { acc0 += bias[l32 * 2]; acc1 += bias[l32 * 2 + 1]; }
    float2 o; o.x = acc0; o.y = acc1;
    *(float2*)&out[(size_t)n * 64 + l32 * 2] = o;
}

// ================= gather (fp32 feat): tier-2 =================
__global__ __launch_bounds__(256) void k_gatherF(const float* __restrict__ feat,
                                                 const int* __restrict__ es,
                                                 const int* __restrict__ off,
                                                 const float* __restrict__ bias,
                                                 float* __restrict__ out) {
    const int wave = threadIdx.x >> 6;
    const int lane = threadIdx.x & 63;
    const int n = blockIdx.x * 4 + wave;
    if (n >= N_NODES) return;
    const int beg = off[n], end = off[n + 1];
    float acc = bias ? bias[lane] : 0.f;
    for (int base = beg; base < end; base += 64) {
        int m = end - base; if (m > 64) m = 64;
        int id = (lane < m) ? es[base + lane] : 0;
        int k = 0;
        for (; k + 4 <= m; k += 4) {
            int s0 = __shfl(id, k), s1 = __shfl(id, k + 1);
            int s2 = __shfl(id, k + 2), s3 = __shfl(id, k + 3);
            float v0 = feat[(size_t)s0 * 64 + lane];
            float v1 = feat[(size_t)s1 * 64 + lane];
            float v2 = feat[(size_t)s2 * 64 + lane];
            float v3 = feat[(size_t)s3 * 64 + lane];
            acc += (v0 + v1) + (v2 + v3);
        }
        for (; k < m; ++k) {
            int s = __shfl(id, k);
            acc += feat[(size_t)s * 64 + lane];
        }
    }
    out[(size_t)n * 64 + lane] = acc;
}

// ================= fallback atomic scatter =================
__global__ void k_scatter64(const float* __restrict__ feat,
                            const int* __restrict__ src,
                            const int* __restrict__ dst,
                            float* __restrict__ out) {
    int i = blockIdx.x * blockDim.x + threadIdx.x;
    int e = i >> 4;
    if (e >= N_EDGES) return;
    int j = (i & 15) << 2;
    int s = src[e];
    int d = dst[e];
    float4 v = *reinterpret_cast<const float4*>(feat + (size_t)s * 64 + j);
    float* o = out + (size_t)d * 64 + j;
    atomicAdd(o + 0, v.x);
    atomicAdd(o + 1, v.y);
    atomicAdd(o + 2, v.z);
    atomicAdd(o + 3, v.w);
}

// ================= split GEMMs =================
#define MROWS 32
#define XS_S 68      // float stride for x rows
#define HS2_S 152    // ushort stride for h rows (304 B, 16B-aligned)

__device__ __forceinline__ void fma4(float4& a, float s, const float4& wv) {
    a.x = fmaf(s, wv.x, a.x);
    a.y = fmaf(s, wv.y, a.y);
    a.z = fmaf(s, wv.z, a.z);
    a.w = fmaf(s, wv.w, a.w);
}

// GEMM1: H(bf16, stride 128, overlays A) = relu(A*W1 + b1)
__global__ __launch_bounds__(256, 3) void k_gemm1(const float* __restrict__ A,
                                                  unsigned short* __restrict__ H,
                                                  const float* __restrict__ W1,
                                                  const float* __restrict__ b1) {
    __shared__ float Ws[64 * 128];          // 32 KB
    __shared__ float xs[MROWS * XS_S];      // 8.7 KB
    __shared__ float b1s[128];
    const int t = threadIdx.x;
    const int row0 = blockIdx.x * MROWS;

    {
        const float4* w4 = (const float4*)W1;
        float4* s4 = (float4*)Ws;
        for (int i = t; i < 2048; i += 256) s4[i] = w4[i];
    }
    if (t < 128) b1s[t] = b1[t];
#pragma unroll
    for (int c = 0; c < 2; ++c) {
        int lin = t + c * 256;
        int r = lin >> 4, k4 = lin & 15;
        float4 v = *(const float4*)(A + (size_t)(row0 + r) * 64 + k4 * 4);
        *(float4*)&xs[r * XS_S + k4 * 4] = v;
    }
    __syncthreads();   // all A-reads done before in-place H writes

    const int rg = t >> 5, cg = t & 31;
    const int r0 = rg * 4, c0 = cg * 4;
    float4 bv = *(const float4*)&b1s[c0];
    float4 acc0 = bv, acc1 = bv, acc2 = bv, acc3 = bv;
#pragma unroll 4
    for (int k4 = 0; k4 < 16; ++k4) {
        float4 a0 = *(const float4*)&xs[(r0 + 0) * XS_S + k4 * 4];
        float4 a1 = *(const float4*)&xs[(r0 + 1) * XS_S + k4 * 4];
        float4 a2 = *(const float4*)&xs[(r0 + 2) * XS_S + k4 * 4];
        float4 a3 = *(const float4*)&xs[(r0 + 3) * XS_S + k4 * 4];
        float4 w0 = *(const float4*)&Ws[(k4 * 4 + 0) * 128 + c0];
        float4 w1 = *(const float4*)&Ws[(k4 * 4 + 1) * 128 + c0];
        float4 w2 = *(const float4*)&Ws[(k4 * 4 + 2) * 128 + c0];
        float4 w3 = *(const float4*)&Ws[(k4 * 4 + 3) * 128 + c0];
        fma4(acc0, a0.x, w0); fma4(acc0, a0.y, w1); fma4(acc0, a0.z, w2); fma4(acc0, a0.w, w3);
        fma4(acc1, a1.x, w0); fma4(acc1, a1.y, w1); fma4(acc1, a1.z, w2); fma4(acc1, a1.w, w3);
        fma4(acc2, a2.x, w0); fma4(acc2, a2.y, w1); fma4(acc2, a2.z, w2); fma4(acc2, a2.w, w3);
        fma4(acc3, a3.x, w0); fma4(acc3, a3.y, w1); fma4(acc3, a3.z, w2); fma4(acc3, a3.w, w3);
    }
    ushort4 o;
    o.x = f2bf(fmaxf(acc0.x, 0.f)); o.y = f2bf(fmaxf(acc0.y, 0.f));
    o.z = f2bf(fmaxf(acc0.z, 0.f)); o.w = f2bf(fmaxf(acc0.w, 0.f));
    *(ushort4*)&H[(size_t)(row0 + r0 + 0) * 128 + c0] = o;
    o.x = f2bf(fmaxf(acc1.x, 0.f)); o.y = f2bf(fmaxf(acc1.y, 0.f));
    o.z = f2bf(fmaxf(acc1.z, 0.f)); o.w = f2bf(fmaxf(acc1.w, 0.f));
    *(ushort4*)&H[(size_t)(row0 + r0 + 1) * 128 + c0] = o;
    o.x = f2bf(fmaxf(acc2.x, 0.f)); o.y = f2bf(fmaxf(acc2.y, 0.f));
    o.z = f2bf(fmaxf(acc2.z, 0.f)); o.w = f2bf(fmaxf(acc2.w, 0.f));
    *(ushort4*)&H[(size_t)(row0 + r0 + 2) * 128 + c0] = o;
    o.x = f2bf(fmaxf(acc3.x, 0.f)); o.y = f2bf(fmaxf(acc3.y, 0.f));
    o.z = f2bf(fmaxf(acc3.z, 0.f)); o.w = f2bf(fmaxf(acc3.w, 0.f));
    *(ushort4*)&H[(size_t)(row0 + r0 + 3) * 128 + c0] = o;
}

// GEMM2: zh(bf16) = H(bf16) * W2
__global__ __launch_bounds__(256, 3) void k_gemm2(const unsigned short* __restrict__ H,
                                                  unsigned short* __restrict__ zh,
                                                  const float* __restrict__ W2) {
    __shared__ float Ws[128 * 64];                 // 32 KB
    __shared__ unsigned short hsb[MROWS * HS2_S];  // 9.5 KB
    const int t = threadIdx.x;
    const int row0 = blockIdx.x * MROWS;

    {
        const float4* w4 = (const float4*)W2;
        float4* s4 = (float4*)Ws;
        for (int i = t; i < 2048; i += 256) s4[i] = w4[i];
    }
    // stage h rows: 32 rows x 128 bf16 = 512 uint4
#pragma unroll
    for (int c = 0; c < 2; ++c) {
        int lin = t + c * 256;
        int r = lin >> 4, k8 = lin & 15;
        uint4 v = *(const uint4*)(H + (size_t)(row0 + r) * 128 + k8 * 8);
        *(uint4*)&hsb[r * HS2_S + k8 * 8] = v;
    }
    __syncthreads();

    const int rg = t >> 4, cg = t & 15;
    const int r0 = rg * 2, c0 = cg * 4;
    float4 acc0 = make_float4(0.f, 0.f, 0.f, 0.f);
    float4 acc1 = make_float4(0.f, 0.f, 0.f, 0.f);
#pragma unroll 4
    for (int k4 = 0; k4 < 32; ++k4) {
        ushort4 u0 = *(const ushort4*)&hsb[(r0 + 0) * HS2_S + k4 * 4];
        ushort4 u1 = *(const ushort4*)&hsb[(r0 + 1) * HS2_S + k4 * 4];
        float4 w0 = *(const float4*)&Ws[(k4 * 4 + 0) * 64 + c0];
        float4 w1 = *(const float4*)&Ws[(k4 * 4 + 1) * 64 + c0];
        float4 w2 = *(const float4*)&Ws[(k4 * 4 + 2) * 64 + c0];
        float4 w3 = *(const float4*)&Ws[(k4 * 4 + 3) * 64 + c0];
        fma4(acc0, bf2f(u0.x), w0); fma4(acc0, bf2f(u0.y), w1);
        fma4(acc0, bf2f(u0.z), w2); fma4(acc0, bf2f(u0.w), w3);
        fma4(acc1, bf2f(u1.x), w0); fma4(acc1, bf2f(u1.y), w1);
        fma4(acc1, bf2f(u1.z), w2); fma4(acc1, bf2f(u1.w), w3);
    }
    ushort4 o0, o1;
    o0.x = f2bf(acc0.x); o0.y = f2bf(acc0.y); o0.z = f2bf(acc0.z); o0.w = f2bf(acc0.w);
    o1.x = f2bf(acc1.x); o1.y = f2bf(acc1.y); o1.z = f2bf(acc1.z); o1.w = f2bf(acc1.w);
    *(ushort4*)&zh[(size_t)(row0 + r0 + 0) * 64 + c0] = o0;
    *(ushort4*)&zh[(size_t)(row0 + r0 + 1) * 64 + c0] = o1;
}

// fp32 in-place MLP (tier-2/3 fallback)
__global__ __launch_bounds__(256, 2) void k_mlpF(float* __restrict__ A,
                                                 const float* __restrict__ W1,
                                                 const float* __restrict__ b1,
                                                 const float* __restrict__ W2) {
    __shared__ float Ws[64 * 128];
    __shared__ float xs[MROWS * XS_S];
    __shared__ float hs[MROWS * 132];
    __shared__ float b1s[128];
    const int t = threadIdx.x;
    const int row0 = blockIdx.x * MROWS;

    {
        const float4* w4 = (const float4*)W1;
        float4* s4 = (float4*)Ws;
        for (int i = t; i < 2048; i += 256) s4[i] = w4[i];
    }
    if (t < 128) b1s[t] = b1[t];
#pragma unroll
    for (int c = 0; c < 2; ++c) {
        int lin = t + c * 256;
        int r = lin >> 4, k4 = lin & 15;
        float4 v = *(const float4*)(A + (size_t)(row0 + r) * 64 + k4 * 4);
        *(float4*)&xs[r * XS_S + k4 * 4] = v;
    }
    __syncthreads();
    {
        const int rg = t >> 5, cg = t & 31;
        const int r0 = rg * 4, c0 = cg * 4;
        float4 bv = *(const float4*)&b1s[c0];
        float4 acc0 = bv, acc1 = bv, acc2 = bv, acc3 = bv;
#pragma unroll 4
        for (int k4 = 0; k4 < 16; ++k4) {
            float4 a0 = *(const float4*)&xs[(r0 + 0) * XS_S + k4 * 4];
            float4 a1 = *(const float4*)&xs[(r0 + 1) * XS_S + k4 * 4];
            float4 a2 = *(const float4*)&xs[(r0 + 2) * XS_S + k4 * 4];
            float4 a3 = *(const float4*)&xs[(r0 + 3) * XS_S + k4 * 4];
            float4 w0 = *(const float4*)&Ws[(k4 * 4 + 0) * 128 + c0];
            float4 w1 = *(const float4*)&Ws[(k4 * 4 + 1) * 128 + c0];
            float4 w2 = *(const float4*)&Ws[(k4 * 4 + 2) * 128 + c0];
            float4 w3 = *(const float4*)&Ws[(k4 * 4 + 3) * 128 + c0];
            fma4(acc0, a0.x, w0); fma4(acc0, a0.y, w1); fma4(acc0, a0.z, w2); fma4(acc0, a0.w, w3);
            fma4(acc1, a1.x, w0); fma4(acc1, a1.y, w1); fma4(acc1, a1.z, w2); fma4(acc1, a1.w, w3);
            fma4(acc2, a2.x, w0); fma4(acc2, a2.y, w1); fma4(acc2, a2.z, w2); fma4(acc2, a2.w, w3);
            fma4(acc3, a3.x, w0); fma4(acc3, a3.y, w1); fma4(acc3, a3.z, w2); fma4(acc3, a3.w, w3);
        }
        float4 h;
        h.x = fmaxf(acc0.x, 0.f); h.y = fmaxf(acc0.y, 0.f); h.z = fmaxf(acc0.z, 0.f); h.w = fmaxf(acc0.w, 0.f);
        *(float4*)&hs[(r0 + 0) * 132 + c0] = h;
        h.x = fmaxf(acc1.x, 0.f); h.y = fmaxf(acc1.y, 0.f); h.z = fmaxf(acc1.z, 0.f); h.w = fmaxf(acc1.w, 0.f);
        *(float4*)&hs[(r0 + 1) * 132 + c0] = h;
        h.x = fmaxf(acc2.x, 0.f); h.y = fmaxf(acc2.y, 0.f); h.z = fmaxf(acc2.z, 0.f); h.w = fmaxf(acc2.w, 0.f);
        *(float4*)&hs[(r0 + 2) * 132 + c0] = h;
        h.x = fmaxf(acc3.x, 0.f); h.y = fmaxf(acc3.y, 0.f); h.z = fmaxf(acc3.z, 0.f); h.w = fmaxf(acc3.w, 0.f);
        *(float4*)&hs[(r0 + 3) * 132 + c0] = h;
    }
    __syncthreads();
    {
        const float4* w4 = (const float4*)W2;
        float4* s4 = (float4*)Ws;
        for (int i = t; i < 2048; i += 256) s4[i] = w4[i];
    }
    __syncthreads();
    {
        const int rg = t >> 4, cg = t & 15;
        const int r0 = rg * 2, c0 = cg * 4;
        float4 acc0 = make_float4(0.f, 0.f, 0.f, 0.f);
        float4 acc1 = make_float4(0.f, 0.f, 0.f, 0.f);
#pragma unroll 4
        for (int k4 = 0; k4 < 32; ++k4) {
            float4 h0 = *(const float4*)&hs[(r0 + 0) * 132 + k4 * 4];
            float4 h1 = *(const float4*)&hs[(r0 + 1) * 132 + k4 * 4];
            float4 w0 = *(const float4*)&Ws[(k4 * 4 + 0) * 64 + c0];
            float4 w1 = *(const float4*)&Ws[(k4 * 4 + 1) * 64 + c0];
            float4 w2 = *(const float4*)&Ws[(k4 * 4 + 2) * 64 + c0];
            float4 w3 = *(const float4*)&Ws[(k4 * 4 + 3) * 64 + c0];
            fma4(acc0, h0.x, w0); fma4(acc0, h0.y, w1); fma4(acc0, h0.z, w2); fma4(acc0, h0.w, w3);
            fma4(acc1, h1.x, w0); fma4(acc1, h1.y, w1); fma4(acc1, h1.z, w2); fma4(acc1, h1.w, w3);
        }
        *(float4*)(A + (size_t)(row0 + r0 + 0) * 64 + c0) = acc0;
        *(float4*)(A + (size_t)(row0 + r0 + 1) * 64 + c0) = acc1;
    }
}

static inline size_t alignup(size_t v, size_t a) { return (v + a - 1) & ~(a - 1); }

extern "C" void kernel_launch(void* const* d_in, const int* in_sizes, int n_in,
                              void* d_out, int out_size, void* d_ws, size_t ws_size,
                              hipStream_t stream) {
    const float* x  = (const float*)d_in[0];
    const float* W1 = (const float*)d_in[1];
    const float* b1 = (const float*)d_in[2];
    const float* W2 = (const float*)d_in[3];
    const float* b2 = (const float*)d_in[4];
    const int* src  = (const int*)d_in[5];
    const int* dst  = (const int*)d_in[6];
    float* out = (float*)d_out;

    const int nfeat = N_NODES * 64;
    const int nfeat4 = nfeat / 4;

    // ---- tier-1 layout (64B-aligned fields) ----
    char* base = (char*)d_ws;
    size_t o = 0;
    size_t o_xh   = o;                  o = alignup(o + (size_t)nfeat * 2, 64);          // 12.8 MB
    size_t o_es   = o;                  o = alignup(o + (size_t)N_EDGES * 4, 64);        // 6.4 MB
    size_t o_off  = o;                  o = alignup(o + (size_t)(N_NODES + 1) * 4, 64);
    size_t o_bcnt = o;                  o = alignup(o + (size_t)NBK2 * PAD * 4, 64);
    size_t o_gcur = o;                  o = alignup(o + (size_t)NBK2 * PAD * 4, 64);
    size_t o_boff = o;                  o = alignup(o + (size_t)(NBK2 + 1) * 4, 64);
    size_t o_shrd = o;                  o = alignup(o + (size_t)nfeat * 4, 64);          // eb / A / H share
    size_t need1 = o;

    unsigned short* xh = (unsigned short*)(base + o_xh);
    int* es    = (int*)(base + o_es);
    int* off   = (int*)(base + o_off);
    int* bcnt  = (int*)(base + o_bcnt);
    int* gcur  = (int*)(base + o_gcur);
    int* boff  = (int*)(base + o_boff);
    int* eb    = (int*)(base + o_shrd);
    float* A   = (float*)(base + o_shrd);
    unsigned short* H = (unsigned short*)(base + o_shrd);   // bf16 h overlays A in place
    unsigned short* zh = xh;                                 // z overlays dead xh

    // ---- tier-2 layout: fp32 path ----
    size_t p = 0;
    size_t p_A    = p;   p = alignup(p + (size_t)nfeat * 4, 64);
    size_t p_eb   = p;   p = alignup(p + (size_t)N_EDGES * 4, 64);
    size_t p_es   = p;   p = alignup(p + (size_t)N_EDGES * 4, 64);
    size_t p_off  = p;   p = alignup(p + (size_t)(N_NODES + 1) * 4, 64);
    size_t p_bcnt = p;   p = alignup(p + (size_t)NBK2 * PAD * 4, 64);
    size_t p_gcur = p;   p = alignup(p + (size_t)NBK2 * PAD * 4, 64);
    size_t p_boff = p;   p = alignup(p + (size_t)(NBK2 + 1) * 4, 64);
    size_t need2 = p;

    if (ws_size >= need1) {
        // ---- x -> bf16 ----
        k_cvt<<<(nfeat / 8 + 255) / 256, 256, 0, stream>>>((const float4*)x, (uint4*)xh, nfeat / 8);
        // ---- CSR build ----
        hipMemsetAsync(bcnt, 0, (size_t)NBK2 * PAD * 4, stream);
        k_bhist<<<512, 256, 0, stream>>>(dst, bcnt);
        k_bscan<<<1, 256, 0, stream>>>(bcnt, boff, gcur);
        k_part<<<NPBLK, 256, 0, stream>>>(src, dst, gcur, eb);
        k_fill3<<<NBK2, 512, 0, stream>>>(eb, boff, off, es);

        // ---- layer 1 aggregate: A = segsum(xh)  (A overlays dead eb) ----
        k_gather2<<<N_NODES / 8, 256, 0, stream>>>((const unsigned*)xh, es, off, nullptr, A);
        // ---- GEMM1: H = bf16(relu(A*W1+b1)), in place over A ----
        k_gemm1<<<N_NODES / MROWS, 256, 0, stream>>>(A, H, W1, b1);
        // ---- GEMM2: zh = bf16(H*W2) ----
        k_gemm2<<<N_NODES / MROWS, 256, 0, stream>>>(H, zh, W2);
        // ---- layer 2 aggregate + bias: out = b2 + segsum(zh) ----
        k_gather2<<<N_NODES / 8, 256, 0, stream>>>((const unsigned*)zh, es, off, b2, out);
    } else if (ws_size >= need2) {
        float* A2  = (float*)(base + p_A);
        int* eb2   = (int*)(base + p_eb);
        int* es2   = (int*)(base + p_es);
        int* off2  = (int*)(base + p_off);
        int* bcnt2 = (int*)(base + p_bcnt);
        int* gcur2 = (int*)(base + p_gcur);
        int* boff2 = (int*)(base + p_boff);

        hipMemsetAsync(bcnt2, 0, (size_t)NBK2 * PAD * 4, stream);
        k_bhist<<<512, 256, 0, stream>>>(dst, bcnt2);
        k_bscan<<<1, 256, 0, stream>>>(bcnt2, boff2, gcur2);
        k_part<<<NPBLK, 256, 0, stream>>>(src, dst, gcur2, eb2);
        k_fill3<<<NBK2, 512, 0, stream>>>(eb2, boff2, off2, es2);

        k_gatherF<<<(N_NODES + 3) / 4, 256, 0, stream>>>(x, es2, off2, nullptr, A2);
        k_mlpF<<<N_NODES / MROWS, 256, 0, stream>>>(A2, W1, b1, W2);
        k_gatherF<<<(N_NODES + 3) / 4, 256, 0, stream>>>(A2, es2, off2, b2, out);
    } else {
        float* A3 = (float*)d_ws;
        k_zero_f4<<<(nfeat4 + 255) / 256, 256, 0, stream>>>((float4*)A3, nfeat4);
        int threads = N_EDGES * 16;
        k_scatter64<<<(threads + 255) / 256, 256, 0, stream>>>(x, src, dst, A3);
        k_mlpF<<<N_NODES / MROWS, 256, 0, stream>>>(A3, W1, b1, W2);
        k_init_bias<<<(nfeat + 255) / 256, 256, 0, stream>>>(out, b2, nfeat);
        k_scatter64<<<(threads + 255) / 256, 256, 0, stream>>>(A3, src, dst, out);
    }
}

// Round 13
// 203.938 us; speedup vs baseline: 7.6839x; 1.0081x over previous
//
#include <hip/hip_runtime.h>

#define N_NODES 100000
#define N_EDGES 1600000
#define IN_F 64
#define HID 128
#define N_CLS 64

#define NPB2 512                                // nodes per coarse bucket (d >> 9)
#define NBK2 ((N_NODES + NPB2 - 1) / NPB2)      // 196
#define PAD 16                                  // ints per padded global counter (64 B)
#define PCHUNK 2048                             // edges per k_part block
#define NPBLK ((N_EDGES + PCHUNK - 1) / PCHUNK) // 782

// ================= bf16 helpers =================
__device__ __forceinline__ unsigned short f2bf(float f) {
    unsigned int u = __float_as_uint(f);
    u = (u + 0x7FFFu + ((u >> 16) & 1u)) >> 16;   // RNE
    return (unsigned short)u;
}
__device__ __forceinline__ float bf2f(unsigned short h) {
    return __uint_as_float(((unsigned int)h) << 16);
}

// ================= generic helpers =================
__global__ void k_zero_f4(float4* __restrict__ p, int n4) {
    int i = blockIdx.x * blockDim.x + threadIdx.x;
    if (i < n4) p[i] = make_float4(0.f, 0.f, 0.f, 0.f);
}
__global__ void k_zero_i(int* __restrict__ p, int n) {
    int i = blockIdx.x * blockDim.x + threadIdx.x;
    if (i < n) p[i] = 0;
}
__global__ void k_init_bias(float* __restrict__ out, const float* __restrict__ b2, int n) {
    int i = blockIdx.x * blockDim.x + threadIdx.x;
    if (i < n) out[i] = b2[i & 63];
}

// convert fp32 -> bf16, 8 elems/thread
__global__ void k_cvt(const float4* __restrict__ x4, uint4* __restrict__ xh, int n8) {
    int i = blockIdx.x * blockDim.x + threadIdx.x;
    if (i >= n8) return;
    float4 a = x4[2 * i], b = x4[2 * i + 1];
    uint4 o;
    o.x = (unsigned)f2bf(a.x) | ((unsigned)f2bf(a.y) << 16);
    o.y = (unsigned)f2bf(a.z) | ((unsigned)f2bf(a.w) << 16);
    o.z = (unsigned)f2bf(b.x) | ((unsigned)f2bf(b.y) << 16);
    o.w = (unsigned)f2bf(b.z) | ((unsigned)f2bf(b.w) << 16);
    xh[i] = o;
}

// ================= coarse bucket histogram (LDS-staged) =================
__global__ __launch_bounds__(256) void k_bhist(const int* __restrict__ dst,
                                               int* __restrict__ bcnt) {
    __shared__ int h[NBK2];
    for (int i = threadIdx.x; i < NBK2; i += 256) h[i] = 0;
    __syncthreads();
    int stride = gridDim.x * blockDim.x;
    for (int e = blockIdx.x * blockDim.x + threadIdx.x; e < N_EDGES; e += stride)
        atomicAdd(&h[dst[e] >> 9], 1);
    __syncthreads();
    for (int i = threadIdx.x; i < NBK2; i += 256) {
        int v = h[i];
        if (v) atomicAdd(&bcnt[i * PAD], v);
    }
}

__global__ __launch_bounds__(256) void k_bscan(const int* __restrict__ bcnt,
                                               int* __restrict__ boff,
                                               int* __restrict__ gcur) {
    __shared__ int s[NBK2];
    const int t = threadIdx.x;
    if (t < NBK2) s[t] = bcnt[t * PAD];
    __syncthreads();
    if (t == 0) {
        int run = 0;
        for (int i = 0; i < NBK2; ++i) { int v = s[i]; s[i] = run; run += v; }
    }
    __syncthreads();
    if (t < NBK2) { boff[t] = s[t]; gcur[t * PAD] = s[t]; }
    if (t == 0) boff[NBK2] = N_EDGES;
}

// ================= block-aggregated partition into coarse buckets =================
__global__ __launch_bounds__(256) void k_part(const int* __restrict__ src,
                                              const int* __restrict__ dst,
                                              int* __restrict__ gcur,
                                              int* __restrict__ eb) {
    __shared__ int hist[NBK2];
    __shared__ int gbase[NBK2];
    __shared__ int lcur[NBK2];
    const int t = threadIdx.x;
    const int e0 = blockIdx.x * PCHUNK;
    int e1 = e0 + PCHUNK; if (e1 > N_EDGES) e1 = N_EDGES;
    for (int i = t; i < NBK2; i += 256) hist[i] = 0;
    __syncthreads();
    for (int e = e0 + t; e < e1; e += 256) atomicAdd(&hist[dst[e] >> 9], 1);
    __syncthreads();
    if (t < NBK2) {
        int c = hist[t];
        gbase[t] = c ? atomicAdd(&gcur[t * PAD], c) : 0;
        lcur[t] = 0;
    }
    __syncthreads();
    for (int e = e0 + t; e < e1; e += 256) {
        int d = dst[e];
        int b = d >> 9;
        int r = atomicAdd(&lcur[b], 1);
        eb[gbase[b] + r] = ((d & 511) << 17) | src[e];   // dstLow(9b) | src(17b)
    }
}

// ================= per-bucket: node-degree hist + scan -> off; sort -> es =================
__global__ __launch_bounds__(512) void k_fill3(const int* __restrict__ eb,
                                               const int* __restrict__ boff,
                                               int* __restrict__ off,
                                               int* __restrict__ es) {
    __shared__ int ldeg[NPB2];
    __shared__ int sc[2][NPB2];
    const int t = threadIdx.x;
    const int b = blockIdx.x;
    const int bbase = boff[b], bend = boff[b + 1];

    ldeg[t] = 0;
    __syncthreads();
    for (int i = bbase + t; i < bend; i += 512) atomicAdd(&ldeg[eb[i] >> 17], 1);
    __syncthreads();

    int v = ldeg[t];
    sc[0][t] = v;
    __syncthreads();
    int cur = 0;
    for (int d = 1; d < NPB2; d <<= 1) {
        int x = sc[cur][t];
        if (t >= d) x += sc[cur][t - d];
        sc[cur ^ 1][t] = x;
        __syncthreads();
        cur ^= 1;
    }
    int ex = sc[cur][t] - v;

    const int n0 = b * NPB2;
    if (n0 + t < N_NODES) off[n0 + t] = bbase + ex;
    if (b == NBK2 - 1 && t == 0) off[N_NODES] = N_EDGES;

    ldeg[t] = ex;
    __syncthreads();

    for (int i = bbase + t; i < bend; i += 512) {
        int p = eb[i];
        int r = atomicAdd(&ldeg[p >> 17], 1);
        es[bbase + r] = p & 0x1FFFF;
    }
}

// ================= gather (bf16 feat, 2 nodes/wave): lanes 0-31 node A, 32-63 node B =================
__global__ __launch_bounds__(256) void k_gather2(const unsigned* __restrict__ feat,
                                                 const int* __restrict__ es,
                                                 const int* __restrict__ off,
                                                 const float* __restrict__ bias,
                                                 float* __restrict__ out) {
    const int wave = threadIdx.x >> 6;
    const int lane = threadIdx.x & 63;
    const int half = lane >> 5;
    const int l32 = lane & 31;
    const int n = blockIdx.x * 8 + wave * 2 + half;    // 12500*8 == N_NODES exactly
    const int beg = off[n], end = off[n + 1];
    const int hb = half << 5;
    float acc0 = 0.f, acc1 = 0.f;
    for (int base = beg; base < end; base += 32) {
        int m = end - base; if (m > 32) m = 32;
        int id = (l32 < m) ? es[base + l32] : 0;
        int k = 0;
        for (; k + 4 <= m; k += 4) {
            int s0 = __shfl(id, hb | (k + 0));
            int s1 = __shfl(id, hb | (k + 1));
            int s2 = __shfl(id, hb | (k + 2));
            int s3 = __shfl(id, hb | (k + 3));
            unsigned u0 = feat[(unsigned)s0 * 32u + l32];
            unsigned u1 = feat[(unsigned)s1 * 32u + l32];
            unsigned u2 = feat[(unsigned)s2 * 32u + l32];
            unsigned u3 = feat[(unsigned)s3 * 32u + l32];
            acc0 += (__uint_as_float(u0 << 16) + __uint_as_float(u1 << 16))
                  + (__uint_as_float(u2 << 16) + __uint_as_float(u3 << 16));
            acc1 += (__uint_as_float(u0 & 0xFFFF0000u) + __uint_as_float(u1 & 0xFFFF0000u))
                  + (__uint_as_float(u2 & 0xFFFF0000u) + __uint_as_float(u3 & 0xFFFF0000u));
        }
        for (; k < m; ++k) {
            int s = __shfl(id, hb | k);
            unsigned u = feat[(unsigned)s * 32u + l32];
            acc0 += __uint_as_float(u << 16);
            acc1 += __uint_as_float(u & 0xFFFF0000u);
        }
    }
    if (bias) { acc0 += bias[l32 * 2]; acc1 += bias[l32 * 2 + 1]; }
    float2 o; o.x = acc0; o.y = acc1;
    *(float2*)&out[(size_t)n * 64 + l32 * 2] = o;
}

// ================= gather (fp32 feat): tier-2 =================
__global__ __launch_bounds__(256) void k_gatherF(const float* __restrict__ feat,
                                                 const int* __restrict__ es,
                                                 const int* __restrict__ off,
                                                 const float* __restrict__ bias,
                                                 float* __restrict__ out) {
    const int wave = threadIdx.x >> 6;
    const int lane = threadIdx.x & 63;
    const int n = blockIdx.x * 4 + wave;
    if (n >= N_NODES) return;
    const int beg = off[n], end = off[n + 1];
    float acc = bias ? bias[lane] : 0.f;
    for (int base = beg; base < end; base += 64) {
        int m = end - base; if (m > 64) m = 64;
        int id = (lane < m) ? es[base + lane] : 0;
        int k = 0;
        for (; k + 4 <= m; k += 4) {
            int s0 = __shfl(id, k), s1 = __shfl(id, k + 1);
            int s2 = __shfl(id, k + 2), s3 = __shfl(id, k + 3);
            float v0 = feat[(size_t)s0 * 64 + lane];
            float v1 = feat[(size_t)s1 * 64 + lane];
            float v2 = feat[(size_t)s2 * 64 + lane];
            float v3 = feat[(size_t)s3 * 64 + lane];
            acc += (v0 + v1) + (v2 + v3);
        }
        for (; k < m; ++k) {
            int s = __shfl(id, k);
            acc += feat[(size_t)s * 64 + lane];
        }
    }
    out[(size_t)n * 64 + lane] = acc;
}

// ================= fallback atomic scatter =================
__global__ void k_scatter64(const float* __restrict__ feat,
                            const int* __restrict__ src,
                            const int* __restrict__ dst,
                            float* __restrict__ out) {
    int i = blockIdx.x * blockDim.x + threadIdx.x;
    int e = i >> 4;
    if (e >= N_EDGES) return;
    int j = (i & 15) << 2;
    int s = src[e];
    int d = dst[e];
    float4 v = *reinterpret_cast<const float4*>(feat + (size_t)s * 64 + j);
    float* o = out + (size_t)d * 64 + j;
    atomicAdd(o + 0, v.x);
    atomicAdd(o + 1, v.y);
    atomicAdd(o + 2, v.z);
    atomicAdd(o + 3, v.w);
}

// ================= split GEMMs =================
#define MROWS 32
#define XS_S 68      // float stride for x rows
#define HS2_S 152    // ushort stride for h rows (304 B, 16B-aligned)

__device__ __forceinline__ void fma4(float4& a, float s, const float4& wv) {
    a.x = fmaf(s, wv.x, a.x);
    a.y = fmaf(s, wv.y, a.y);
    a.z = fmaf(s, wv.z, a.z);
    a.w = fmaf(s, wv.w, a.w);
}

// GEMM1: H(bf16, stride 128, overlays A) = relu(A*W1 + b1)
__global__ __launch_bounds__(256, 3) void k_gemm1(const float* __restrict__ A,
                                                  unsigned short* __restrict__ H,
                                                  const float* __restrict__ W1,
                                                  const float* __restrict__ b1) {
    __shared__ float Ws[64 * 128];          // 32 KB
    __shared__ float xs[MROWS * XS_S];      // 8.7 KB
    __shared__ float b1s[128];
    const int t = threadIdx.x;
    const int row0 = blockIdx.x * MROWS;

    {
        const float4* w4 = (const float4*)W1;
        float4* s4 = (float4*)Ws;
        for (int i = t; i < 2048; i += 256) s4[i] = w4[i];
    }
    if (t < 128) b1s[t] = b1[t];
#pragma unroll
    for (int c = 0; c < 2; ++c) {
        int lin = t + c * 256;
        int r = lin >> 4, k4 = lin & 15;
        float4 v = *(const float4*)(A + (size_t)(row0 + r) * 64 + k4 * 4);
        *(float4*)&xs[r * XS_S + k4 * 4] = v;
    }
    __syncthreads();   // all A-reads done before in-place H writes

    const int rg = t >> 5, cg = t & 31;
    const int r0 = rg * 4, c0 = cg * 4;
    float4 bv = *(const float4*)&b1s[c0];
    float4 acc0 = bv, acc1 = bv, acc2 = bv, acc3 = bv;
#pragma unroll 4
    for (int k4 = 0; k4 < 16; ++k4) {
        float4 a0 = *(const float4*)&xs[(r0 + 0) * XS_S + k4 * 4];
        float4 a1 = *(const float4*)&xs[(r0 + 1) * XS_S + k4 * 4];
        float4 a2 = *(const float4*)&xs[(r0 + 2) * XS_S + k4 * 4];
        float4 a3 = *(const float4*)&xs[(r0 + 3) * XS_S + k4 * 4];
        float4 w0 = *(const float4*)&Ws[(k4 * 4 + 0) * 128 + c0];
        float4 w1 = *(const float4*)&Ws[(k4 * 4 + 1) * 128 + c0];
        float4 w2 = *(const float4*)&Ws[(k4 * 4 + 2) * 128 + c0];
        float4 w3 = *(const float4*)&Ws[(k4 * 4 + 3) * 128 + c0];
        fma4(acc0, a0.x, w0); fma4(acc0, a0.y, w1); fma4(acc0, a0.z, w2); fma4(acc0, a0.w, w3);
        fma4(acc1, a1.x, w0); fma4(acc1, a1.y, w1); fma4(acc1, a1.z, w2); fma4(acc1, a1.w, w3);
        fma4(acc2, a2.x, w0); fma4(acc2, a2.y, w1); fma4(acc2, a2.z, w2); fma4(acc2, a2.w, w3);
        fma4(acc3, a3.x, w0); fma4(acc3, a3.y, w1); fma4(acc3, a3.z, w2); fma4(acc3, a3.w, w3);
    }
    ushort4 o;
    o.x = f2bf(fmaxf(acc0.x, 0.f)); o.y = f2bf(fmaxf(acc0.y, 0.f));
    o.z = f2bf(fmaxf(acc0.z, 0.f)); o.w = f2bf(fmaxf(acc0.w, 0.f));
    *(ushort4*)&H[(size_t)(row0 + r0 + 0) * 128 + c0] = o;
    o.x = f2bf(fmaxf(acc1.x, 0.f)); o.y = f2bf(fmaxf(acc1.y, 0.f));
    o.z = f2bf(fmaxf(acc1.z, 0.f)); o.w = f2bf(fmaxf(acc1.w, 0.f));
    *(ushort4*)&H[(size_t)(row0 + r0 + 1) * 128 + c0] = o;
    o.x = f2bf(fmaxf(acc2.x, 0.f)); o.y = f2bf(fmaxf(acc2.y, 0.f));
    o.z = f2bf(fmaxf(acc2.z, 0.f)); o.w = f2bf(fmaxf(acc2.w, 0.f));
    *(ushort4*)&H[(size_t)(row0 + r0 + 2) * 128 + c0] = o;
    o.x = f2bf(fmaxf(acc3.x, 0.f)); o.y = f2bf(fmaxf(acc3.y, 0.f));
    o.z = f2bf(fmaxf(acc3.z, 0.f)); o.w = f2bf(fmaxf(acc3.w, 0.f));
    *(ushort4*)&H[(size_t)(row0 + r0 + 3) * 128 + c0] = o;
}

// GEMM2: zh(bf16) = H(bf16) * W2
__global__ __launch_bounds__(256, 3) void k_gemm2(const unsigned short* __restrict__ H,
                                                  unsigned short* __restrict__ zh,
                                                  const float* __restrict__ W2) {
    __shared__ float Ws[128 * 64];                 // 32 KB
    __shared__ unsigned short hsb[MROWS * HS2_S];  // 9.5 KB
    const int t = threadIdx.x;
    const int row0 = blockIdx.x * MROWS;

    {
        const float4* w4 = (const float4*)W2;
        float4* s4 = (float4*)Ws;
        for (int i = t; i < 2048; i += 256) s4[i] = w4[i];
    }
    // stage h rows: 32 rows x 128 bf16 = 512 uint4
#pragma unroll
    for (int c = 0; c < 2; ++c) {
        int lin = t + c * 256;
        int r = lin >> 4, k8 = lin & 15;
        uint4 v = *(const uint4*)(H + (size_t)(row0 + r) * 128 + k8 * 8);
        *(uint4*)&hsb[r * HS2_S + k8 * 8] = v;
    }
    __syncthreads();

    const int rg = t >> 4, cg = t & 15;
    const int r0 = rg * 2, c0 = cg * 4;
    float4 acc0 = make_float4(0.f, 0.f, 0.f, 0.f);
    float4 acc1 = make_float4(0.f, 0.f, 0.f, 0.f);
#pragma unroll 4
    for (int k4 = 0; k4 < 32; ++k4) {
        ushort4 u0 = *(const ushort4*)&hsb[(r0 + 0) * HS2_S + k4 * 4];
        ushort4 u1 = *(const ushort4*)&hsb[(r0 + 1) * HS2_S + k4 * 4];
        float4 w0 = *(const float4*)&Ws[(k4 * 4 + 0) * 64 + c0];
        float4 w1 = *(const float4*)&Ws[(k4 * 4 + 1) * 64 + c0];
        float4 w2 = *(const float4*)&Ws[(k4 * 4 + 2) * 64 + c0];
        float4 w3 = *(const float4*)&Ws[(k4 * 4 + 3) * 64 + c0];
        fma4(acc0, bf2f(u0.x), w0); fma4(acc0, bf2f(u0.y), w1);
        fma4(acc0, bf2f(u0.z), w2); fma4(acc0, bf2f(u0.w), w3);
        fma4(acc1, bf2f(u1.x), w0); fma4(acc1, bf2f(u1.y), w1);
        fma4(acc1, bf2f(u1.z), w2); fma4(acc1, bf2f(u1.w), w3);
    }
    ushort4 o0, o1;
    o0.x = f2bf(acc0.x); o0.y = f2bf(acc0.y); o0.z = f2bf(acc0.z); o0.w = f2bf(acc0.w);
    o1.x = f2bf(acc1.x); o1.y = f2bf(acc1.y); o1.z = f2bf(acc1.z); o1.w = f2bf(acc1.w);
    *(ushort4*)&zh[(size_t)(row0 + r0 + 0) * 64 + c0] = o0;
    *(ushort4*)&zh[(size_t)(row0 + r0 + 1) * 64 + c0] = o1;
}

// fp32 in-place MLP (tier-2/3 fallback)
__global__ __launch_bounds__(256, 2) void k_mlpF(float* __restrict__ A,
                                                 const float* __restrict__ W1,
                                                 const float* __restrict__ b1,
                                                 const float* __restrict__ W2) {
    __shared__ float Ws[64 * 128];
    __shared__ float xs[MROWS * XS_S];
    __shared__ float hs[MROWS * 132];
    __shared__ float b1s[128];
    const int t = threadIdx.x;
    const int row0 = blockIdx.x * MROWS;

    {
        const float4* w4 = (const float4*)W1;
        float4* s4 = (float4*)Ws;
        for (int i = t; i < 2048; i += 256) s4[i] = w4[i];
    }
    if (t < 128) b1s[t] = b1[t];
#pragma unroll
    for (int c = 0; c < 2; ++c) {
        int lin = t + c * 256;
        int r = lin >> 4, k4 = lin & 15;
        float4 v = *(const float4*)(A + (size_t)(row0 + r) * 64 + k4 * 4);
        *(float4*)&xs[r * XS_S + k4 * 4] = v;
    }
    __syncthreads();
    {
        const int rg = t >> 5, cg = t & 31;
        const int r0 = rg * 4, c0 = cg * 4;
        float4 bv = *(const float4*)&b1s[c0];
        float4 acc0 = bv, acc1 = bv, acc2 = bv, acc3 = bv;
#pragma unroll 4
        for (int k4 = 0; k4 < 16; ++k4) {
            float4 a0 = *(const float4*)&xs[(r0 + 0) * XS_S + k4 * 4];
            float4 a1 = *(const float4*)&xs[(r0 + 1) * XS_S + k4 * 4];
            float4 a2 = *(const float4*)&xs[(r0 + 2) * XS_S + k4 * 4];
            float4 a3 = *(const float4*)&xs[(r0 + 3) * XS_S + k4 * 4];
            float4 w0 = *(const float4*)&Ws[(k4 * 4 + 0) * 128 + c0];
            float4 w1 = *(const float4*)&Ws[(k4 * 4 + 1) * 128 + c0];
            float4 w2 = *(const float4*)&Ws[(k4 * 4 + 2) * 128 + c0];
            float4 w3 = *(const float4*)&Ws[(k4 * 4 + 3) * 128 + c0];
            fma4(acc0, a0.x, w0); fma4(acc0, a0.y, w1); fma4(acc0, a0.z, w2); fma4(acc0, a0.w, w3);
            fma4(acc1, a1.x, w0); fma4(acc1, a1.y, w1); fma4(acc1, a1.z, w2); fma4(acc1, a1.w, w3);
            fma4(acc2, a2.x, w0); fma4(acc2, a2.y, w1); fma4(acc2, a2.z, w2); fma4(acc2, a2.w, w3);
            fma4(acc3, a3.x, w0); fma4(acc3, a3.y, w1); fma4(acc3, a3.z, w2); fma4(acc3, a3.w, w3);
        }
        float4 h;
        h.x = fmaxf(acc0.x, 0.f); h.y = fmaxf(acc0.y, 0.f); h.z = fmaxf(acc0.z, 0.f); h.w = fmaxf(acc0.w, 0.f);
        *(float4*)&hs[(r0 + 0) * 132 + c0] = h;
        h.x = fmaxf(acc1.x, 0.f); h.y = fmaxf(acc1.y, 0.f); h.z = fmaxf(acc1.z, 0.f); h.w = fmaxf(acc1.w, 0.f);
        *(float4*)&hs[(r0 + 1) * 132 + c0] = h;
        h.x = fmaxf(acc2.x, 0.f); h.y = fmaxf(acc2.y, 0.f); h.z = fmaxf(acc2.z, 0.f); h.w = fmaxf(acc2.w, 0.f);
        *(float4*)&hs[(r0 + 2) * 132 + c0] = h;
        h.x = fmaxf(acc3.x, 0.f); h.y = fmaxf(acc3.y, 0.f); h.z = fmaxf(acc3.z, 0.f); h.w = fmaxf(acc3.w, 0.f);
        *(float4*)&hs[(r0 + 3) * 132 + c0] = h;
    }
    __syncthreads();
    {
        const float4* w4 = (const float4*)W2;
        float4* s4 = (float4*)Ws;
        for (int i = t; i < 2048; i += 256) s4[i] = w4[i];
    }
    __syncthreads();
    {
        const int rg = t >> 4, cg = t & 15;
        const int r0 = rg * 2, c0 = cg * 4;
        float4 acc0 = make_float4(0.f, 0.f, 0.f, 0.f);
        float4 acc1 = make_float4(0.f, 0.f, 0.f, 0.f);
#pragma unroll 4
        for (int k4 = 0; k4 < 32; ++k4) {
            float4 h0 = *(const float4*)&hs[(r0 + 0) * 132 + k4 * 4];
            float4 h1 = *(const float4*)&hs[(r0 + 1) * 132 + k4 * 4];
            float4 w0 = *(const float4*)&Ws[(k4 * 4 + 0) * 64 + c0];
            float4 w1 = *(const float4*)&Ws[(k4 * 4 + 1) * 64 + c0];
            float4 w2 = *(const float4*)&Ws[(k4 * 4 + 2) * 64 + c0];
            float4 w3 = *(const float4*)&Ws[(k4 * 4 + 3) * 64 + c0];
            fma4(acc0, h0.x, w0); fma4(acc0, h0.y, w1); fma4(acc0, h0.z, w2); fma4(acc0, h0.w, w3);
            fma4(acc1, h1.x, w0); fma4(acc1, h1.y, w1); fma4(acc1, h1.z, w2); fma4(acc1, h1.w, w3);
        }
        *(float4*)(A + (size_t)(row0 + r0 + 0) * 64 + c0) = acc0;
        *(float4*)(A + (size_t)(row0 + r0 + 1) * 64 + c0) = acc1;
    }
}

static inline size_t alignup(size_t v, size_t a) { return (v + a - 1) & ~(a - 1); }

extern "C" void kernel_launch(void* const* d_in, const int* in_sizes, int n_in,
                              void* d_out, int out_size, void* d_ws, size_t ws_size,
                              hipStream_t stream) {
    const float* x  = (const float*)d_in[0];
    const float* W1 = (const float*)d_in[1];
    const float* b1 = (const float*)d_in[2];
    const float* W2 = (const float*)d_in[3];
    const float* b2 = (const float*)d_in[4];
    const int* src  = (const int*)d_in[5];
    const int* dst  = (const int*)d_in[6];
    float* out = (float*)d_out;

    const int nfeat = N_NODES * 64;
    const int nfeat4 = nfeat / 4;

    // ---- tier-1 layout (64B-aligned fields) ----
    char* base = (char*)d_ws;
    size_t o = 0;
    size_t o_xh   = o;                  o = alignup(o + (size_t)nfeat * 2, 64);          // 12.8 MB
    size_t o_es   = o;                  o = alignup(o + (size_t)N_EDGES * 4, 64);        // 6.4 MB
    size_t o_off  = o;                  o = alignup(o + (size_t)(N_NODES + 1) * 4, 64);
    size_t o_bcnt = o;                  o = alignup(o + (size_t)NBK2 * PAD * 4, 64);
    size_t o_gcur = o;                  o = alignup(o + (size_t)NBK2 * PAD * 4, 64);
    size_t o_boff = o;                  o = alignup(o + (size_t)(NBK2 + 1) * 4, 64);
    size_t o_shrd = o;                  o = alignup(o + (size_t)nfeat * 4, 64);          // eb / A / H share
    size_t need1 = o;

    unsigned short* xh = (unsigned short*)(base + o_xh);
    int* es    = (int*)(base + o_es);
    int* off   = (int*)(base + o_off);
    int* bcnt  = (int*)(base + o_bcnt);
    int* gcur  = (int*)(base + o_gcur);
    int* boff  = (int*)(base + o_boff);
    int* eb    = (int*)(base + o_shrd);
    float* A   = (float*)(base + o_shrd);
    unsigned short* H = (unsigned short*)(base + o_shrd);   // bf16 h overlays A in place
    unsigned short* zh = xh;                                 // z overlays dead xh

    // ---- tier-2 layout: fp32 path ----
    size_t p = 0;
    size_t p_A    = p;   p = alignup(p + (size_t)nfeat * 4, 64);
    size_t p_eb   = p;   p = alignup(p + (size_t)N_EDGES * 4, 64);
    size_t p_es   = p;   p = alignup(p + (size_t)N_EDGES * 4, 64);
    size_t p_off  = p;   p = alignup(p + (size_t)(N_NODES + 1) * 4, 64);
    size_t p_bcnt = p;   p = alignup(p + (size_t)NBK2 * PAD * 4, 64);
    size_t p_gcur = p;   p = alignup(p + (size_t)NBK2 * PAD * 4, 64);
    size_t p_boff = p;   p = alignup(p + (size_t)(NBK2 + 1) * 4, 64);
    size_t need2 = p;

    if (ws_size >= need1) {
        // ---- x -> bf16 ----
        k_cvt<<<(nfeat / 8 + 255) / 256, 256, 0, stream>>>((const float4*)x, (uint4*)xh, nfeat / 8);
        // ---- CSR build ----
        k_zero_i<<<(NBK2 * PAD + 255) / 256, 256, 0, stream>>>(bcnt, NBK2 * PAD);
        k_bhist<<<512, 256, 0, stream>>>(dst, bcnt);
        k_bscan<<<1, 256, 0, stream>>>(bcnt, boff, gcur);
        k_part<<<NPBLK, 256, 0, stream>>>(src, dst, gcur, eb);
        k_fill3<<<NBK2, 512, 0, stream>>>(eb, boff, off, es);

        // ---- layer 1 aggregate: A = segsum(xh)  (A overlays dead eb) ----
        k_gather2<<<N_NODES / 8, 256, 0, stream>>>((const unsigned*)xh, es, off, nullptr, A);
        // ---- GEMM1: H = bf16(relu(A*W1+b1)), in place over A ----
        k_gemm1<<<N_NODES / MROWS, 256, 0, stream>>>(A, H, W1, b1);
        // ---- GEMM2: zh = bf16(H*W2) ----
        k_gemm2<<<N_NODES / MROWS, 256, 0, stream>>>(H, zh, W2);
        // ---- layer 2 aggregate + bias: out = b2 + segsum(zh) ----
        k_gather2<<<N_NODES / 8, 256, 0, stream>>>((const unsigned*)zh, es, off, b2, out);
    } else if (ws_size >= need2) {
        float* A2  = (float*)(base + p_A);
        int* eb2   = (int*)(base + p_eb);
        int* es2   = (int*)(base + p_es);
        int* off2  = (int*)(base + p_off);
        int* bcnt2 = (int*)(base + p_bcnt);
        int* gcur2 = (int*)(base + p_gcur);
        int* boff2 = (int*)(base + p_boff);

        k_zero_i<<<(NBK2 * PAD + 255) / 256, 256, 0, stream>>>(bcnt2, NBK2 * PAD);
        k_bhist<<<512, 256, 0, stream>>>(dst, bcnt2);
        k_bscan<<<1, 256, 0, stream>>>(bcnt2, boff2, gcur2);
        k_part<<<NPBLK, 256, 0, stream>>>(src, dst, gcur2, eb2);
        k_fill3<<<NBK2, 512, 0, stream>>>(eb2, boff2, off2, es2);

        k_gatherF<<<(N_NODES + 3) / 4, 256, 0, stream>>>(x, es2, off2, nullptr, A2);
        k_mlpF<<<N_NODES / MROWS, 256, 0, stream>>>(A2, W1, b1, W2);
        k_gatherF<<<(N_NODES + 3) / 4, 256, 0, stream>>>(A2, es2, off2, b2, out);
    } else {
        float* A3 = (float*)d_ws;
        k_zero_f4<<<(nfeat4 + 255) / 256, 256, 0, stream>>>((float4*)A3, nfeat4);
        int threads = N_EDGES * 16;
        k_scatter64<<<(threads + 255) / 256, 256, 0, stream>>>(x, src, dst, A3);
        k_mlpF<<<N_NODES / MROWS, 256, 0, stream>>>(A3, W1, b1, W2);
        k_init_bias<<<(nfeat + 255) / 256, 256, 0, stream>>>(out, b2, nfeat);
        k_scatter64<<<(threads + 255) / 256, 256, 0, stream>>>(A3, src, dst, out);
    }
}

// Round 14
// 184.607 us; speedup vs baseline: 8.4885x; 1.1047x over previous
//
#include <hip/hip_runtime.h>

#define N_NODES 100000
#define N_EDGES 1600000
#define IN_F 64
#define HID 128
#define N_CLS 64

#define NPB2 256                                 // nodes per bucket (d >> 8)
#define NBK2 ((N_NODES + NPB2 - 1) / NPB2)       // 391
#define NPBLK 512                                // scatter blocks
#define PCHUNK (N_EDGES / NPBLK)                 // 3125 edges per block (exact)

// ================= bf16 helpers =================
__device__ __forceinline__ unsigned short f2bf(float f) {
    unsigned int u = __float_as_uint(f);
    u = (u + 0x7FFFu + ((u >> 16) & 1u)) >> 16;   // RNE
    return (unsigned short)u;
}
__device__ __forceinline__ float bf2f(unsigned short h) {
    return __uint_as_float(((unsigned int)h) << 16);
}

// ================= generic helpers =================
__global__ void k_zero_f4(float4* __restrict__ p, int n4) {
    int i = blockIdx.x * blockDim.x + threadIdx.x;
    if (i < n4) p[i] = make_float4(0.f, 0.f, 0.f, 0.f);
}
__global__ void k_init_bias(float* __restrict__ out, const float* __restrict__ b2, int n) {
    int i = blockIdx.x * blockDim.x + threadIdx.x;
    if (i < n) out[i] = b2[i & 63];
}

// convert fp32 -> bf16, 8 elems/thread
__global__ void k_cvt(const float4* __restrict__ x4, uint4* __restrict__ xh, int n8) {
    int i = blockIdx.x * blockDim.x + threadIdx.x;
    if (i >= n8) return;
    float4 a = x4[2 * i], b = x4[2 * i + 1];
    uint4 o;
    o.x = (unsigned)f2bf(a.x) | ((unsigned)f2bf(a.y) << 16);
    o.y = (unsigned)f2bf(a.z) | ((unsigned)f2bf(a.w) << 16);
    o.z = (unsigned)f2bf(b.x) | ((unsigned)f2bf(b.y) << 16);
    o.w = (unsigned)f2bf(b.z) | ((unsigned)f2bf(b.w) << 16);
    xh[i] = o;
}

// ================= multi-split partition (atomic-free global) =================
// 1) per-(block,bucket) counts
__global__ __launch_bounds__(256) void k_count(const int* __restrict__ dst,
                                               int* __restrict__ C) {
    __shared__ int h[NBK2];
    const int t = threadIdx.x;
    for (int i = t; i < NBK2; i += 256) h[i] = 0;
    __syncthreads();
    const int e0 = blockIdx.x * PCHUNK;
    int e1 = e0 + PCHUNK; if (e1 > N_EDGES) e1 = N_EDGES;
    for (int e = e0 + t; e < e1; e += 256) atomicAdd(&h[dst[e] >> 8], 1);
    __syncthreads();
    for (int i = t; i < NBK2; i += 256) C[blockIdx.x * NBK2 + i] = h[i];
}

// 2) per-bucket column scan of C (in place -> exclusive offsets); emit totals
__global__ __launch_bounds__(NPBLK) void k_colscan(int* __restrict__ C,
                                                   int* __restrict__ btot) {
    __shared__ int sc[2][NPBLK];
    const int t = threadIdx.x;
    const int bucket = blockIdx.x;
    int v = C[t * NBK2 + bucket];
    sc[0][t] = v;
    __syncthreads();
    int cur = 0;
    for (int d = 1; d < NPBLK; d <<= 1) {
        int x = sc[cur][t];
        if (t >= d) x += sc[cur][t - d];
        sc[cur ^ 1][t] = x;
        __syncthreads();
        cur ^= 1;
    }
    C[t * NBK2 + bucket] = sc[cur][t] - v;            // exclusive within bucket
    if (t == NPBLK - 1) btot[bucket] = sc[cur][t];    // bucket total
}

// 3) scan bucket totals -> boff
__global__ __launch_bounds__(512) void k_btscan(const int* __restrict__ btot,
                                                int* __restrict__ boff) {
    __shared__ int sc[2][512];
    const int t = threadIdx.x;
    int v = (t < NBK2) ? btot[t] : 0;
    sc[0][t] = v;
    __syncthreads();
    int cur = 0;
    for (int d = 1; d < 512; d <<= 1) {
        int x = sc[cur][t];
        if (t >= d) x += sc[cur][t - d];
        sc[cur ^ 1][t] = x;
        __syncthreads();
        cur ^= 1;
    }
    if (t < NBK2) boff[t] = sc[cur][t] - v;
    if (t == 0) boff[NBK2] = N_EDGES;
}

// 4) scatter into exactly-reserved spans (no global atomics)
__global__ __launch_bounds__(256) void k_scat(const int* __restrict__ src,
                                              const int* __restrict__ dst,
                                              const int* __restrict__ C,
                                              const int* __restrict__ boff,
                                              int* __restrict__ eb) {
    __shared__ int gbase[NBK2];
    __shared__ int lcur[NBK2];
    const int t = threadIdx.x;
    for (int i = t; i < NBK2; i += 256) {
        gbase[i] = boff[i] + C[blockIdx.x * NBK2 + i];
        lcur[i] = 0;
    }
    __syncthreads();
    const int e0 = blockIdx.x * PCHUNK;
    int e1 = e0 + PCHUNK; if (e1 > N_EDGES) e1 = N_EDGES;
    for (int e = e0 + t; e < e1; e += 256) {
        int d = dst[e];
        int b = d >> 8;
        int r = atomicAdd(&lcur[b], 1);
        eb[gbase[b] + r] = ((d & 255) << 17) | src[e];   // dstLow(8b) | src(17b)
    }
}

// 5) per-bucket: node-degree hist + scan -> off; sort -> es
__global__ __launch_bounds__(256) void k_fill3(const int* __restrict__ eb,
                                               const int* __restrict__ boff,
                                               int* __restrict__ off,
                                               int* __restrict__ es) {
    __shared__ int ldeg[NPB2];
    __shared__ int sc[2][NPB2];
    const int t = threadIdx.x;
    const int b = blockIdx.x;
    const int bbase = boff[b], bend = boff[b + 1];

    ldeg[t] = 0;
    __syncthreads();
    for (int i = bbase + t; i < bend; i += 256) atomicAdd(&ldeg[eb[i] >> 17], 1);
    __syncthreads();

    int v = ldeg[t];
    sc[0][t] = v;
    __syncthreads();
    int cur = 0;
    for (int d = 1; d < NPB2; d <<= 1) {
        int x = sc[cur][t];
        if (t >= d) x += sc[cur][t - d];
        sc[cur ^ 1][t] = x;
        __syncthreads();
        cur ^= 1;
    }
    int ex = sc[cur][t] - v;

    const int n0 = b * NPB2;
    if (n0 + t < N_NODES) off[n0 + t] = bbase + ex;
    if (b == NBK2 - 1 && t == 0) off[N_NODES] = N_EDGES;

    ldeg[t] = ex;
    __syncthreads();

    for (int i = bbase + t; i < bend; i += 256) {
        int p = eb[i];
        int r = atomicAdd(&ldeg[p >> 17], 1);
        es[bbase + r] = p & 0x1FFFF;
    }
}

// ================= gather (bf16 feat, 2 nodes/wave) =================
__global__ __launch_bounds__(256) void k_gather2(const unsigned* __restrict__ feat,
                                                 const int* __restrict__ es,
                                                 const int* __restrict__ off,
                                                 const float* __restrict__ bias,
                                                 float* __restrict__ out) {
    const int wave = threadIdx.x >> 6;
    const int lane = threadIdx.x & 63;
    const int half = lane >> 5;
    const int l32 = lane & 31;
    const int n = blockIdx.x * 8 + wave * 2 + half;    // 12500*8 == N_NODES exactly
    const int beg = off[n], end = off[n + 1];
    const int hb = half << 5;
    float acc0 = 0.f, acc1 = 0.f;
    for (int base = beg; base < end; base += 32) {
        int m = end - base; if (m > 32) m = 32;
        int id = (l32 < m) ? es[base + l32] : 0;
        int k = 0;
        for (; k + 4 <= m; k += 4) {
            int s0 = __shfl(id, hb | (k + 0));
            int s1 = __shfl(id, hb | (k + 1));
            int s2 = __shfl(id, hb | (k + 2));
            int s3 = __shfl(id, hb | (k + 3));
            unsigned u0 = feat[(unsigned)s0 * 32u + l32];
            unsigned u1 = feat[(unsigned)s1 * 32u + l32];
            unsigned u2 = feat[(unsigned)s2 * 32u + l32];
            unsigned u3 = feat[(unsigned)s3 * 32u + l32];
            acc0 += (__uint_as_float(u0 << 16) + __uint_as_float(u1 << 16))
                  + (__uint_as_float(u2 << 16) + __uint_as_float(u3 << 16));
            acc1 += (__uint_as_float(u0 & 0xFFFF0000u) + __uint_as_float(u1 & 0xFFFF0000u))
                  + (__uint_as_float(u2 & 0xFFFF0000u) + __uint_as_float(u3 & 0xFFFF0000u));
        }
        for (; k < m; ++k) {
            int s = __shfl(id, hb | k);
            unsigned u = feat[(unsigned)s * 32u + l32];
            acc0 += __uint_as_float(u << 16);
            acc1 += __uint_as_float(u & 0xFFFF0000u);
        }
    }
    if (bias) { acc0 += bias[l32 * 2]; acc1 += bias[l32 * 2 + 1]; }
    float2 o; o.x = acc0; o.y = acc1;
    *(float2*)&out[(size_t)n * 64 + l32 * 2] = o;
}

// ================= fallback atomic scatter =================
__global__ void k_scatter64(const float* __restrict__ feat,
                            const int* __restrict__ src,
                            const int* __restrict__ dst,
                            float* __restrict__ out) {
    int i = blockIdx.x * blockDim.x + threadIdx.x;
    int e = i >> 4;
    if (e >= N_EDGES) return;
    int j = (i & 15) << 2;
    int s = src[e];
    int d = dst[e];
    float4 v = *reinterpret_cast<const float4*>(feat + (size_t)s * 64 + j);
    float* o = out + (size_t)d * 64 + j;
    atomicAdd(o + 0, v.x);
    atomicAdd(o + 1, v.y);
    atomicAdd(o + 2, v.z);
    atomicAdd(o + 3, v.w);
}

// ================= split GEMMs =================
#define MROWS 32
#define XS_S 68      // float stride for x rows
#define HS2_S 152    // ushort stride for h rows

__device__ __forceinline__ void fma4(float4& a, float s, const float4& wv) {
    a.x = fmaf(s, wv.x, a.x);
    a.y = fmaf(s, wv.y, a.y);
    a.z = fmaf(s, wv.z, a.z);
    a.w = fmaf(s, wv.w, a.w);
}

// GEMM1: H(bf16, stride 128, overlays A) = relu(A*W1 + b1)
__global__ __launch_bounds__(256, 3) void k_gemm1(const float* __restrict__ A,
                                                  unsigned short* __restrict__ H,
                                                  const float* __restrict__ W1,
                                                  const float* __restrict__ b1) {
    __shared__ float Ws[64 * 128];
    __shared__ float xs[MROWS * XS_S];
    __shared__ float b1s[128];
    const int t = threadIdx.x;
    const int row0 = blockIdx.x * MROWS;

    {
        const float4* w4 = (const float4*)W1;
        float4* s4 = (float4*)Ws;
        for (int i = t; i < 2048; i += 256) s4[i] = w4[i];
    }
    if (t < 128) b1s[t] = b1[t];
#pragma unroll
    for (int c = 0; c < 2; ++c) {
        int lin = t + c * 256;
        int r = lin >> 4, k4 = lin & 15;
        float4 v = *(const float4*)(A + (size_t)(row0 + r) * 64 + k4 * 4);
        *(float4*)&xs[r * XS_S + k4 * 4] = v;
    }
    __syncthreads();

    const int rg = t >> 5, cg = t & 31;
    const int r0 = rg * 4, c0 = cg * 4;
    float4 bv = *(const float4*)&b1s[c0];
    float4 acc0 = bv, acc1 = bv, acc2 = bv, acc3 = bv;
#pragma unroll 4
    for (int k4 = 0; k4 < 16; ++k4) {
        float4 a0 = *(const float4*)&xs[(r0 + 0) * XS_S + k4 * 4];
        float4 a1 = *(const float4*)&xs[(r0 + 1) * XS_S + k4 * 4];
        float4 a2 = *(const float4*)&xs[(r0 + 2) * XS_S + k4 * 4];
        float4 a3 = *(const float4*)&xs[(r0 + 3) * XS_S + k4 * 4];
        float4 w0 = *(const float4*)&Ws[(k4 * 4 + 0) * 128 + c0];
        float4 w1 = *(const float4*)&Ws[(k4 * 4 + 1) * 128 + c0];
        float4 w2 = *(const float4*)&Ws[(k4 * 4 + 2) * 128 + c0];
        float4 w3 = *(const float4*)&Ws[(k4 * 4 + 3) * 128 + c0];
        fma4(acc0, a0.x, w0); fma4(acc0, a0.y, w1); fma4(acc0, a0.z, w2); fma4(acc0, a0.w, w3);
        fma4(acc1, a1.x, w0); fma4(acc1, a1.y, w1); fma4(acc1, a1.z, w2); fma4(acc1, a1.w, w3);
        fma4(acc2, a2.x, w0); fma4(acc2, a2.y, w1); fma4(acc2, a2.z, w2); fma4(acc2, a2.w, w3);
        fma4(acc3, a3.x, w0); fma4(acc3, a3.y, w1); fma4(acc3, a3.z, w2); fma4(acc3, a3.w, w3);
    }
    ushort4 o;
    o.x = f2bf(fmaxf(acc0.x, 0.f)); o.y = f2bf(fmaxf(acc0.y, 0.f));
    o.z = f2bf(fmaxf(acc0.z, 0.f)); o.w = f2bf(fmaxf(acc0.w, 0.f));
    *(ushort4*)&H[(size_t)(row0 + r0 + 0) * 128 + c0] = o;
    o.x = f2bf(fmaxf(acc1.x, 0.f)); o.y = f2bf(fmaxf(acc1.y, 0.f));
    o.z = f2bf(fmaxf(acc1.z, 0.f)); o.w = f2bf(fmaxf(acc1.w, 0.f));
    *(ushort4*)&H[(size_t)(row0 + r0 + 1) * 128 + c0] = o;
    o.x = f2bf(fmaxf(acc2.x, 0.f)); o.y = f2bf(fmaxf(acc2.y, 0.f));
    o.z = f2bf(fmaxf(acc2.z, 0.f)); o.w = f2bf(fmaxf(acc2.w, 0.f));
    *(ushort4*)&H[(size_t)(row0 + r0 + 2) * 128 + c0] = o;
    o.x = f2bf(fmaxf(acc3.x, 0.f)); o.y = f2bf(fmaxf(acc3.y, 0.f));
    o.z = f2bf(fmaxf(acc3.z, 0.f)); o.w = f2bf(fmaxf(acc3.w, 0.f));
    *(ushort4*)&H[(size_t)(row0 + r0 + 3) * 128 + c0] = o;
}

// GEMM2: zh(bf16) = H(bf16) * W2
__global__ __launch_bounds__(256, 3) void k_gemm2(const unsigned short* __restrict__ H,
                                                  unsigned short* __restrict__ zh,
                                                  const float* __restrict__ W2) {
    __shared__ float Ws[128 * 64];
    __shared__ unsigned short hsb[MROWS * HS2_S];
    const int t = threadIdx.x;
    const int row0 = blockIdx.x * MROWS;

    {
        const float4* w4 = (const float4*)W2;
        float4* s4 = (float4*)Ws;
        for (int i = t; i < 2048; i += 256) s4[i] = w4[i];
    }
#pragma unroll
    for (int c = 0; c < 2; ++c) {
        int lin = t + c * 256;
        int r = lin >> 4, k8 = lin & 15;
        uint4 v = *(const uint4*)(H + (size_t)(row0 + r) * 128 + k8 * 8);
        *(uint4*)&hsb[r * HS2_S + k8 * 8] = v;
    }
    __syncthreads();

    const int rg = t >> 4, cg = t & 15;
    const int r0 = rg * 2, c0 = cg * 4;
    float4 acc0 = make_float4(0.f, 0.f, 0.f, 0.f);
    float4 acc1 = make_float4(0.f, 0.f, 0.f, 0.f);
#pragma unroll 4
    for (int k4 = 0; k4 < 32; ++k4) {
        ushort4 u0 = *(const ushort4*)&hsb[(r0 + 0) * HS2_S + k4 * 4];
        ushort4 u1 = *(const ushort4*)&hsb[(r0 + 1) * HS2_S + k4 * 4];
        float4 w0 = *(const float4*)&Ws[(k4 * 4 + 0) * 64 + c0];
        float4 w1 = *(const float4*)&Ws[(k4 * 4 + 1) * 64 + c0];
        float4 w2 = *(const float4*)&Ws[(k4 * 4 + 2) * 64 + c0];
        float4 w3 = *(const float4*)&Ws[(k4 * 4 + 3) * 64 + c0];
        fma4(acc0, bf2f(u0.x), w0); fma4(acc0, bf2f(u0.y), w1);
        fma4(acc0, bf2f(u0.z), w2); fma4(acc0, bf2f(u0.w), w3);
        fma4(acc1, bf2f(u1.x), w0); fma4(acc1, bf2f(u1.y), w1);
        fma4(acc1, bf2f(u1.z), w2); fma4(acc1, bf2f(u1.w), w3);
    }
    ushort4 o0, o1;
    o0.x = f2bf(acc0.x); o0.y = f2bf(acc0.y); o0.z = f2bf(acc0.z); o0.w = f2bf(acc0.w);
    o1.x = f2bf(acc1.x); o1.y = f2bf(acc1.y); o1.z = f2bf(acc1.z); o1.w = f2bf(acc1.w);
    *(ushort4*)&zh[(size_t)(row0 + r0 + 0) * 64 + c0] = o0;
    *(ushort4*)&zh[(size_t)(row0 + r0 + 1) * 64 + c0] = o1;
}

// fp32 in-place MLP (fallback)
__global__ __launch_bounds__(256, 2) void k_mlpF(float* __restrict__ A,
                                                 const float* __restrict__ W1,
                                                 const float* __restrict__ b1,
                                                 const float* __restrict__ W2) {
    __shared__ float Ws[64 * 128];
    __shared__ float xs[MROWS * XS_S];
    __shared__ float hs[MROWS * 132];
    __shared__ float b1s[128];
    const int t = threadIdx.x;
    const int row0 = blockIdx.x * MROWS;

    {
        const float4* w4 = (const float4*)W1;
        float4* s4 = (float4*)Ws;
        for (int i = t; i < 2048; i += 256) s4[i] = w4[i];
    }
    if (t < 128) b1s[t] = b1[t];
#pragma unroll
    for (int c = 0; c < 2; ++c) {
        int lin = t + c * 256;
        int r = lin >> 4, k4 = lin & 15;
        float4 v = *(const float4*)(A + (size_t)(row0 + r) * 64 + k4 * 4);
        *(float4*)&xs[r * XS_S + k4 * 4] = v;
    }
    __syncthreads();
    {
        const int rg = t >> 5, cg = t & 31;
        const int r0 = rg * 4, c0 = cg * 4;
        float4 bv = *(const float4*)&b1s[c0];
        float4 acc0 = bv, acc1 = bv, acc2 = bv, acc3 = bv;
#pragma unroll 4
        for (int k4 = 0; k4 < 16; ++k4) {
            float4 a0 = *(const float4*)&xs[(r0 + 0) * XS_S + k4 * 4];
            float4 a1 = *(const float4*)&xs[(r0 + 1) * XS_S + k4 * 4];
            float4 a2 = *(const float4*)&xs[(r0 + 2) * XS_S + k4 * 4];
            float4 a3 = *(const float4*)&xs[(r0 + 3) * XS_S + k4 * 4];
            float4 w0 = *(const float4*)&Ws[(k4 * 4 + 0) * 128 + c0];
            float4 w1 = *(const float4*)&Ws[(k4 * 4 + 1) * 128 + c0];
            float4 w2 = *(const float4*)&Ws[(k4 * 4 + 2) * 128 + c0];
            float4 w3 = *(const float4*)&Ws[(k4 * 4 + 3) * 128 + c0];
            fma4(acc0, a0.x, w0); fma4(acc0, a0.y, w1); fma4(acc0, a0.z, w2); fma4(acc0, a0.w, w3);
            fma4(acc1, a1.x, w0); fma4(acc1, a1.y, w1); fma4(acc1, a1.z, w2); fma4(acc1, a1.w, w3);
            fma4(acc2, a2.x, w0); fma4(acc2, a2.y, w1); fma4(acc2, a2.z, w2); fma4(acc2, a2.w, w3);
            fma4(acc3, a3.x, w0); fma4(acc3, a3.y, w1); fma4(acc3, a3.z, w2); fma4(acc3, a3.w, w3);
        }
        float4 h;
        h.x = fmaxf(acc0.x, 0.f); h.y = fmaxf(acc0.y, 0.f); h.z = fmaxf(acc0.z, 0.f); h.w = fmaxf(acc0.w, 0.f);
        *(float4*)&hs[(r0 + 0) * 132 + c0] = h;
        h.x = fmaxf(acc1.x, 0.f); h.y = fmaxf(acc1.y, 0.f); h.z = fmaxf(acc1.z, 0.f); h.w = fmaxf(acc1.w, 0.f);
        *(float4*)&hs[(r0 + 1) * 132 + c0] = h;
        h.x = fmaxf(acc2.x, 0.f); h.y = fmaxf(acc2.y, 0.f); h.z = fmaxf(acc2.z, 0.f); h.w = fmaxf(acc2.w, 0.f);
        *(float4*)&hs[(r0 + 2) * 132 + c0] = h;
        h.x = fmaxf(acc3.x, 0.f); h.y = fmaxf(acc3.y, 0.f); h.z = fmaxf(acc3.z, 0.f); h.w = fmaxf(acc3.w, 0.f);
        *(float4*)&hs[(r0 + 3) * 132 + c0] = h;
    }
    __syncthreads();
    {
        const float4* w4 = (const float4*)W2;
        float4* s4 = (float4*)Ws;
        for (int i = t; i < 2048; i += 256) s4[i] = w4[i];
    }
    __syncthreads();
    {
        const int rg = t >> 4, cg = t & 15;
        const int r0 = rg * 2, c0 = cg * 4;
        float4 acc0 = make_float4(0.f, 0.f, 0.f, 0.f);
        float4 acc1 = make_float4(0.f, 0.f, 0.f, 0.f);
#pragma unroll 4
        for (int k4 = 0; k4 < 32; ++k4) {
            float4 h0 = *(const float4*)&hs[(r0 + 0) * 132 + k4 * 4];
            float4 h1 = *(const float4*)&hs[(r0 + 1) * 132 + k4 * 4];
            float4 w0 = *(const float4*)&Ws[(k4 * 4 + 0) * 64 + c0];
            float4 w1 = *(const float4*)&Ws[(k4 * 4 + 1) * 64 + c0];
            float4 w2 = *(const float4*)&Ws[(k4 * 4 + 2) * 64 + c0];
            float4 w3 = *(const float4*)&Ws[(k4 * 4 + 3) * 64 + c0];
            fma4(acc0, h0.x, w0); fma4(acc0, h0.y, w1); fma4(acc0, h0.z, w2); fma4(acc0, h0.w, w3);
            fma4(acc1, h1.x, w0); fma4(acc1, h1.y, w1); fma4(acc1, h1.z, w2); fma4(acc1, h1.w, w3);
        }
        *(float4*)(A + (size_t)(row0 + r0 + 0) * 64 + c0) = acc0;
        *(float4*)(A + (size_t)(row0 + r0 + 1) * 64 + c0) = acc1;
    }
}

static inline size_t alignup(size_t v, size_t a) { return (v + a - 1) & ~(a - 1); }

extern "C" void kernel_launch(void* const* d_in, const int* in_sizes, int n_in,
                              void* d_out, int out_size, void* d_ws, size_t ws_size,
                              hipStream_t stream) {
    const float* x  = (const float*)d_in[0];
    const float* W1 = (const float*)d_in[1];
    const float* b1 = (const float*)d_in[2];
    const float* W2 = (const float*)d_in[3];
    const float* b2 = (const float*)d_in[4];
    const int* src  = (const int*)d_in[5];
    const int* dst  = (const int*)d_in[6];
    float* out = (float*)d_out;

    const int nfeat = N_NODES * 64;
    const int nfeat4 = nfeat / 4;

    // ---- tier-1 layout (64B-aligned fields) ----
    char* base = (char*)d_ws;
    size_t o = 0;
    size_t o_xh   = o;   o = alignup(o + (size_t)nfeat * 2, 64);            // 12.8 MB
    size_t o_es   = o;   o = alignup(o + (size_t)N_EDGES * 4, 64);          // 6.4 MB
    size_t o_off  = o;   o = alignup(o + (size_t)(N_NODES + 1) * 4, 64);
    size_t o_C    = o;   o = alignup(o + (size_t)NPBLK * NBK2 * 4, 64);     // 800 KB
    size_t o_btot = o;   o = alignup(o + (size_t)NBK2 * 4, 64);
    size_t o_boff = o;   o = alignup(o + (size_t)(NBK2 + 1) * 4, 64);
    size_t o_shrd = o;   o = alignup(o + (size_t)nfeat * 4, 64);            // eb / A / H share
    size_t need1 = o;

    unsigned short* xh = (unsigned short*)(base + o_xh);
    int* es    = (int*)(base + o_es);
    int* off   = (int*)(base + o_off);
    int* C     = (int*)(base + o_C);
    int* btot  = (int*)(base + o_btot);
    int* boff  = (int*)(base + o_boff);
    int* eb    = (int*)(base + o_shrd);
    float* A   = (float*)(base + o_shrd);
    unsigned short* H = (unsigned short*)(base + o_shrd);
    unsigned short* zh = xh;

    if (ws_size >= need1) {
        // ---- x -> bf16 ----
        k_cvt<<<(nfeat / 8 + 255) / 256, 256, 0, stream>>>((const float4*)x, (uint4*)xh, nfeat / 8);
        // ---- CSR build: multi-split, zero global atomics ----
        k_count<<<NPBLK, 256, 0, stream>>>(dst, C);
        k_colscan<<<NBK2, NPBLK, 0, stream>>>(C, btot);
        k_btscan<<<1, 512, 0, stream>>>(btot, boff);
        k_scat<<<NPBLK, 256, 0, stream>>>(src, dst, C, boff, eb);
        k_fill3<<<NBK2, 256, 0, stream>>>(eb, boff, off, es);

        // ---- layer 1 aggregate: A = segsum(xh)  (A overlays dead eb) ----
        k_gather2<<<N_NODES / 8, 256, 0, stream>>>((const unsigned*)xh, es, off, nullptr, A);
        // ---- GEMM1: H = bf16(relu(A*W1+b1)), in place over A ----
        k_gemm1<<<N_NODES / MROWS, 256, 0, stream>>>(A, H, W1, b1);
        // ---- GEMM2: zh = bf16(H*W2) ----
        k_gemm2<<<N_NODES / MROWS, 256, 0, stream>>>(H, zh, W2);
        // ---- layer 2 aggregate + bias: out = b2 + segsum(zh) ----
        k_gather2<<<N_NODES / 8, 256, 0, stream>>>((const unsigned*)zh, es, off, b2, out);
    } else {
        // ---- fallback: atomic scatter (fp32, minimal workspace) ----
        float* A3 = (float*)d_ws;
        k_zero_f4<<<(nfeat4 + 255) / 256, 256, 0, stream>>>((float4*)A3, nfeat4);
        int threads = N_EDGES * 16;
        k_scatter64<<<(threads + 255) / 256, 256, 0, stream>>>(x, src, dst, A3);
        k_mlpF<<<N_NODES / MROWS, 256, 0, stream>>>(A3, W1, b1, W2);
        k_init_bias<<<(nfeat + 255) / 256, 256, 0, stream>>>(out, b2, nfeat);
        k_scatter64<<<(threads + 255) / 256, 256, 0, stream>>>(A3, src, dst, out);
    }
}

// Round 15
// 178.577 us; speedup vs baseline: 8.7752x; 1.0338x over previous
//
#include <hip/hip_runtime.h>

#define N_NODES 100000
#define N_EDGES 1600000
#define IN_F 64
#define HID 128
#define N_CLS 64

#define NPB2 256                                 // nodes per bucket (d >> 8)
#define NBK2 ((N_NODES + NPB2 - 1) / NPB2)       // 391
#define NPBLK 512                                // scatter blocks
#define PCHUNK (N_EDGES / NPBLK)                 // 3125 edges per block (exact)
#define CVTBLK ((N_NODES * 64 / 8 + 255) / 256)  // 3125 cvt blocks

// ================= bf16 helpers =================
__device__ __forceinline__ unsigned short f2bf(float f) {
    unsigned int u = __float_as_uint(f);
    u = (u + 0x7FFFu + ((u >> 16) & 1u)) >> 16;   // RNE
    return (unsigned short)u;
}
__device__ __forceinline__ float bf2f(unsigned short h) {
    return __uint_as_float(((unsigned int)h) << 16);
}

// ================= generic helpers =================
__global__ void k_zero_f4(float4* __restrict__ p, int n4) {
    int i = blockIdx.x * blockDim.x + threadIdx.x;
    if (i < n4) p[i] = make_float4(0.f, 0.f, 0.f, 0.f);
}
__global__ void k_init_bias(float* __restrict__ out, const float* __restrict__ b2, int n) {
    int i = blockIdx.x * blockDim.x + threadIdx.x;
    if (i < n) out[i] = b2[i & 63];
}

// ================= fused: fp32->bf16 convert + per-(block,bucket) counts =================
// blocks [0, NPBLK): histogram chunk of dst into C row.
// blocks [NPBLK, NPBLK+CVTBLK): convert 8 floats/thread to bf16.
__global__ __launch_bounds__(256) void k_cvt_count(const float4* __restrict__ x4,
                                                   uint4* __restrict__ xh,
                                                   const int* __restrict__ dst,
                                                   int* __restrict__ C) {
    __shared__ int h[NBK2];
    const int t = threadIdx.x;
    if (blockIdx.x < NPBLK) {
        for (int i = t; i < NBK2; i += 256) h[i] = 0;
        __syncthreads();
        const int e0 = blockIdx.x * PCHUNK;
        int e1 = e0 + PCHUNK; if (e1 > N_EDGES) e1 = N_EDGES;
        for (int e = e0 + t; e < e1; e += 256) atomicAdd(&h[dst[e] >> 8], 1);
        __syncthreads();
        for (int i = t; i < NBK2; i += 256) C[blockIdx.x * NBK2 + i] = h[i];
    } else {
        int i = (blockIdx.x - NPBLK) * 256 + t;
        const int n8 = N_NODES * 64 / 8;
        if (i < n8) {
            float4 a = x4[2 * i], b = x4[2 * i + 1];
            uint4 o;
            o.x = (unsigned)f2bf(a.x) | ((unsigned)f2bf(a.y) << 16);
            o.y = (unsigned)f2bf(a.z) | ((unsigned)f2bf(a.w) << 16);
            o.z = (unsigned)f2bf(b.x) | ((unsigned)f2bf(b.y) << 16);
            o.w = (unsigned)f2bf(b.z) | ((unsigned)f2bf(b.w) << 16);
            xh[i] = o;
        }
    }
}

// 2) per-bucket column scan of C (in place -> exclusive offsets); emit totals
__global__ __launch_bounds__(NPBLK) void k_colscan(int* __restrict__ C,
                                                   int* __restrict__ btot) {
    __shared__ int sc[2][NPBLK];
    const int t = threadIdx.x;
    const int bucket = blockIdx.x;
    int v = C[t * NBK2 + bucket];
    sc[0][t] = v;
    __syncthreads();
    int cur = 0;
    for (int d = 1; d < NPBLK; d <<= 1) {
        int x = sc[cur][t];
        if (t >= d) x += sc[cur][t - d];
        sc[cur ^ 1][t] = x;
        __syncthreads();
        cur ^= 1;
    }
    C[t * NBK2 + bucket] = sc[cur][t] - v;            // exclusive within bucket
    if (t == NPBLK - 1) btot[bucket] = sc[cur][t];    // bucket total
}

// 3) scan bucket totals -> boff
__global__ __launch_bounds__(512) void k_btscan(const int* __restrict__ btot,
                                                int* __restrict__ boff) {
    __shared__ int sc[2][512];
    const int t = threadIdx.x;
    int v = (t < NBK2) ? btot[t] : 0;
    sc[0][t] = v;
    __syncthreads();
    int cur = 0;
    for (int d = 1; d < 512; d <<= 1) {
        int x = sc[cur][t];
        if (t >= d) x += sc[cur][t - d];
        sc[cur ^ 1][t] = x;
        __syncthreads();
        cur ^= 1;
    }
    if (t < NBK2) boff[t] = sc[cur][t] - v;
    if (t == 0) boff[NBK2] = N_EDGES;
}

// 4) scatter into exactly-reserved spans (no global atomics)
__global__ __launch_bounds__(256) void k_scat(const int* __restrict__ src,
                                              const int* __restrict__ dst,
                                              const int* __restrict__ C,
                                              const int* __restrict__ boff,
                                              int* __restrict__ eb) {
    __shared__ int gbase[NBK2];
    __shared__ int lcur[NBK2];
    const int t = threadIdx.x;
    for (int i = t; i < NBK2; i += 256) {
        gbase[i] = boff[i] + C[blockIdx.x * NBK2 + i];
        lcur[i] = 0;
    }
    __syncthreads();
    const int e0 = blockIdx.x * PCHUNK;
    int e1 = e0 + PCHUNK; if (e1 > N_EDGES) e1 = N_EDGES;
    for (int e = e0 + t; e < e1; e += 256) {
        int d = dst[e];
        int b = d >> 8;
        int r = atomicAdd(&lcur[b], 1);
        eb[gbase[b] + r] = ((d & 255) << 17) | src[e];   // dstLow(8b) | src(17b)
    }
}

// 5) per-bucket: node-degree hist + scan -> off; sort -> es
__global__ __launch_bounds__(256) void k_fill3(const int* __restrict__ eb,
                                               const int* __restrict__ boff,
                                               int* __restrict__ off,
                                               int* __restrict__ es) {
    __shared__ int ldeg[NPB2];
    __shared__ int sc[2][NPB2];
    const int t = threadIdx.x;
    const int b = blockIdx.x;
    const int bbase = boff[b], bend = boff[b + 1];

    ldeg[t] = 0;
    __syncthreads();
    for (int i = bbase + t; i < bend; i += 256) atomicAdd(&ldeg[eb[i] >> 17], 1);
    __syncthreads();

    int v = ldeg[t];
    sc[0][t] = v;
    __syncthreads();
    int cur = 0;
    for (int d = 1; d < NPB2; d <<= 1) {
        int x = sc[cur][t];
        if (t >= d) x += sc[cur][t - d];
        sc[cur ^ 1][t] = x;
        __syncthreads();
        cur ^= 1;
    }
    int ex = sc[cur][t] - v;

    const int n0 = b * NPB2;
    if (n0 + t < N_NODES) off[n0 + t] = bbase + ex;
    if (b == NBK2 - 1 && t == 0) off[N_NODES] = N_EDGES;

    ldeg[t] = ex;
    __syncthreads();

    for (int i = bbase + t; i < bend; i += 256) {
        int p = eb[i];
        int r = atomicAdd(&ldeg[p >> 17], 1);
        es[bbase + r] = p & 0x1FFFF;
    }
}

// ================= gather (bf16 feat, 4 nodes/wave, 16 lanes/node) =================
// feat viewed as uint2 rows of 16 (4 bf16 per uint2). Per edge: 1 shfl + 1 qword load per 16 lanes.
__global__ __launch_bounds__(256) void k_gather4(const uint2* __restrict__ feat,
                                                 const int* __restrict__ es,
                                                 const int* __restrict__ off,
                                                 const float* __restrict__ bias,
                                                 float* __restrict__ out) {
    const int wave = threadIdx.x >> 6;
    const int lane = threadIdx.x & 63;
    const int grp = lane >> 4;                 // 0..3
    const int l16 = lane & 15;
    const int n = blockIdx.x * 16 + wave * 4 + grp;   // 6250*16 == N_NODES exactly
    const int beg = off[n], end = off[n + 1];
    const int gb = grp << 4;
    float a0 = 0.f, a1 = 0.f, a2 = 0.f, a3 = 0.f;
    for (int base = beg; base < end; base += 16) {
        int m = end - base; if (m > 16) m = 16;
        int id = (l16 < m) ? es[base + l16] : 0;
        int k = 0;
        for (; k + 4 <= m; k += 4) {
            int s0 = __shfl(id, gb | (k + 0));
            int s1 = __shfl(id, gb | (k + 1));
            int s2 = __shfl(id, gb | (k + 2));
            int s3 = __shfl(id, gb | (k + 3));
            uint2 u0 = feat[(unsigned)s0 * 16u + l16];
            uint2 u1 = feat[(unsigned)s1 * 16u + l16];
            uint2 u2 = feat[(unsigned)s2 * 16u + l16];
            uint2 u3 = feat[(unsigned)s3 * 16u + l16];
            a0 += (__uint_as_float(u0.x << 16) + __uint_as_float(u1.x << 16))
                + (__uint_as_float(u2.x << 16) + __uint_as_float(u3.x << 16));
            a1 += (__uint_as_float(u0.x & 0xFFFF0000u) + __uint_as_float(u1.x & 0xFFFF0000u))
                + (__uint_as_float(u2.x & 0xFFFF0000u) + __uint_as_float(u3.x & 0xFFFF0000u));
            a2 += (__uint_as_float(u0.y << 16) + __uint_as_float(u1.y << 16))
                + (__uint_as_float(u2.y << 16) + __uint_as_float(u3.y << 16));
            a3 += (__uint_as_float(u0.y & 0xFFFF0000u) + __uint_as_float(u1.y & 0xFFFF0000u))
                + (__uint_as_float(u2.y & 0xFFFF0000u) + __uint_as_float(u3.y & 0xFFFF0000u));
        }
        for (; k < m; ++k) {
            int s = __shfl(id, gb | k);
            uint2 u = feat[(unsigned)s * 16u + l16];
            a0 += __uint_as_float(u.x << 16);
            a1 += __uint_as_float(u.x & 0xFFFF0000u);
            a2 += __uint_as_float(u.y << 16);
            a3 += __uint_as_float(u.y & 0xFFFF0000u);
        }
    }
    if (bias) {
        float4 bv = *(const float4*)&bias[l16 * 4];
        a0 += bv.x; a1 += bv.y; a2 += bv.z; a3 += bv.w;
    }
    float4 o; o.x = a0; o.y = a1; o.z = a2; o.w = a3;
    *(float4*)&out[(size_t)n * 64 + l16 * 4] = o;
}

// ================= fallback atomic scatter =================
__global__ void k_scatter64(const float* __restrict__ feat,
                            const int* __restrict__ src,
                            const int* __restrict__ dst,
                            float* __restrict__ out) {
    int i = blockIdx.x * blockDim.x + threadIdx.x;
    int e = i >> 4;
    if (e >= N_EDGES) return;
    int j = (i & 15) << 2;
    int s = src[e];
    int d = dst[e];
    float4 v = *reinterpret_cast<const float4*>(feat + (size_t)s * 64 + j);
    float* o = out + (size_t)d * 64 + j;
    atomicAdd(o + 0, v.x);
    atomicAdd(o + 1, v.y);
    atomicAdd(o + 2, v.z);
    atomicAdd(o + 3, v.w);
}

// ================= split GEMMs =================
#define MROWS 32
#define XS_S 68      // float stride for x rows
#define HS2_S 152    // ushort stride for h rows

__device__ __forceinline__ void fma4(float4& a, float s, const float4& wv) {
    a.x = fmaf(s, wv.x, a.x);
    a.y = fmaf(s, wv.y, a.y);
    a.z = fmaf(s, wv.z, a.z);
    a.w = fmaf(s, wv.w, a.w);
}

// GEMM1: H(bf16, stride 128, overlays A) = relu(A*W1 + b1)
__global__ __launch_bounds__(256, 3) void k_gemm1(const float* __restrict__ A,
                                                  unsigned short* __restrict__ H,
                                                  const float* __restrict__ W1,
                                                  const float* __restrict__ b1) {
    __shared__ float Ws[64 * 128];
    __shared__ float xs[MROWS * XS_S];
    __shared__ float b1s[128];
    const int t = threadIdx.x;
    const int row0 = blockIdx.x * MROWS;

    {
        const float4* w4 = (const float4*)W1;
        float4* s4 = (float4*)Ws;
        for (int i = t; i < 2048; i += 256) s4[i] = w4[i];
    }
    if (t < 128) b1s[t] = b1[t];
#pragma unroll
    for (int c = 0; c < 2; ++c) {
        int lin = t + c * 256;
        int r = lin >> 4, k4 = lin & 15;
        float4 v = *(const float4*)(A + (size_t)(row0 + r) * 64 + k4 * 4);
        *(float4*)&xs[r * XS_S + k4 * 4] = v;
    }
    __syncthreads();

    const int rg = t >> 5, cg = t & 31;
    const int r0 = rg * 4, c0 = cg * 4;
    float4 bv = *(const float4*)&b1s[c0];
    float4 acc0 = bv, acc1 = bv, acc2 = bv, acc3 = bv;
#pragma unroll 4
    for (int k4 = 0; k4 < 16; ++k4) {
        float4 a0 = *(const float4*)&xs[(r0 + 0) * XS_S + k4 * 4];
        float4 a1 = *(const float4*)&xs[(r0 + 1) * XS_S + k4 * 4];
        float4 a2 = *(const float4*)&xs[(r0 + 2) * XS_S + k4 * 4];
        float4 a3 = *(const float4*)&xs[(r0 + 3) * XS_S + k4 * 4];
        float4 w0 = *(const float4*)&Ws[(k4 * 4 + 0) * 128 + c0];
        float4 w1 = *(const float4*)&Ws[(k4 * 4 + 1) * 128 + c0];
        float4 w2 = *(const float4*)&Ws[(k4 * 4 + 2) * 128 + c0];
        float4 w3 = *(const float4*)&Ws[(k4 * 4 + 3) * 128 + c0];
        fma4(acc0, a0.x, w0); fma4(acc0, a0.y, w1); fma4(acc0, a0.z, w2); fma4(acc0, a0.w, w3);
        fma4(acc1, a1.x, w0); fma4(acc1, a1.y, w1); fma4(acc1, a1.z, w2); fma4(acc1, a1.w, w3);
        fma4(acc2, a2.x, w0); fma4(acc2, a2.y, w1); fma4(acc2, a2.z, w2); fma4(acc2, a2.w, w3);
        fma4(acc3, a3.x, w0); fma4(acc3, a3.y, w1); fma4(acc3, a3.z, w2); fma4(acc3, a3.w, w3);
    }
    ushort4 o;
    o.x = f2bf(fmaxf(acc0.x, 0.f)); o.y = f2bf(fmaxf(acc0.y, 0.f));
    o.z = f2bf(fmaxf(acc0.z, 0.f)); o.w = f2bf(fmaxf(acc0.w, 0.f));
    *(ushort4*)&H[(size_t)(row0 + r0 + 0) * 128 + c0] = o;
    o.x = f2bf(fmaxf(acc1.x, 0.f)); o.y = f2bf(fmaxf(acc1.y, 0.f));
    o.z = f2bf(fmaxf(acc1.z, 0.f)); o.w = f2bf(fmaxf(acc1.w, 0.f));
    *(ushort4*)&H[(size_t)(row0 + r0 + 1) * 128 + c0] = o;
    o.x = f2bf(fmaxf(acc2.x, 0.f)); o.y = f2bf(fmaxf(acc2.y, 0.f));
    o.z = f2bf(fmaxf(acc2.z, 0.f)); o.w = f2bf(fmaxf(acc2.w, 0.f));
    *(ushort4*)&H[(size_t)(row0 + r0 + 2) * 128 + c0] = o;
    o.x = f2bf(fmaxf(acc3.x, 0.f)); o.y = f2bf(fmaxf(acc3.y, 0.f));
    o.z = f2bf(fmaxf(acc3.z, 0.f)); o.w = f2bf(fmaxf(acc3.w, 0.f));
    *(ushort4*)&H[(size_t)(row0 + r0 + 3) * 128 + c0] = o;
}

// GEMM2: zh(bf16) = H(bf16) * W2
__global__ __launch_bounds__(256, 3) void k_gemm2(const unsigned short* __restrict__ H,
                                                  unsigned short* __restrict__ zh,
                                                  const float* __restrict__ W2) {
    __shared__ float Ws[128 * 64];
    __shared__ unsigned short hsb[MROWS * HS2_S];
    const int t = threadIdx.x;
    const int row0 = blockIdx.x * MROWS;

    {
        const float4* w4 = (const float4*)W2;
        float4* s4 = (float4*)Ws;
        for (int i = t; i < 2048; i += 256) s4[i] = w4[i];
    }
#pragma unroll
    for (int c = 0; c < 2; ++c) {
        int lin = t + c * 256;
        int r = lin >> 4, k8 = lin & 15;
        uint4 v = *(const uint4*)(H + (size_t)(row0 + r) * 128 + k8 * 8);
        *(uint4*)&hsb[r * HS2_S + k8 * 8] = v;
    }
    __syncthreads();

    const int rg = t >> 4, cg = t & 15;
    const int r0 = rg * 2, c0 = cg * 4;
    float4 acc0 = make_float4(0.f, 0.f, 0.f, 0.f);
    float4 acc1 = make_float4(0.f, 0.f, 0.f, 0.f);
#pragma unroll 4
    for (int k4 = 0; k4 < 32; ++k4) {
        ushort4 u0 = *(const ushort4*)&hsb[(r0 + 0) * HS2_S + k4 * 4];
        ushort4 u1 = *(const ushort4*)&hsb[(r0 + 1) * HS2_S + k4 * 4];
        float4 w0 = *(const float4*)&Ws[(k4 * 4 + 0) * 64 + c0];
        float4 w1 = *(const float4*)&Ws[(k4 * 4 + 1) * 64 + c0];
        float4 w2 = *(const float4*)&Ws[(k4 * 4 + 2) * 64 + c0];
        float4 w3 = *(const float4*)&Ws[(k4 * 4 + 3) * 64 + c0];
        fma4(acc0, bf2f(u0.x), w0); fma4(acc0, bf2f(u0.y), w1);
        fma4(acc0, bf2f(u0.z), w2); fma4(acc0, bf2f(u0.w), w3);
        fma4(acc1, bf2f(u1.x), w0); fma4(acc1, bf2f(u1.y), w1);
        fma4(acc1, bf2f(u1.z), w2); fma4(acc1, bf2f(u1.w), w3);
    }
    ushort4 o0, o1;
    o0.x = f2bf(acc0.x); o0.y = f2bf(acc0.y); o0.z = f2bf(acc0.z); o0.w = f2bf(acc0.w);
    o1.x = f2bf(acc1.x); o1.y = f2bf(acc1.y); o1.z = f2bf(acc1.z); o1.w = f2bf(acc1.w);
    *(ushort4*)&zh[(size_t)(row0 + r0 + 0) * 64 + c0] = o0;
    *(ushort4*)&zh[(size_t)(row0 + r0 + 1) * 64 + c0] = o1;
}

// fp32 in-place MLP (fallback)
__global__ __launch_bounds__(256, 2) void k_mlpF(float* __restrict__ A,
                                                 const float* __restrict__ W1,
                                                 const float* __restrict__ b1,
                                                 const float* __restrict__ W2) {
    __shared__ float Ws[64 * 128];
    __shared__ float xs[MROWS * XS_S];
    __shared__ float hs[MROWS * 132];
    __shared__ float b1s[128];
    const int t = threadIdx.x;
    const int row0 = blockIdx.x * MROWS;

    {
        const float4* w4 = (const float4*)W1;
        float4* s4 = (float4*)Ws;
        for (int i = t; i < 2048; i += 256) s4[i] = w4[i];
    }
    if (t < 128) b1s[t] = b1[t];
#pragma unroll
    for (int c = 0; c < 2; ++c) {
        int lin = t + c * 256;
        int r = lin >> 4, k4 = lin & 15;
        float4 v = *(const float4*)(A + (size_t)(row0 + r) * 64 + k4 * 4);
        *(float4*)&xs[r * XS_S + k4 * 4] = v;
    }
    __syncthreads();
    {
        const int rg = t >> 5, cg = t & 31;
        const int r0 = rg * 4, c0 = cg * 4;
        float4 bv = *(const float4*)&b1s[c0];
        float4 acc0 = bv, acc1 = bv, acc2 = bv, acc3 = bv;
#pragma unroll 4
        for (int k4 = 0; k4 < 16; ++k4) {
            float4 a0 = *(const float4*)&xs[(r0 + 0) * XS_S + k4 * 4];
            float4 a1 = *(const float4*)&xs[(r0 + 1) * XS_S + k4 * 4];
            float4 a2 = *(const float4*)&xs[(r0 + 2) * XS_S + k4 * 4];
            float4 a3 = *(const float4*)&xs[(r0 + 3) * XS_S + k4 * 4];
            float4 w0 = *(const float4*)&Ws[(k4 * 4 + 0) * 128 + c0];
            float4 w1 = *(const float4*)&Ws[(k4 * 4 + 1) * 128 + c0];
            float4 w2 = *(const float4*)&Ws[(k4 * 4 + 2) * 128 + c0];
            float4 w3 = *(const float4*)&Ws[(k4 * 4 + 3) * 128 + c0];
            fma4(acc0, a0.x, w0); fma4(acc0, a0.y, w1); fma4(acc0, a0.z, w2); fma4(acc0, a0.w, w3);
            fma4(acc1, a1.x, w0); fma4(acc1, a1.y, w1); fma4(acc1, a1.z, w2); fma4(acc1, a1.w, w3);
            fma4(acc2, a2.x, w0); fma4(acc2, a2.y, w1); fma4(acc2, a2.z, w2); fma4(acc2, a2.w, w3);
            fma4(acc3, a3.x, w0); fma4(acc3, a3.y, w1); fma4(acc3, a3.z, w2); fma4(acc3, a3.w, w3);
        }
        float4 h;
        h.x = fmaxf(acc0.x, 0.f); h.y = fmaxf(acc0.y, 0.f); h.z = fmaxf(acc0.z, 0.f); h.w = fmaxf(acc0.w, 0.f);
        *(float4*)&hs[(r0 + 0) * 132 + c0] = h;
        h.x = fmaxf(acc1.x, 0.f); h.y = fmaxf(acc1.y, 0.f); h.z = fmaxf(acc1.z, 0.f); h.w = fmaxf(acc1.w, 0.f);
        *(float4*)&hs[(r0 + 1) * 132 + c0] = h;
        h.x = fmaxf(acc2.x, 0.f); h.y = fmaxf(acc2.y, 0.f); h.z = fmaxf(acc2.z, 0.f); h.w = fmaxf(acc2.w, 0.f);
        *(float4*)&hs[(r0 + 2) * 132 + c0] = h;
        h.x = fmaxf(acc3.x, 0.f); h.y = fmaxf(acc3.y, 0.f); h.z = fmaxf(acc3.z, 0.f); h.w = fmaxf(acc3.w, 0.f);
        *(float4*)&hs[(r0 + 3) * 132 + c0] = h;
    }
    __syncthreads();
    {
        const float4* w4 = (const float4*)W2;
        float4* s4 = (float4*)Ws;
        for (int i = t; i < 2048; i += 256) s4[i] = w4[i];
    }
    __syncthreads();
    {
        const int rg = t >> 4, cg = t & 15;
        const int r0 = rg * 2, c0 = cg * 4;
        float4 acc0 = make_float4(0.f, 0.f, 0.f, 0.f);
        float4 acc1 = make_float4(0.f, 0.f, 0.f, 0.f);
#pragma unroll 4
        for (int k4 = 0; k4 < 32; ++k4) {
            float4 h0 = *(const float4*)&hs[(r0 + 0) * 132 + k4 * 4];
            float4 h1 = *(const float4*)&hs[(r0 + 1) * 132 + k4 * 4];
            float4 w0 = *(const float4*)&Ws[(k4 * 4 + 0) * 64 + c0];
            float4 w1 = *(const float4*)&Ws[(k4 * 4 + 1) * 64 + c0];
            float4 w2 = *(const float4*)&Ws[(k4 * 4 + 2) * 64 + c0];
            float4 w3 = *(const float4*)&Ws[(k4 * 4 + 3) * 64 + c0];
            fma4(acc0, h0.x, w0); fma4(acc0, h0.y, w1); fma4(acc0, h0.z, w2); fma4(acc0, h0.w, w3);
            fma4(acc1, h1.x, w0); fma4(acc1, h1.y, w1); fma4(acc1, h1.z, w2); fma4(acc1, h1.w, w3);
        }
        *(float4*)(A + (size_t)(row0 + r0 + 0) * 64 + c0) = acc0;
        *(float4*)(A + (size_t)(row0 + r0 + 1) * 64 + c0) = acc1;
    }
}

static inline size_t alignup(size_t v, size_t a) { return (v + a - 1) & ~(a - 1); }

extern "C" void kernel_launch(void* const* d_in, const int* in_sizes, int n_in,
                              void* d_out, int out_size, void* d_ws, size_t ws_size,
                              hipStream_t stream) {
    const float* x  = (const float*)d_in[0];
    const float* W1 = (const float*)d_in[1];
    const float* b1 = (const float*)d_in[2];
    const float* W2 = (const float*)d_in[3];
    const float* b2 = (const float*)d_in[4];
    const int* src  = (const int*)d_in[5];
    const int* dst  = (const int*)d_in[6];
    float* out = (float*)d_out;

    const int nfeat = N_NODES * 64;
    const int nfeat4 = nfeat / 4;

    // ---- tier-1 layout (64B-aligned fields) ----
    char* base = (char*)d_ws;
    size_t o = 0;
    size_t o_xh   = o;   o = alignup(o + (size_t)nfeat * 2, 64);            // 12.8 MB
    size_t o_es   = o;   o = alignup(o + (size_t)N_EDGES * 4, 64);          // 6.4 MB
    size_t o_off  = o;   o = alignup(o + (size_t)(N_NODES + 1) * 4, 64);
    size_t o_C    = o;   o = alignup(o + (size_t)NPBLK * NBK2 * 4, 64);     // 800 KB
    size_t o_btot = o;   o = alignup(o + (size_t)NBK2 * 4, 64);
    size_t o_boff = o;   o = alignup(o + (size_t)(NBK2 + 1) * 4, 64);
    size_t o_shrd = o;   o = alignup(o + (size_t)nfeat * 4, 64);            // eb / A / H share
    size_t need1 = o;

    unsigned short* xh = (unsigned short*)(base + o_xh);
    int* es    = (int*)(base + o_es);
    int* off   = (int*)(base + o_off);
    int* C     = (int*)(base + o_C);
    int* btot  = (int*)(base + o_btot);
    int* boff  = (int*)(base + o_boff);
    int* eb    = (int*)(base + o_shrd);
    float* A   = (float*)(base + o_shrd);
    unsigned short* H = (unsigned short*)(base + o_shrd);
    unsigned short* zh = xh;

    if (ws_size >= need1) {
        // ---- fused cvt + count ----
        k_cvt_count<<<NPBLK + CVTBLK, 256, 0, stream>>>((const float4*)x, (uint4*)xh, dst, C);
        // ---- CSR build: multi-split, zero global atomics ----
        k_colscan<<<NBK2, NPBLK, 0, stream>>>(C, btot);
        k_btscan<<<1, 512, 0, stream>>>(btot, boff);
        k_scat<<<NPBLK, 256, 0, stream>>>(src, dst, C, boff, eb);
        k_fill3<<<NBK2, 256, 0, stream>>>(eb, boff, off, es);

        // ---- layer 1 aggregate: A = segsum(xh)  (A overlays dead eb) ----
        k_gather4<<<N_NODES / 16, 256, 0, stream>>>((const uint2*)xh, es, off, nullptr, A);
        // ---- GEMM1: H = bf16(relu(A*W1+b1)), in place over A ----
        k_gemm1<<<N_NODES / MROWS, 256, 0, stream>>>(A, H, W1, b1);
        // ---- GEMM2: zh = bf16(H*W2) ----
        k_gemm2<<<N_NODES / MROWS, 256, 0, stream>>>(H, zh, W2);
        // ---- layer 2 aggregate + bias: out = b2 + segsum(zh) ----
        k_gather4<<<N_NODES / 16, 256, 0, stream>>>((const uint2*)zh, es, off, b2, out);
    } else {
        // ---- fallback: atomic scatter (fp32, minimal workspace) ----
        float* A3 = (float*)d_ws;
        k_zero_f4<<<(nfeat4 + 255) / 256, 256, 0, stream>>>((float4*)A3, nfeat4);
        int threads = N_EDGES * 16;
        k_scatter64<<<(threads + 255) / 256, 256, 0, stream>>>(x, src, dst, A3);
        k_mlpF<<<N_NODES / MROWS, 256, 0, stream>>>(A3, W1, b1, W2);
        k_init_bias<<<(nfeat + 255) / 256, 256, 0, stream>>>(out, b2, nfeat);
        k_scatter64<<<(threads + 255) / 256, 256, 0, stream>>>(A3, src, dst, out);
    }
}

// Round 16
// 177.526 us; speedup vs baseline: 8.8271x; 1.0059x over previous
//
#include <hip/hip_runtime.h>

#define N_NODES 100000
#define N_EDGES 1600000
#define IN_F 64
#define HID 128
#define N_CLS 64

#define NPB2 256                                 // nodes per bucket (d >> 8)
#define NBK2 ((N_NODES + NPB2 - 1) / NPB2)       // 391
#define NPBLK 512                                // scatter blocks
#define PCHUNK (N_EDGES / NPBLK)                 // 3125 edges per block (exact)
#define CVTBLK ((N_NODES * 64 / 8 + 255) / 256)  // 3125 cvt blocks

// ================= bf16 helpers =================
__device__ __forceinline__ unsigned short f2bf(float f) {
    unsigned int u = __float_as_uint(f);
    u = (u + 0x7FFFu + ((u >> 16) & 1u)) >> 16;   // RNE
    return (unsigned short)u;
}
__device__ __forceinline__ float bf2f(unsigned short h) {
    return __uint_as_float(((unsigned int)h) << 16);
}

// ================= generic helpers =================
__global__ void k_zero_f4(float4* __restrict__ p, int n4) {
    int i = blockIdx.x * blockDim.x + threadIdx.x;
    if (i < n4) p[i] = make_float4(0.f, 0.f, 0.f, 0.f);
}
__global__ void k_init_bias(float* __restrict__ out, const float* __restrict__ b2, int n) {
    int i = blockIdx.x * blockDim.x + threadIdx.x;
    if (i < n) out[i] = b2[i & 63];
}

// ================= fused: fp32->bf16 convert + per-(block,bucket) counts =================
__global__ __launch_bounds__(256) void k_cvt_count(const float4* __restrict__ x4,
                                                   uint4* __restrict__ xh,
                                                   const int* __restrict__ dst,
                                                   int* __restrict__ C) {
    __shared__ int h[NBK2];
    const int t = threadIdx.x;
    if (blockIdx.x < NPBLK) {
        for (int i = t; i < NBK2; i += 256) h[i] = 0;
        __syncthreads();
        const int e0 = blockIdx.x * PCHUNK;
        int e1 = e0 + PCHUNK; if (e1 > N_EDGES) e1 = N_EDGES;
        for (int e = e0 + t; e < e1; e += 256) atomicAdd(&h[dst[e] >> 8], 1);
        __syncthreads();
        for (int i = t; i < NBK2; i += 256) C[blockIdx.x * NBK2 + i] = h[i];
    } else {
        int i = (blockIdx.x - NPBLK) * 256 + t;
        const int n8 = N_NODES * 64 / 8;
        if (i < n8) {
            float4 a = x4[2 * i], b = x4[2 * i + 1];
            uint4 o;
            o.x = (unsigned)f2bf(a.x) | ((unsigned)f2bf(a.y) << 16);
            o.y = (unsigned)f2bf(a.z) | ((unsigned)f2bf(a.w) << 16);
            o.z = (unsigned)f2bf(b.x) | ((unsigned)f2bf(b.y) << 16);
            o.w = (unsigned)f2bf(b.z) | ((unsigned)f2bf(b.w) << 16);
            xh[i] = o;
        }
    }
}

// 2) per-bucket column scan of C (in place -> exclusive offsets); emit totals
__global__ __launch_bounds__(NPBLK) void k_colscan(int* __restrict__ C,
                                                   int* __restrict__ btot) {
    __shared__ int sc[2][NPBLK];
    const int t = threadIdx.x;
    const int bucket = blockIdx.x;
    int v = C[t * NBK2 + bucket];
    sc[0][t] = v;
    __syncthreads();
    int cur = 0;
    for (int d = 1; d < NPBLK; d <<= 1) {
        int x = sc[cur][t];
        if (t >= d) x += sc[cur][t - d];
        sc[cur ^ 1][t] = x;
        __syncthreads();
        cur ^= 1;
    }
    C[t * NBK2 + bucket] = sc[cur][t] - v;            // exclusive within bucket
    if (t == NPBLK - 1) btot[bucket] = sc[cur][t];    // bucket total
}

// 3) scatter into exactly-reserved spans; boff recomputed in-block from btot
__global__ __launch_bounds__(256) void k_scat(const int* __restrict__ src,
                                              const int* __restrict__ dst,
                                              const int* __restrict__ C,
                                              const int* __restrict__ btot,
                                              int* __restrict__ eb) {
    __shared__ int gbase[NBK2];
    __shared__ int lcur[NBK2];
    __shared__ int sc[2][256];
    const int t = threadIdx.x;
    // pair-scan btot (391 entries, 2 per thread)
    int v0 = (2 * t < NBK2) ? btot[2 * t] : 0;
    int v1 = (2 * t + 1 < NBK2) ? btot[2 * t + 1] : 0;
    int s = v0 + v1;
    sc[0][t] = s;
    __syncthreads();
    int cur = 0;
    for (int d = 1; d < 256; d <<= 1) {
        int x = sc[cur][t];
        if (t >= d) x += sc[cur][t - d];
        sc[cur ^ 1][t] = x;
        __syncthreads();
        cur ^= 1;
    }
    int exp = sc[cur][t] - s;       // exclusive prefix of pair
    if (2 * t < NBK2) {
        gbase[2 * t] = exp + C[blockIdx.x * NBK2 + 2 * t];
        lcur[2 * t] = 0;
    }
    if (2 * t + 1 < NBK2) {
        gbase[2 * t + 1] = exp + v0 + C[blockIdx.x * NBK2 + 2 * t + 1];
        lcur[2 * t + 1] = 0;
    }
    __syncthreads();
    const int e0 = blockIdx.x * PCHUNK;
    int e1 = e0 + PCHUNK; if (e1 > N_EDGES) e1 = N_EDGES;
    for (int e = e0 + t; e < e1; e += 256) {
        int d = dst[e];
        int b = d >> 8;
        int r = atomicAdd(&lcur[b], 1);
        eb[gbase[b] + r] = ((d & 255) << 17) | src[e];   // dstLow(8b) | src(17b)
    }
}

// 4) per-bucket: node hist + scan -> off; sort -> es; boff recomputed from btot
__global__ __launch_bounds__(256) void k_fill3(const int* __restrict__ eb,
                                               const int* __restrict__ btot,
                                               int* __restrict__ off,
                                               int* __restrict__ es) {
    __shared__ int ldeg[NPB2];
    __shared__ int sc[2][NPB2];
    __shared__ int sh_base, sh_end;
    const int t = threadIdx.x;
    const int b = blockIdx.x;

    // pair-scan btot to find this bucket's span
    int v0 = (2 * t < NBK2) ? btot[2 * t] : 0;
    int v1 = (2 * t + 1 < NBK2) ? btot[2 * t + 1] : 0;
    int s = v0 + v1;
    sc[0][t] = s;
    __syncthreads();
    int cur = 0;
    for (int d = 1; d < 256; d <<= 1) {
        int x = sc[cur][t];
        if (t >= d) x += sc[cur][t - d];
        sc[cur ^ 1][t] = x;
        __syncthreads();
        cur ^= 1;
    }
    int exp = sc[cur][t] - s;
    if (2 * t == b)     { sh_base = exp;          sh_end = exp + v0; }
    if (2 * t + 1 == b) { sh_base = exp + v0;     sh_end = exp + v0 + v1; }
    __syncthreads();
    const int bbase = sh_base, bend = sh_end;

    ldeg[t] = 0;
    __syncthreads();
    for (int i = bbase + t; i < bend; i += 256) atomicAdd(&ldeg[eb[i] >> 17], 1);
    __syncthreads();

    int v = ldeg[t];
    sc[0][t] = v;
    __syncthreads();
    cur = 0;
    for (int d = 1; d < NPB2; d <<= 1) {
        int x = sc[cur][t];
        if (t >= d) x += sc[cur][t - d];
        sc[cur ^ 1][t] = x;
        __syncthreads();
        cur ^= 1;
    }
    int ex = sc[cur][t] - v;

    const int n0 = b * NPB2;
    if (n0 + t < N_NODES) off[n0 + t] = bbase + ex;
    if (b == NBK2 - 1 && t == 0) off[N_NODES] = N_EDGES;

    ldeg[t] = ex;
    __syncthreads();

    for (int i = bbase + t; i < bend; i += 256) {
        int p = eb[i];
        int r = atomicAdd(&ldeg[p >> 17], 1);
        es[bbase + r] = p & 0x1FFFF;
    }
}

// ================= gather (bf16 feat, 8 nodes/wave, 8 lanes/node) =================
// feat viewed as uint4 rows of 8 (8 bf16 per uint4). One load instr serves 8 edges.
__global__ __launch_bounds__(256) void k_gather8(const uint4* __restrict__ feat,
                                                 const int* __restrict__ es,
                                                 const int* __restrict__ off,
                                                 const float* __restrict__ bias,
                                                 float* __restrict__ out) {
    const int wave = threadIdx.x >> 6;
    const int lane = threadIdx.x & 63;
    const int grp = lane >> 3;                 // 0..7
    const int l8 = lane & 7;
    const int n = blockIdx.x * 32 + wave * 8 + grp;   // 3125*32 == N_NODES exactly
    const int beg = off[n], end = off[n + 1];
    const int gb = grp << 3;
    float a0 = 0.f, a1 = 0.f, a2 = 0.f, a3 = 0.f;
    float a4 = 0.f, a5 = 0.f, a6 = 0.f, a7 = 0.f;
    for (int base = beg; base < end; base += 8) {
        int m = end - base; if (m > 8) m = 8;
        int id = (l8 < m) ? es[base + l8] : 0;
        int k = 0;
        for (; k + 4 <= m; k += 4) {
            int s0 = __shfl(id, gb | (k + 0));
            int s1 = __shfl(id, gb | (k + 1));
            int s2 = __shfl(id, gb | (k + 2));
            int s3 = __shfl(id, gb | (k + 3));
            uint4 u0 = feat[(unsigned)s0 * 8u + l8];
            uint4 u1 = feat[(unsigned)s1 * 8u + l8];
            uint4 u2 = feat[(unsigned)s2 * 8u + l8];
            uint4 u3 = feat[(unsigned)s3 * 8u + l8];
            a0 += (__uint_as_float(u0.x << 16) + __uint_as_float(u1.x << 16))
                + (__uint_as_float(u2.x << 16) + __uint_as_float(u3.x << 16));
            a1 += (__uint_as_float(u0.x & 0xFFFF0000u) + __uint_as_float(u1.x & 0xFFFF0000u))
                + (__uint_as_float(u2.x & 0xFFFF0000u) + __uint_as_float(u3.x & 0xFFFF0000u));
            a2 += (__uint_as_float(u0.y << 16) + __uint_as_float(u1.y << 16))
                + (__uint_as_float(u2.y << 16) + __uint_as_float(u3.y << 16));
            a3 += (__uint_as_float(u0.y & 0xFFFF0000u) + __uint_as_float(u1.y & 0xFFFF0000u))
                + (__uint_as_float(u2.y & 0xFFFF0000u) + __uint_as_float(u3.y & 0xFFFF0000u));
            a4 += (__uint_as_float(u0.z << 16) + __uint_as_float(u1.z << 16))
                + (__uint_as_float(u2.z << 16) + __uint_as_float(u3.z << 16));
            a5 += (__uint_as_float(u0.z & 0xFFFF0000u) + __uint_as_float(u1.z & 0xFFFF0000u))
                + (__uint_as_float(u2.z & 0xFFFF0000u) + __uint_as_float(u3.z & 0xFFFF0000u));
            a6 += (__uint_as_float(u0.w << 16) + __uint_as_float(u1.w << 16))
                + (__uint_as_float(u2.w << 16) + __uint_as_float(u3.w << 16));
            a7 += (__uint_as_float(u0.w & 0xFFFF0000u) + __uint_as_float(u1.w & 0xFFFF0000u))
                + (__uint_as_float(u2.w & 0xFFFF0000u) + __uint_as_float(u3.w & 0xFFFF0000u));
        }
        for (; k < m; ++k) {
            int s = __shfl(id, gb | k);
            uint4 u = feat[(unsigned)s * 8u + l8];
            a0 += __uint_as_float(u.x << 16);
            a1 += __uint_as_float(u.x & 0xFFFF0000u);
            a2 += __uint_as_float(u.y << 16);
            a3 += __uint_as_float(u.y & 0xFFFF0000u);
            a4 += __uint_as_float(u.z << 16);
            a5 += __uint_as_float(u.z & 0xFFFF0000u);
            a6 += __uint_as_float(u.w << 16);
            a7 += __uint_as_float(u.w & 0xFFFF0000u);
        }
    }
    if (bias) {
        float4 b0 = *(const float4*)&bias[l8 * 8];
        float4 b1 = *(const float4*)&bias[l8 * 8 + 4];
        a0 += b0.x; a1 += b0.y; a2 += b0.z; a3 += b0.w;
        a4 += b1.x; a5 += b1.y; a6 += b1.z; a7 += b1.w;
    }
    float4 o0, o1;
    o0.x = a0; o0.y = a1; o0.z = a2; o0.w = a3;
    o1.x = a4; o1.y = a5; o1.z = a6; o1.w = a7;
    *(float4*)&out[(size_t)n * 64 + l8 * 8] = o0;
    *(float4*)&out[(size_t)n * 64 + l8 * 8 + 4] = o1;
}

// ================= fallback atomic scatter =================
__global__ void k_scatter64(const float* __restrict__ feat,
                            const int* __restrict__ src,
                            const int* __restrict__ dst,
                            float* __restrict__ out) {
    int i = blockIdx.x * blockDim.x + threadIdx.x;
    int e = i >> 4;
    if (e >= N_EDGES) return;
    int j = (i & 15) << 2;
    int s = src[e];
    int d = dst[e];
    float4 v = *reinterpret_cast<const float4*>(feat + (size_t)s * 64 + j);
    float* o = out + (size_t)d * 64 + j;
    atomicAdd(o + 0, v.x);
    atomicAdd(o + 1, v.y);
    atomicAdd(o + 2, v.z);
    atomicAdd(o + 3, v.w);
}

// ================= split GEMMs =================
#define MROWS 32
#define XS_S 68      // float stride for x rows
#define HS2_S 152    // ushort stride for h rows

__device__ __forceinline__ void fma4(float4& a, float s, const float4& wv) {
    a.x = fmaf(s, wv.x, a.x);
    a.y = fmaf(s, wv.y, a.y);
    a.z = fmaf(s, wv.z, a.z);
    a.w = fmaf(s, wv.w, a.w);
}

// GEMM1: H(bf16, stride 128, overlays A) = relu(A*W1 + b1)
__global__ __launch_bounds__(256, 3) void k_gemm1(const float* __restrict__ A,
                                                  unsigned short* __restrict__ H,
                                                  const float* __restrict__ W1,
                                                  const float* __restrict__ b1) {
    __shared__ float Ws[64 * 128];
    __shared__ float xs[MROWS * XS_S];
    __shared__ float b1s[128];
    const int t = threadIdx.x;
    const int row0 = blockIdx.x * MROWS;

    {
        const float4* w4 = (const float4*)W1;
        float4* s4 = (float4*)Ws;
        for (int i = t; i < 2048; i += 256) s4[i] = w4[i];
    }
    if (t < 128) b1s[t] = b1[t];
#pragma unroll
    for (int c = 0; c < 2; ++c) {
        int lin = t + c * 256;
        int r = lin >> 4, k4 = lin & 15;
        float4 v = *(const float4*)(A + (size_t)(row0 + r) * 64 + k4 * 4);
        *(float4*)&xs[r * XS_S + k4 * 4] = v;
    }
    __syncthreads();

    const int rg = t >> 5, cg = t & 31;
    const int r0 = rg * 4, c0 = cg * 4;
    float4 bv = *(const float4*)&b1s[c0];
    float4 acc0 = bv, acc1 = bv, acc2 = bv, acc3 = bv;
#pragma unroll 4
    for (int k4 = 0; k4 < 16; ++k4) {
        float4 a0 = *(const float4*)&xs[(r0 + 0) * XS_S + k4 * 4];
        float4 a1 = *(const float4*)&xs[(r0 + 1) * XS_S + k4 * 4];
        float4 a2 = *(const float4*)&xs[(r0 + 2) * XS_S + k4 * 4];
        float4 a3 = *(const float4*)&xs[(r0 + 3) * XS_S + k4 * 4];
        float4 w0 = *(const float4*)&Ws[(k4 * 4 + 0) * 128 + c0];
        float4 w1 = *(const float4*)&Ws[(k4 * 4 + 1) * 128 + c0];
        float4 w2 = *(const float4*)&Ws[(k4 * 4 + 2) * 128 + c0];
        float4 w3 = *(const float4*)&Ws[(k4 * 4 + 3) * 128 + c0];
        fma4(acc0, a0.x, w0); fma4(acc0, a0.y, w1); fma4(acc0, a0.z, w2); fma4(acc0, a0.w, w3);
        fma4(acc1, a1.x, w0); fma4(acc1, a1.y, w1); fma4(acc1, a1.z, w2); fma4(acc1, a1.w, w3);
        fma4(acc2, a2.x, w0); fma4(acc2, a2.y, w1); fma4(acc2, a2.z, w2); fma4(acc2, a2.w, w3);
        fma4(acc3, a3.x, w0); fma4(acc3, a3.y, w1); fma4(acc3, a3.z, w2); fma4(acc3, a3.w, w3);
    }
    ushort4 o;
    o.x = f2bf(fmaxf(acc0.x, 0.f)); o.y = f2bf(fmaxf(acc0.y, 0.f));
    o.z = f2bf(fmaxf(acc0.z, 0.f)); o.w = f2bf(fmaxf(acc0.w, 0.f));
    *(ushort4*)&H[(size_t)(row0 + r0 + 0) * 128 + c0] = o;
    o.x = f2bf(fmaxf(acc1.x, 0.f)); o.y = f2bf(fmaxf(acc1.y, 0.f));
    o.z = f2bf(fmaxf(acc1.z, 0.f)); o.w = f2bf(fmaxf(acc1.w, 0.f));
    *(ushort4*)&H[(size_t)(row0 + r0 + 1) * 128 + c0] = o;
    o.x = f2bf(fmaxf(acc2.x, 0.f)); o.y = f2bf(fmaxf(acc2.y, 0.f));
    o.z = f2bf(fmaxf(acc2.z, 0.f)); o.w = f2bf(fmaxf(acc2.w, 0.f));
    *(ushort4*)&H[(size_t)(row0 + r0 + 2) * 128 + c0] = o;
    o.x = f2bf(fmaxf(acc3.x, 0.f)); o.y = f2bf(fmaxf(acc3.y, 0.f));
    o.z = f2bf(fmaxf(acc3.z, 0.f)); o.w = f2bf(fmaxf(acc3.w, 0.f));
    *(ushort4*)&H[(size_t)(row0 + r0 + 3) * 128 + c0] = o;
}

// GEMM2: zh(bf16) = H(bf16) * W2
__global__ __launch_bounds__(256, 3) void k_gemm2(const unsigned short* __restrict__ H,
                                                  unsigned short* __restrict__ zh,
                                                  const float* __restrict__ W2) {
    __shared__ float Ws[128 * 64];
    __shared__ unsigned short hsb[MROWS * HS2_S];
    const int t = threadIdx.x;
    const int row0 = blockIdx.x * MROWS;

    {
        const float4* w4 = (const float4*)W2;
        float4* s4 = (float4*)Ws;
        for (int i = t; i < 2048; i += 256) s4[i] = w4[i];
    }
#pragma unroll
    for (int c = 0; c < 2; ++c) {
        int lin = t + c * 256;
        int r = lin >> 4, k8 = lin & 15;
        uint4 v = *(const uint4*)(H + (size_t)(row0 + r) * 128 + k8 * 8);
        *(uint4*)&hsb[r * HS2_S + k8 * 8] = v;
    }
    __syncthreads();

    const int rg = t >> 4, cg = t & 15;
    const int r0 = rg * 2, c0 = cg * 4;
    float4 acc0 = make_float4(0.f, 0.f, 0.f, 0.f);
    float4 acc1 = make_float4(0.f, 0.f, 0.f, 0.f);
#pragma unroll 4
    for (int k4 = 0; k4 < 32; ++k4) {
        ushort4 u0 = *(const ushort4*)&hsb[(r0 + 0) * HS2_S + k4 * 4];
        ushort4 u1 = *(const ushort4*)&hsb[(r0 + 1) * HS2_S + k4 * 4];
        float4 w0 = *(const float4*)&Ws[(k4 * 4 + 0) * 64 + c0];
        float4 w1 = *(const float4*)&Ws[(k4 * 4 + 1) * 64 + c0];
        float4 w2 = *(const float4*)&Ws[(k4 * 4 + 2) * 64 + c0];
        float4 w3 = *(const float4*)&Ws[(k4 * 4 + 3) * 64 + c0];
        fma4(acc0, bf2f(u0.x), w0); fma4(acc0, bf2f(u0.y), w1);
        fma4(acc0, bf2f(u0.z), w2); fma4(acc0, bf2f(u0.w), w3);
        fma4(acc1, bf2f(u1.x), w0); fma4(acc1, bf2f(u1.y), w1);
        fma4(acc1, bf2f(u1.z), w2); fma4(acc1, bf2f(u1.w), w3);
    }
    ushort4 o0, o1;
    o0.x = f2bf(acc0.x); o0.y = f2bf(acc0.y); o0.z = f2bf(acc0.z); o0.w = f2bf(acc0.w);
    o1.x = f2bf(acc1.x); o1.y = f2bf(acc1.y); o1.z = f2bf(acc1.z); o1.w = f2bf(acc1.w);
    *(ushort4*)&zh[(size_t)(row0 + r0 + 0) * 64 + c0] = o0;
    *(ushort4*)&zh[(size_t)(row0 + r0 + 1) * 64 + c0] = o1;
}

// fp32 in-place MLP (fallback)
__global__ __launch_bounds__(256, 2) void k_mlpF(float* __restrict__ A,
                                                 const float* __restrict__ W1,
                                                 const float* __restrict__ b1,
                                                 const float* __restrict__ W2) {
    __shared__ float Ws[64 * 128];
    __shared__ float xs[MROWS * XS_S];
    __shared__ float hs[MROWS * 132];
    __shared__ float b1s[128];
    const int t = threadIdx.x;
    const int row0 = blockIdx.x * MROWS;

    {
        const float4* w4 = (const float4*)W1;
        float4* s4 = (float4*)Ws;
        for (int i = t; i < 2048; i += 256) s4[i] = w4[i];
    }
    if (t < 128) b1s[t] = b1[t];
#pragma unroll
    for (int c = 0; c < 2; ++c) {
        int lin = t + c * 256;
        int r = lin >> 4, k4 = lin & 15;
        float4 v = *(const float4*)(A + (size_t)(row0 + r) * 64 + k4 * 4);
        *(float4*)&xs[r * XS_S + k4 * 4] = v;
    }
    __syncthreads();
    {
        const int rg = t >> 5, cg = t & 31;
        const int r0 = rg * 4, c0 = cg * 4;
        float4 bv = *(const float4*)&b1s[c0];
        float4 acc0 = bv, acc1 = bv, acc2 = bv, acc3 = bv;
#pragma unroll 4
        for (int k4 = 0; k4 < 16; ++k4) {
            float4 a0 = *(const float4*)&xs[(r0 + 0) * XS_S + k4 * 4];
            float4 a1 = *(const float4*)&xs[(r0 + 1) * XS_S + k4 * 4];
            float4 a2 = *(const float4*)&xs[(r0 + 2) * XS_S + k4 * 4];
            float4 a3 = *(const float4*)&xs[(r0 + 3) * XS_S + k4 * 4];
            float4 w0 = *(const float4*)&Ws[(k4 * 4 + 0) * 128 + c0];
            float4 w1 = *(const float4*)&Ws[(k4 * 4 + 1) * 128 + c0];
            float4 w2 = *(const float4*)&Ws[(k4 * 4 + 2) * 128 + c0];
            float4 w3 = *(const float4*)&Ws[(k4 * 4 + 3) * 128 + c0];
            fma4(acc0, a0.x, w0); fma4(acc0, a0.y, w1); fma4(acc0, a0.z, w2); fma4(acc0, a0.w, w3);
            fma4(acc1, a1.x, w0); fma4(acc1, a1.y, w1); fma4(acc1, a1.z, w2); fma4(acc1, a1.w, w3);
            fma4(acc2, a2.x, w0); fma4(acc2, a2.y, w1); fma4(acc2, a2.z, w2); fma4(acc2, a2.w, w3);
            fma4(acc3, a3.x, w0); fma4(acc3, a3.y, w1); fma4(acc3, a3.z, w2); fma4(acc3, a3.w, w3);
        }
        float4 h;
        h.x = fmaxf(acc0.x, 0.f); h.y = fmaxf(acc0.y, 0.f); h.z = fmaxf(acc0.z, 0.f); h.w = fmaxf(acc0.w, 0.f);
        *(float4*)&hs[(r0 + 0) * 132 + c0] = h;
        h.x = fmaxf(acc1.x, 0.f); h.y = fmaxf(acc1.y, 0.f); h.z = fmaxf(acc1.z, 0.f); h.w = fmaxf(acc1.w, 0.f);
        *(float4*)&hs[(r0 + 1) * 132 + c0] = h;
        h.x = fmaxf(acc2.x, 0.f); h.y = fmaxf(acc2.y, 0.f); h.z = fmaxf(acc2.z, 0.f); h.w = fmaxf(acc2.w, 0.f);
        *(float4*)&hs[(r0 + 2) * 132 + c0] = h;
        h.x = fmaxf(acc3.x, 0.f); h.y = fmaxf(acc3.y, 0.f); h.z = fmaxf(acc3.z, 0.f); h.w = fmaxf(acc3.w, 0.f);
        *(float4*)&hs[(r0 + 3) * 132 + c0] = h;
    }
    __syncthreads();
    {
        const float4* w4 = (const float4*)W2;
        float4* s4 = (float4*)Ws;
        for (int i = t; i < 2048; i += 256) s4[i] = w4[i];
    }
    __syncthreads();
    {
        const int rg = t >> 4, cg = t & 15;
        const int r0 = rg * 2, c0 = cg * 4;
        float4 acc0 = make_float4(0.f, 0.f, 0.f, 0.f);
        float4 acc1 = make_float4(0.f, 0.f, 0.f, 0.f);
#pragma unroll 4
        for (int k4 = 0; k4 < 32; ++k4) {
            float4 h0 = *(const float4*)&hs[(r0 + 0) * 132 + k4 * 4];
            float4 h1 = *(const float4*)&hs[(r0 + 1) * 132 + k4 * 4];
            float4 w0 = *(const float4*)&Ws[(k4 * 4 + 0) * 64 + c0];
            float4 w1 = *(const float4*)&Ws[(k4 * 4 + 1) * 64 + c0];
            float4 w2 = *(const float4*)&Ws[(k4 * 4 + 2) * 64 + c0];
            float4 w3 = *(const float4*)&Ws[(k4 * 4 + 3) * 64 + c0];
            fma4(acc0, h0.x, w0); fma4(acc0, h0.y, w1); fma4(acc0, h0.z, w2); fma4(acc0, h0.w, w3);
            fma4(acc1, h1.x, w0); fma4(acc1, h1.y, w1); fma4(acc1, h1.z, w2); fma4(acc1, h1.w, w3);
        }
        *(float4*)(A + (size_t)(row0 + r0 + 0) * 64 + c0) = acc0;
        *(float4*)(A + (size_t)(row0 + r0 + 1) * 64 + c0) = acc1;
    }
}

static inline size_t alignup(size_t v, size_t a) { return (v + a - 1) & ~(a - 1); }

extern "C" void kernel_launch(void* const* d_in, const int* in_sizes, int n_in,
                              void* d_out, int out_size, void* d_ws, size_t ws_size,
                              hipStream_t stream) {
    const float* x  = (const float*)d_in[0];
    const float* W1 = (const float*)d_in[1];
    const float* b1 = (const float*)d_in[2];
    const float* W2 = (const float*)d_in[3];
    const float* b2 = (const float*)d_in[4];
    const int* src  = (const int*)d_in[5];
    const int* dst  = (const int*)d_in[6];
    float* out = (float*)d_out;

    const int nfeat = N_NODES * 64;
    const int nfeat4 = nfeat / 4;

    // ---- tier-1 layout (64B-aligned fields) ----
    char* base = (char*)d_ws;
    size_t o = 0;
    size_t o_xh   = o;   o = alignup(o + (size_t)nfeat * 2, 64);            // 12.8 MB
    size_t o_es   = o;   o = alignup(o + (size_t)N_EDGES * 4, 64);          // 6.4 MB
    size_t o_off  = o;   o = alignup(o + (size_t)(N_NODES + 1) * 4, 64);
    size_t o_C    = o;   o = alignup(o + (size_t)NPBLK * NBK2 * 4, 64);     // 800 KB
    size_t o_btot = o;   o = alignup(o + (size_t)NBK2 * 4, 64);
    size_t o_shrd = o;   o = alignup(o + (size_t)nfeat * 4, 64);            // eb / A / H share
    size_t need1 = o;

    unsigned short* xh = (unsigned short*)(base + o_xh);
    int* es    = (int*)(base + o_es);
    int* off   = (int*)(base + o_off);
    int* C     = (int*)(base + o_C);
    int* btot  = (int*)(base + o_btot);
    int* eb    = (int*)(base + o_shrd);
    float* A   = (float*)(base + o_shrd);
    unsigned short* H = (unsigned short*)(base + o_shrd);
    unsigned short* zh = xh;

    if (ws_size >= need1) {
        // ---- fused cvt + count ----
        k_cvt_count<<<NPBLK + CVTBLK, 256, 0, stream>>>((const float4*)x, (uint4*)xh, dst, C);
        // ---- CSR build: multi-split, zero global atomics, no btscan launch ----
        k_colscan<<<NBK2, NPBLK, 0, stream>>>(C, btot);
        k_scat<<<NPBLK, 256, 0, stream>>>(src, dst, C, btot, eb);
        k_fill3<<<NBK2, 256, 0, stream>>>(eb, btot, off, es);

        // ---- layer 1 aggregate: A = segsum(xh)  (A overlays dead eb) ----
        k_gather8<<<N_NODES / 32, 256, 0, stream>>>((const uint4*)xh, es, off, nullptr, A);
        // ---- GEMM1: H = bf16(relu(A*W1+b1)), in place over A ----
        k_gemm1<<<N_NODES / MROWS, 256, 0, stream>>>(A, H, W1, b1);
        // ---- GEMM2: zh = bf16(H*W2) ----
        k_gemm2<<<N_NODES / MROWS, 256, 0, stream>>>(H, zh, W2);
        // ---- layer 2 aggregate + bias: out = b2 + segsum(zh) ----
        k_gather8<<<N_NODES / 32, 256, 0, stream>>>((const uint4*)zh, es, off, b2, out);
    } else {
        // ---- fallback: atomic scatter (fp32, minimal workspace) ----
        float* A3 = (float*)d_ws;
        k_zero_f4<<<(nfeat4 + 255) / 256, 256, 0, stream>>>((float4*)A3, nfeat4);
        int threads = N_EDGES * 16;
        k_scatter64<<<(threads + 255) / 256, 256, 0, stream>>>(x, src, dst, A3);
        k_mlpF<<<N_NODES / MROWS, 256, 0, stream>>>(A3, W1, b1, W2);
        k_init_bias<<<(nfeat + 255) / 256, 256, 0, stream>>>(out, b2, nfeat);
        k_scatter64<<<(threads + 255) / 256, 256, 0, stream>>>(A3, src, dst, out);
    }
}